// Round 1
// 1954.496 us; speedup vs baseline: 1.2286x; 1.2286x over previous
//
#include <hip/hip_runtime.h>

using bf16 = __bf16;
typedef __bf16 bf16x4 __attribute__((ext_vector_type(4)));
typedef __bf16 bf16x8 __attribute__((ext_vector_type(8)));
typedef float  f32x4  __attribute__((ext_vector_type(4)));

#define LDS_STRIDE 40  // 32+8 pad

// ---- dtype-dispatched access helpers (flag: 1 = inputs are fp32, 0 = bf16) --
__device__ __forceinline__ float ldf(const void* p, size_t i, int f32) {
    return f32 ? ((const float*)p)[i] : (float)((const bf16*)p)[i];
}
__device__ __forceinline__ bf16x8 ld8(const void* p, size_t i, int f32) {
    bf16x8 r;
    if (f32) {
        f32x4 a = *(const f32x4*)((const float*)p + i);
        f32x4 b = *(const f32x4*)((const float*)p + i + 4);
#pragma unroll
        for (int j = 0; j < 4; ++j) { r[j] = (bf16)a[j]; r[j + 4] = (bf16)b[j]; }
    } else {
        r = *(const bf16x8*)((const bf16*)p + i);
    }
    return r;
}
__device__ __forceinline__ void st1(void* p, size_t i, float v, int f32) {
    if (f32) ((float*)p)[i] = v;
    else     ((bf16*)p)[i] = (bf16)v;
}

// ---- detect: bf16 NaN/Inf bit patterns exist iff backing store is fp32 -----
__global__ void init_flag(int* __restrict__ dflag) { *dflag = 0; }

__global__ void detect_kernel(const unsigned short* __restrict__ p, int n,
                              int* __restrict__ dflag)
{
    // scan as u32 words; bf16 NaN/Inf pattern = exponent bits (14:7) all ones
    const unsigned int* q = (const unsigned int*)p;
    const int nw = n >> 1;
    int hit = 0;
    for (int i = blockIdx.x * 256 + threadIdx.x; i < nw; i += gridDim.x * 256) {
        unsigned int w = q[i];
        if ((w & 0x7F80u) == 0x7F80u || (w & 0x7F800000u) == 0x7F800000u) hit = 1;
    }
    if (__any(hit) && (threadIdx.x & 63) == 0) atomicOr(dflag, 1);
}

// ---- convert an input array to internal bf16 (vectorized 8/thread) ---------
__global__ void cvt_kernel(const void* __restrict__ src, bf16* __restrict__ dst,
                           int n, const int* __restrict__ dflag)
{
    const int f32 = *dflag;
    const int stride = gridDim.x * 256;
    if ((n & 7) == 0) {
        const int nv = n >> 3;
        for (int i = blockIdx.x * 256 + threadIdx.x; i < nv; i += stride) {
            bf16x8 v = ld8(src, (size_t)i * 8, f32);
            *(bf16x8*)(dst + (size_t)i * 8) = v;
        }
    } else {
        for (int i = blockIdx.x * 256 + threadIdx.x; i < n; i += stride)
            dst[i] = (bf16)ldf(src, i, f32);
    }
}

// ---- transpose input weight (KxN) -> bf16 Wt (NxK) -------------------------
__global__ void transpose_any(const void* __restrict__ W, bf16* __restrict__ Wt,
                              int K, int N, const int* __restrict__ dflag)
{
    __shared__ bf16 tile[32][33];
    const int f32 = *dflag;
    const int n0 = blockIdx.x * 32, k0 = blockIdx.y * 32;
    const int tx = threadIdx.x, ty = threadIdx.y;  // (32, 8)
#pragma unroll
    for (int i = 0; i < 4; ++i)
        tile[ty + i * 8][tx] = (bf16)ldf(W, (size_t)(k0 + ty + i * 8) * N + n0 + tx, f32);
    __syncthreads();
#pragma unroll
    for (int i = 0; i < 4; ++i)
        Wt[(size_t)(n0 + ty + i * 8) * K + k0 + tx] = tile[tx][ty + i * 8];
}

// ---------------------------------------------------------------------------
// bf16 MFMA GEMM, C = act(A @ B + bias). A: internal bf16 MxK row-major.
// B: INPUT weight (dtype-dispatched), KxN row-major, element offset boff.
// Block 256 = 4 waves 2x2, wave tile 32x32, BK=32.
// ---------------------------------------------------------------------------
template<bool RELU, bool BIAS, bool F32OUT>
__global__ __launch_bounds__(256)
void gemm_bn(const bf16* __restrict__ A, int lda,
             const void* __restrict__ B, size_t boff, int ldb,
             const bf16* __restrict__ bias,
             void* __restrict__ Cout, int ldc, int K,
             const int* __restrict__ dflag)
{
    __shared__ bf16 As[64 * LDS_STRIDE];
    __shared__ bf16 Bs[64 * LDS_STRIDE];
    const int f32 = *dflag;
    const int t = threadIdx.x;
    const int l = t & 63;
    const int quad = l >> 4, lr = l & 15;
    const int w = t >> 6, wm = w >> 1, wn = w & 1;
    const int mBlock = blockIdx.y * 64, nBlock = blockIdx.x * 64;
    const int ar = t >> 2, ac = (t & 3) * 8;      // A-stage coords
    const int kr = t >> 3, nc = (t & 7) * 8;      // B-stage coords

    f32x4 acc[2][2] = {};

    for (int k0 = 0; k0 < K; k0 += 32) {
        __syncthreads();
        *(bf16x8*)&As[ar * LDS_STRIDE + ac] =
            *(const bf16x8*)(A + (size_t)(mBlock + ar) * lda + k0 + ac);
        {
            bf16x8 v = ld8(B, boff + (size_t)(k0 + kr) * ldb + nBlock + nc, f32);
#pragma unroll
            for (int j = 0; j < 8; ++j)
                Bs[(nc + j) * LDS_STRIDE + kr] = v[j];
        }
        __syncthreads();

        bf16x8 af[2], bfr[2];
#pragma unroll
        for (int mi = 0; mi < 2; ++mi)
            af[mi] = *(const bf16x8*)&As[(wm * 32 + mi * 16 + lr) * LDS_STRIDE + quad * 8];
#pragma unroll
        for (int nj = 0; nj < 2; ++nj)
            bfr[nj] = *(const bf16x8*)&Bs[(wn * 32 + nj * 16 + lr) * LDS_STRIDE + quad * 8];
#pragma unroll
        for (int mi = 0; mi < 2; ++mi)
#pragma unroll
            for (int nj = 0; nj < 2; ++nj)
                acc[mi][nj] = __builtin_amdgcn_mfma_f32_16x16x32_bf16(
                    af[mi], bfr[nj], acc[mi][nj], 0, 0, 0);
    }

#pragma unroll
    for (int mi = 0; mi < 2; ++mi)
#pragma unroll
        for (int nj = 0; nj < 2; ++nj) {
            int col = nBlock + wn * 32 + nj * 16 + lr;
            float bv = BIAS ? (float)bias[col] : 0.f;
#pragma unroll
            for (int rr = 0; rr < 4; ++rr) {
                int row = mBlock + wm * 32 + mi * 16 + quad * 4 + rr;
                float v = acc[mi][nj][rr] + bv;
                if (RELU) v = fmaxf(v, 0.f);
                if (F32OUT) ((float*)Cout)[(size_t)row * ldc + col] = v;
                else        ((bf16*)Cout)[(size_t)row * ldc + col] = (bf16)v;
            }
        }
}

// ---------------------------------------------------------------------------
// Fused pair MLP. A[p,k] = relu(Hpart[h(p),k]+Opart[n(p),k]+b_a1[k]) on the
// fly, MFMA vs Wt_a2 (1024x2048 bf16), epilogue folds relu(.+b_a2).W_a3 into
// per-row partials -> slots[p*16 + nb*2 + wn] (deterministic, no atomics).
// Grid (8 nb, 128 mb); block 256 = 4 waves 2x2, wave tile 64x64.
// ---------------------------------------------------------------------------
__global__ __launch_bounds__(256)
void pair_gemm(const float* __restrict__ Hpart, const float* __restrict__ Opart,
               const bf16* __restrict__ b_a1, const bf16* __restrict__ Wt_a2,
               const bf16* __restrict__ b_a2, const bf16* __restrict__ w_a3,
               float* __restrict__ slots)
{
    __shared__ bf16 As[128 * LDS_STRIDE];
    __shared__ bf16 Bs[128 * LDS_STRIDE];
    const int t = threadIdx.x;
    const int l = t & 63, w = t >> 6;
    const int quad = l >> 4, lr = l & 15;
    const int wm = w >> 1, wn = w & 1;
    const int nb = blockIdx.x, mb = blockIdx.y;
    const int p0 = mb * 128;
    const int h = p0 >> 8;            // 128-row tile never crosses an h boundary
    const int nBase = p0 & 255;
    const int ar = t >> 1, ac0 = (t & 1) * 16;
    const float* Hrow = Hpart + h * 2048;
    const float* Orow = Opart + (size_t)(nBase + ar) * 2048;

    f32x4 acc[4][4] = {};

    for (int k0 = 0; k0 < 2048; k0 += 32) {
        __syncthreads();
        {
            const float* hp = Hrow + k0 + ac0;
            const float* op = Orow + k0 + ac0;
            f32x4 h0 = *(const f32x4*)(hp);
            f32x4 h1 = *(const f32x4*)(hp + 4);
            f32x4 h2 = *(const f32x4*)(hp + 8);
            f32x4 h3 = *(const f32x4*)(hp + 12);
            f32x4 o0 = *(const f32x4*)(op);
            f32x4 o1 = *(const f32x4*)(op + 4);
            f32x4 o2 = *(const f32x4*)(op + 8);
            f32x4 o3 = *(const f32x4*)(op + 12);
            bf16x8 r0, r1;
#pragma unroll
            for (int j = 0; j < 4; ++j) {
                r0[j]     = (bf16)fmaxf(h0[j] + o0[j] + (float)b_a1[k0 + ac0 + j],      0.f);
                r0[j + 4] = (bf16)fmaxf(h1[j] + o1[j] + (float)b_a1[k0 + ac0 + 4 + j],  0.f);
                r1[j]     = (bf16)fmaxf(h2[j] + o2[j] + (float)b_a1[k0 + ac0 + 8 + j],  0.f);
                r1[j + 4] = (bf16)fmaxf(h3[j] + o3[j] + (float)b_a1[k0 + ac0 + 12 + j], 0.f);
            }
            *(bf16x8*)&As[ar * LDS_STRIDE + ac0]     = r0;
            *(bf16x8*)&As[ar * LDS_STRIDE + ac0 + 8] = r1;
        }
#pragma unroll
        for (int i = 0; i < 2; ++i) {
            int idx = t + i * 256;
            int r = idx >> 2, c = (idx & 3) * 8;
            *(bf16x8*)&Bs[r * LDS_STRIDE + c] =
                *(const bf16x8*)(Wt_a2 + (size_t)(nb * 128 + r) * 2048 + k0 + c);
        }
        __syncthreads();

        bf16x8 af[4], bfr[4];
#pragma unroll
        for (int mi = 0; mi < 4; ++mi)
            af[mi] = *(const bf16x8*)&As[(wm * 64 + mi * 16 + lr) * LDS_STRIDE + quad * 8];
#pragma unroll
        for (int nj = 0; nj < 4; ++nj)
            bfr[nj] = *(const bf16x8*)&Bs[(wn * 64 + nj * 16 + lr) * LDS_STRIDE + quad * 8];
#pragma unroll
        for (int mi = 0; mi < 4; ++mi)
#pragma unroll
            for (int nj = 0; nj < 4; ++nj)
                acc[mi][nj] = __builtin_amdgcn_mfma_f32_16x16x32_bf16(
                    af[mi], bfr[nj], acc[mi][nj], 0, 0, 0);
    }

    float w3v[4], b2v[4];
#pragma unroll
    for (int nj = 0; nj < 4; ++nj) {
        int col = nb * 128 + wn * 64 + nj * 16 + lr;
        w3v[nj] = (float)w_a3[col];
        b2v[nj] = (float)b_a2[col];
    }
#pragma unroll
    for (int mi = 0; mi < 4; ++mi) {
        f32x4 rs = {0.f, 0.f, 0.f, 0.f};
#pragma unroll
        for (int nj = 0; nj < 4; ++nj)
#pragma unroll
            for (int rr = 0; rr < 4; ++rr)
                rs[rr] += fmaxf(acc[mi][nj][rr] + b2v[nj], 0.f) * w3v[nj];
#pragma unroll
        for (int off = 1; off < 16; off <<= 1) {
            rs[0] += __shfl_xor(rs[0], off);
            rs[1] += __shfl_xor(rs[1], off);
            rs[2] += __shfl_xor(rs[2], off);
            rs[3] += __shfl_xor(rs[3], off);
        }
        if (lr == 0) {
            int p = p0 + wm * 64 + mi * 16 + quad * 4;
            int slot = nb * 2 + wn;
            slots[(size_t)(p + 0) * 16 + slot] = rs[0];
            slots[(size_t)(p + 1) * 16 + slot] = rs[1];
            slots[(size_t)(p + 2) * 16 + slot] = rs[2];
            slots[(size_t)(p + 3) * 16 + slot] = rs[3];
        }
    }
}

__global__ void adj_finalize(const float* __restrict__ slots,
                             const bf16* __restrict__ b_a3, float* __restrict__ adj)
{
    int i = blockIdx.x * 256 + threadIdx.x;
    float s = (float)b_a3[0];
#pragma unroll
    for (int k = 0; k < 16; ++k) s += slots[(size_t)i * 16 + k];
    adj[i] = 1.f / (1.f + expf(-s));
}

__global__ void copy_rows(const bf16* __restrict__ src, int lds_,
                          bf16* __restrict__ dst, int ldd)
{
    int c = blockIdx.x * 256 + threadIdx.x;  // 1024 cols
    int r = blockIdx.y;
    dst[(size_t)r * ldd + c] = src[(size_t)r * lds_ + c];
}

// agg_o[h,e] = sum_n adj[h,n]*obj_msg[n,e]*(nsW[h,e]-nsW[n,e]); out stride 2048
__global__ void agg_o_kernel(const float* __restrict__ adj, const bf16* __restrict__ obj_msg,
                             const bf16* __restrict__ nsW, bf16* __restrict__ out)
{
    int e = blockIdx.x * 256 + threadIdx.x;
    int h = blockIdx.y;
    float nh = (float)nsW[h * 1024 + e];
    float s = 0.f;
    for (int n = 0; n < 256; ++n) {
        float a  = adj[h * 256 + n];
        float om = (float)obj_msg[n * 1024 + e];
        float nw = (float)nsW[n * 1024 + e];
        s += a * om * (nh - nw);
    }
    out[(size_t)h * 2048 + e] = (bf16)s;
}

// agg_h[n,e] = sum_h adj[h,n]*hum_msg[h,e]*(nsW[n,e]-nsW[h,e]); out stride 2048
__global__ void agg_h_kernel(const float* __restrict__ adj, const bf16* __restrict__ hum_msg,
                             const bf16* __restrict__ nsW, bf16* __restrict__ out)
{
    int e = blockIdx.x * 256 + threadIdx.x;
    int n = blockIdx.y;
    float nn = (float)nsW[n * 1024 + e];
    float s = 0.f;
    for (int h = 0; h < 64; ++h) {
        float a  = adj[h * 256 + n];
        float hm = (float)hum_msg[h * 1024 + e];
        float nw = (float)nsW[h * 1024 + e];
        s += a * hm * (nn - nw);
    }
    out[(size_t)n * 2048 + e] = (bf16)s;
}

// Output row r=(x,y): [h_enc[x] | nsp[x] | enc[y] | nsp[y] | prior(117)]
__global__ void out_kernel(const bf16* __restrict__ h_enc, const bf16* __restrict__ enc,
                           const bf16* __restrict__ nsp_bf, const float* __restrict__ adj,
                           const bf16* __restrict__ scores_bf, const int* __restrict__ labels,
                           const int* __restrict__ cmask, void* __restrict__ out,
                           const int* __restrict__ dflag)
{
    const int f32 = *dflag;
    const int r = blockIdx.x;
    const int x = r / 255;
    const int tt = r % 255;
    const int y = tt + (tt >= x ? 1 : 0);
    const size_t rbase = (size_t)r * 4213;
    const bf16* seg[4] = { h_enc + x * 1024, nsp_bf + x * 1024, enc + y * 1024, nsp_bf + y * 1024 };
    const int t = threadIdx.x;
#pragma unroll
    for (int k = 0; k < 4; ++k) {
        int ci = t + k * 256;            // 4-element chunk id
        int sidx = ci >> 8;
        int off = (ci & 255) * 4;
        bf16x4 v = *(const bf16x4*)(seg[sidx] + off);
        size_t d = rbase + sidx * 1024 + off;
        st1(out, d + 0, (float)v[0], f32);
        st1(out, d + 1, (float)v[1], f32);
        st1(out, d + 2, (float)v[2], f32);
        st1(out, d + 3, (float)v[3], f32);
    }
    if (t < 117) {
        float sx = (float)scores_bf[x], sy = (float)scores_bf[y];
        float lx = 8.3f / (1.f + expf(12.f - 10.f * sx));
        float ly = 8.3f / (1.f + expf(12.f - 10.f * sy));
        float a = adj[x * 256 + y];
        float m = cmask[labels[y] * 117 + t] ? 1.f : 0.f;
        st1(out, rbase + 4096 + t, a * lx * ly * m, f32);
    }
}

// ---------------------------------------------------------------------------
extern "C" void kernel_launch(void* const* d_in, const int* in_sizes, int n_in,
                              void* d_out, int out_size, void* d_ws, size_t ws_size,
                              hipStream_t stream)
{
    (void)in_sizes; (void)n_in; (void)out_size; (void)ws_size;
    const void* box    = d_in[0];
    const void* nsp    = d_in[1];
    const void* scores = d_in[2];
    const int*  labels = (const int*)d_in[3];
    const int*  cmask  = (const int*)d_in[4];
    const void* W_bh1 = d_in[5],  *b_bh1 = d_in[6];
    const void* W_bh2 = d_in[7],  *b_bh2 = d_in[8];
    const void* W_sa  = d_in[9];
    const void* W_a1  = d_in[10], *b_a1  = d_in[11];
    const void* W_a2  = d_in[12], *b_a2  = d_in[13];
    const void* W_a3  = d_in[14], *b_a3  = d_in[15];
    const void* W_hm  = d_in[16], *b_hm  = d_in[17];
    const void* W_om  = d_in[18], *b_om  = d_in[19];
    const void* W_hu  = d_in[20];
    const void* W_ou  = d_in[21];

    char* ws = (char*)d_ws;
    size_t off = 0;
    auto alloc = [&](size_t bytes) -> void* {
        off = (off + 255) & ~(size_t)255;
        void* p = ws + off;
        off += bytes;
        return p;
    };
    int*  dflag   = (int*)alloc(4);
    bf16* box_bf  = (bf16*)alloc((size_t)256 * 12544 * 2);
    bf16* nsp_bf  = (bf16*)alloc((size_t)256 * 1024 * 2);
    bf16* Wt_a2   = (bf16*)alloc((size_t)1024 * 2048 * 2);
    bf16* smalls  = (bf16*)alloc((size_t)8464 * 2);
    bf16* sb_bh1 = smalls,        *sb_bh2 = smalls + 1024;
    bf16* sb_om  = smalls + 2048, *sb_hm  = smalls + 3072;
    bf16* sb_a1  = smalls + 4096, *sb_a2  = smalls + 6144;
    bf16* sw_a3  = smalls + 7168, *sb_a3  = smalls + 8192;
    bf16* sscore = smalls + 8208;
    bf16* t0      = (bf16*)alloc((size_t)256 * 1024 * 2);
    bf16* enc     = (bf16*)alloc((size_t)256 * 1024 * 2);
    bf16* nsW     = (bf16*)alloc((size_t)256 * 1024 * 2);
    bf16* h_enc   = (bf16*)alloc((size_t)64 * 1024 * 2);
    bf16* hf      = (bf16*)alloc((size_t)64 * 2048 * 2);
    bf16* of      = (bf16*)alloc((size_t)256 * 2048 * 2);
    float* Hpart  = (float*)alloc((size_t)64 * 2048 * 4);
    float* Opart  = (float*)alloc((size_t)256 * 2048 * 4);
    float* slots  = (float*)alloc((size_t)16384 * 16 * 4);
    float* adj    = (float*)alloc((size_t)16384 * 4);
    bf16* obj_msg = (bf16*)alloc((size_t)256 * 1024 * 2);
    bf16* hu_in   = (bf16*)alloc((size_t)64 * 2048 * 2);
    bf16* hum_msg = (bf16*)alloc((size_t)64 * 1024 * 2);
    bf16* ou_in   = (bf16*)alloc((size_t)256 * 2048 * 2);

    // 1) dtype probe (fp32 backing store injects bf16-NaN patterns; bf16 cannot)
    //    parallelized: init flag, then 256 blocks grid-stride the 1 MB scan
    init_flag<<<1, 1, 0, stream>>>(dflag);
    detect_kernel<<<256, 256, 0, stream>>>((const unsigned short*)box, 524288, dflag);

    // 2) convert inputs used as A-operands / epilogue scalars to internal bf16
    auto cvt = [&](const void* s, bf16* d, int n) {
        int g = (n + 2047) / 2048; if (g < 1) g = 1; if (g > 4096) g = 4096;
        cvt_kernel<<<g, 256, 0, stream>>>(s, d, n, dflag);
    };
    cvt(box, box_bf, 256 * 12544);
    cvt(nsp, nsp_bf, 256 * 1024);
    cvt(b_bh1, sb_bh1, 1024);  cvt(b_bh2, sb_bh2, 1024);
    cvt(b_om,  sb_om,  1024);  cvt(b_hm,  sb_hm,  1024);
    cvt(b_a1,  sb_a1,  2048);  cvt(b_a2,  sb_a2,  1024);
    cvt(W_a3,  sw_a3,  1024);  cvt(b_a3,  sb_a3,  1);
    cvt(scores, sscore, 256);

    // 3) W_a2 -> bf16 transposed (hot operand of pair_gemm, re-read 128x)
    transpose_any<<<dim3(1024 / 32, 2048 / 32), dim3(32, 8), 0, stream>>>(
        W_a2, Wt_a2, 2048, 1024, dflag);

    // 4) enc = relu(relu(box@W_bh1+b)@W_bh2+b); nsW = nsp@W_sa
    gemm_bn<true, true, false><<<dim3(16, 4), 256, 0, stream>>>(
        box_bf, 12544, W_bh1, 0, 1024, sb_bh1, t0, 1024, 12544, dflag);
    gemm_bn<true, true, false><<<dim3(16, 4), 256, 0, stream>>>(
        t0, 1024, W_bh2, 0, 1024, sb_bh2, enc, 1024, 1024, dflag);
    gemm_bn<false, false, false><<<dim3(16, 4), 256, 0, stream>>>(
        nsp_bf, 1024, W_sa, 0, 1024, nullptr, nsW, 1024, 1024, dflag);
    copy_rows<<<dim3(4, 64), 256, 0, stream>>>(enc, 1024, h_enc, 1024);

    for (int it = 0; it < 2; ++it) {
        copy_rows<<<dim3(4, 64), 256, 0, stream>>>(h_enc, 1024, hf, 2048);
        copy_rows<<<dim3(4, 64), 256, 0, stream>>>(nsp_bf, 1024, hf + 1024, 2048);
        copy_rows<<<dim3(4, 256), 256, 0, stream>>>(enc, 1024, of, 2048);
        copy_rows<<<dim3(4, 256), 256, 0, stream>>>(nsp_bf, 1024, of + 1024, 2048);
        // Hpart = hf @ W_a1[:2048,:], Opart = of @ W_a1[2048:,:]   (fp32 out)
        gemm_bn<false, false, true><<<dim3(32, 1), 256, 0, stream>>>(
            hf, 2048, W_a1, 0, 2048, nullptr, Hpart, 2048, 2048, dflag);
        gemm_bn<false, false, true><<<dim3(32, 4), 256, 0, stream>>>(
            of, 2048, W_a1, (size_t)2048 * 2048, 2048, nullptr, Opart, 2048, 2048, dflag);
        // adj = sigmoid(pair MLP)   (deterministic slots, no atomics)
        pair_gemm<<<dim3(8, 128), 256, 0, stream>>>(Hpart, Opart, sb_a1, Wt_a2, sb_a2, sw_a3, slots);
        adj_finalize<<<dim3(64), 256, 0, stream>>>(slots, sb_a3, adj);
        // obj_msg = relu(enc @ W_om + b)
        gemm_bn<true, true, false><<<dim3(16, 4), 256, 0, stream>>>(
            enc, 1024, W_om, 0, 1024, sb_om, obj_msg, 1024, 1024, dflag);
        // h_enc = [h_enc | agg_o] @ W_hu
        copy_rows<<<dim3(4, 64), 256, 0, stream>>>(h_enc, 1024, hu_in, 2048);
        agg_o_kernel<<<dim3(4, 64), 256, 0, stream>>>(adj, obj_msg, nsW, hu_in + 1024);
        gemm_bn<false, false, false><<<dim3(16, 1), 256, 0, stream>>>(
            hu_in, 2048, W_hu, 0, 1024, nullptr, h_enc, 1024, 2048, dflag);
        // hum_msg = relu(h_enc @ W_hm + b)
        gemm_bn<true, true, false><<<dim3(16, 1), 256, 0, stream>>>(
            h_enc, 1024, W_hm, 0, 1024, sb_hm, hum_msg, 1024, 1024, dflag);
        // enc = [enc | agg_h] @ W_ou
        copy_rows<<<dim3(4, 256), 256, 0, stream>>>(enc, 1024, ou_in, 2048);
        agg_h_kernel<<<dim3(4, 256), 256, 0, stream>>>(adj, hum_msg, nsW, ou_in + 1024);
        gemm_bn<false, false, false><<<dim3(16, 4), 256, 0, stream>>>(
            ou_in, 2048, W_ou, 0, 1024, nullptr, enc, 1024, 2048, dflag);
    }

    out_kernel<<<dim3(16320), 256, 0, stream>>>(
        h_enc, enc, nsp_bf, adj, sscore, labels, cmask, d_out, dflag);
}

// Round 2
// 1152.217 us; speedup vs baseline: 2.0841x; 1.6963x over previous
//
#include <hip/hip_runtime.h>

using bf16 = __bf16;
typedef __bf16 bf16x4 __attribute__((ext_vector_type(4)));
typedef __bf16 bf16x8 __attribute__((ext_vector_type(8)));
typedef float  f32x4  __attribute__((ext_vector_type(4)));

#define LDS_STRIDE 40  // pair_gemm LDS row stride
#define GST 40         // gemm_p LDS row stride (80 B -> 16B-aligned b128 reads)

// ---- dtype-dispatched access helpers (flag: 1 = inputs are fp32, 0 = bf16) --
__device__ __forceinline__ float ldf(const void* p, size_t i, int f32) {
    return f32 ? ((const float*)p)[i] : (float)((const bf16*)p)[i];
}
__device__ __forceinline__ bf16x8 ld8(const void* p, size_t i, int f32) {
    bf16x8 r;
    if (f32) {
        f32x4 a = *(const f32x4*)((const float*)p + i);
        f32x4 b = *(const f32x4*)((const float*)p + i + 4);
#pragma unroll
        for (int j = 0; j < 4; ++j) { r[j] = (bf16)a[j]; r[j + 4] = (bf16)b[j]; }
    } else {
        r = *(const bf16x8*)((const bf16*)p + i);
    }
    return r;
}
__device__ __forceinline__ void st1(void* p, size_t i, float v, int f32) {
    if (f32) ((float*)p)[i] = v;
    else     ((bf16*)p)[i] = (bf16)v;
}

// ---- detect: bf16 NaN/Inf bit patterns exist iff backing store is fp32 -----
__global__ void init_flag(int* __restrict__ dflag) { *dflag = 0; }

__global__ void detect_kernel(const unsigned short* __restrict__ p, int n,
                              int* __restrict__ dflag)
{
    const unsigned int* q = (const unsigned int*)p;
    const int nw = n >> 1;
    int hit = 0;
    for (int i = blockIdx.x * 256 + threadIdx.x; i < nw; i += gridDim.x * 256) {
        unsigned int w = q[i];
        if ((w & 0x7F80u) == 0x7F80u || (w & 0x7F800000u) == 0x7F800000u) hit = 1;
    }
    if (__any(hit) && (threadIdx.x & 63) == 0) atomicOr(dflag, 1);
}

// ---- convert an input array to internal bf16 (vectorized 8/thread) ---------
__global__ void cvt_kernel(const void* __restrict__ src, bf16* __restrict__ dst,
                           int n, const int* __restrict__ dflag)
{
    const int f32 = *dflag;
    const int stride = gridDim.x * 256;
    if ((n & 7) == 0) {
        const int nv = n >> 3;
        for (int i = blockIdx.x * 256 + threadIdx.x; i < nv; i += stride) {
            bf16x8 v = ld8(src, (size_t)i * 8, f32);
            *(bf16x8*)(dst + (size_t)i * 8) = v;
        }
    } else {
        for (int i = blockIdx.x * 256 + threadIdx.x; i < n; i += stride)
            dst[i] = (bf16)ldf(src, i, f32);
    }
}

// ---- transpose input weight (KxN) -> bf16 Wt (NxK) -------------------------
__global__ void transpose_any(const void* __restrict__ W, bf16* __restrict__ Wt,
                              int K, int N, const int* __restrict__ dflag)
{
    __shared__ bf16 tile[32][33];
    const int f32 = *dflag;
    const int n0 = blockIdx.x * 32, k0 = blockIdx.y * 32;
    const int tx = threadIdx.x, ty = threadIdx.y;  // (32, 8)
#pragma unroll
    for (int i = 0; i < 4; ++i)
        tile[ty + i * 8][tx] = (bf16)ldf(W, (size_t)(k0 + ty + i * 8) * N + n0 + tx, f32);
    __syncthreads();
#pragma unroll
    for (int i = 0; i < 4; ++i)
        Wt[(size_t)(n0 + ty + i * 8) * K + k0 + tx] = tile[tx][ty + i * 8];
}

// ---------------------------------------------------------------------------
// Split-K bf16 MFMA GEMM -> fp32 partials. A: internal bf16 MxK row-major.
// B: INPUT weight (dtype-dispatched), KxN row-major, element offset boff.
// Block 256 = 4 waves 2x2, wave tile 32x32, BK=32. blockIdx.z = K-split;
// each split writes its own fp32 slab part[z][M][N]. Reg-staged prefetch;
// B scatter uses group-XOR swizzle (kills the 16-way bank conflict).
// ---------------------------------------------------------------------------
__global__ __launch_bounds__(256)
void gemm_p(const bf16* __restrict__ A, int lda,
            const void* __restrict__ B, size_t boff, int ldb,
            float* __restrict__ part, int N, int Kc,
            const int* __restrict__ dflag)
{
    __shared__ bf16 As[64 * GST];
    __shared__ bf16 Bs[64 * GST];
    const int f32 = *dflag;
    const int t = threadIdx.x;
    const int l = t & 63;
    const int quad = l >> 4, lr = l & 15;
    const int w = t >> 6, wm = w >> 1, wn = w & 1;
    const int mBlock = blockIdx.y * 64, nBlock = blockIdx.x * 64;
    const int ar = t >> 2, ac = (t & 3) * 8;      // A-stage coords
    const int kr = t >> 3, nc = (t & 7) * 8;      // B-stage coords
    const int kBeg = blockIdx.z * Kc;
    const int nIter = Kc >> 5;

    f32x4 acc[2][2] = {};

    // preload tile 0 into registers
    bf16x8 avr = *(const bf16x8*)(A + (size_t)(mBlock + ar) * lda + kBeg + ac);
    bf16x8 bvr = ld8(B, boff + (size_t)(kBeg + kr) * ldb + nBlock + nc, f32);

    for (int it = 0; it < nIter; ++it) {
        // stage current tile (B scatter with group-XOR swizzle)
        *(bf16x8*)&As[ar * GST + ac] = avr;
#pragma unroll
        for (int j = 0; j < 8; ++j) {
            int wr = nc + j;
            Bs[wr * GST + (kr ^ (((wr >> 3) & 3) << 3))] = bvr[j];
        }
        __syncthreads();
        // prefetch next tile (latency hides under frag reads + MFMA)
        if (it + 1 < nIter) {
            int k0 = kBeg + (it + 1) * 32;
            avr = *(const bf16x8*)(A + (size_t)(mBlock + ar) * lda + k0 + ac);
            bvr = ld8(B, boff + (size_t)(k0 + kr) * ldb + nBlock + nc, f32);
        }
        bf16x8 af[2], bfr[2];
#pragma unroll
        for (int mi = 0; mi < 2; ++mi)
            af[mi] = *(const bf16x8*)&As[(wm * 32 + mi * 16 + lr) * GST + quad * 8];
#pragma unroll
        for (int nj = 0; nj < 2; ++nj) {
            int row = wn * 32 + nj * 16 + lr;
            bfr[nj] = *(const bf16x8*)&Bs[row * GST + ((quad * 8) ^ (((row >> 3) & 3) << 3))];
        }
#pragma unroll
        for (int mi = 0; mi < 2; ++mi)
#pragma unroll
            for (int nj = 0; nj < 2; ++nj)
                acc[mi][nj] = __builtin_amdgcn_mfma_f32_16x16x32_bf16(
                    af[mi], bfr[nj], acc[mi][nj], 0, 0, 0);
        __syncthreads();
    }

    float* outp = part + (size_t)blockIdx.z * ((size_t)gridDim.y * 64 * N);
#pragma unroll
    for (int mi = 0; mi < 2; ++mi)
#pragma unroll
        for (int nj = 0; nj < 2; ++nj) {
            int col = nBlock + wn * 32 + nj * 16 + lr;
#pragma unroll
            for (int rr = 0; rr < 4; ++rr) {
                int row = mBlock + wm * 32 + mi * 16 + quad * 4 + rr;
                outp[(size_t)row * N + col] = acc[mi][nj][rr];
            }
        }
}

// ---- reduce split-K partials, apply bias/relu, write bf16 or fp32 ----------
template<bool RELU, bool BIAS, bool F32OUT>
__global__ void reduce_k(const float* __restrict__ part, int S, int total,
                         const bf16* __restrict__ bias, void* __restrict__ out, int N)
{
    int base = (blockIdx.x * 256 + threadIdx.x) * 4;
    if (base >= total) return;
    f32x4 s = *(const f32x4*)(part + base);
    for (int z = 1; z < S; ++z) {
        f32x4 v = *(const f32x4*)(part + (size_t)z * total + base);
        s[0] += v[0]; s[1] += v[1]; s[2] += v[2]; s[3] += v[3];
    }
    int col = base % N;
#pragma unroll
    for (int j = 0; j < 4; ++j) {
        float v = s[j];
        if (BIAS) v += (float)bias[col + j];
        if (RELU) v = fmaxf(v, 0.f);
        if (F32OUT) ((float*)out)[base + j] = v;
        else        ((bf16*)out)[base + j] = (bf16)v;
    }
}

// ---------------------------------------------------------------------------
// Fused pair MLP (unchanged this round).
// ---------------------------------------------------------------------------
__global__ __launch_bounds__(256)
void pair_gemm(const float* __restrict__ Hpart, const float* __restrict__ Opart,
               const bf16* __restrict__ b_a1, const bf16* __restrict__ Wt_a2,
               const bf16* __restrict__ b_a2, const bf16* __restrict__ w_a3,
               float* __restrict__ slots)
{
    __shared__ bf16 As[128 * LDS_STRIDE];
    __shared__ bf16 Bs[128 * LDS_STRIDE];
    const int t = threadIdx.x;
    const int l = t & 63, w = t >> 6;
    const int quad = l >> 4, lr = l & 15;
    const int wm = w >> 1, wn = w & 1;
    const int nb = blockIdx.x, mb = blockIdx.y;
    const int p0 = mb * 128;
    const int h = p0 >> 8;            // 128-row tile never crosses an h boundary
    const int nBase = p0 & 255;
    const int ar = t >> 1, ac0 = (t & 1) * 16;
    const float* Hrow = Hpart + h * 2048;
    const float* Orow = Opart + (size_t)(nBase + ar) * 2048;

    f32x4 acc[4][4] = {};

    for (int k0 = 0; k0 < 2048; k0 += 32) {
        __syncthreads();
        {
            const float* hp = Hrow + k0 + ac0;
            const float* op = Orow + k0 + ac0;
            f32x4 h0 = *(const f32x4*)(hp);
            f32x4 h1 = *(const f32x4*)(hp + 4);
            f32x4 h2 = *(const f32x4*)(hp + 8);
            f32x4 h3 = *(const f32x4*)(hp + 12);
            f32x4 o0 = *(const f32x4*)(op);
            f32x4 o1 = *(const f32x4*)(op + 4);
            f32x4 o2 = *(const f32x4*)(op + 8);
            f32x4 o3 = *(const f32x4*)(op + 12);
            bf16x8 r0, r1;
#pragma unroll
            for (int j = 0; j < 4; ++j) {
                r0[j]     = (bf16)fmaxf(h0[j] + o0[j] + (float)b_a1[k0 + ac0 + j],      0.f);
                r0[j + 4] = (bf16)fmaxf(h1[j] + o1[j] + (float)b_a1[k0 + ac0 + 4 + j],  0.f);
                r1[j]     = (bf16)fmaxf(h2[j] + o2[j] + (float)b_a1[k0 + ac0 + 8 + j],  0.f);
                r1[j + 4] = (bf16)fmaxf(h3[j] + o3[j] + (float)b_a1[k0 + ac0 + 12 + j], 0.f);
            }
            *(bf16x8*)&As[ar * LDS_STRIDE + ac0]     = r0;
            *(bf16x8*)&As[ar * LDS_STRIDE + ac0 + 8] = r1;
        }
#pragma unroll
        for (int i = 0; i < 2; ++i) {
            int idx = t + i * 256;
            int r = idx >> 2, c = (idx & 3) * 8;
            *(bf16x8*)&Bs[r * LDS_STRIDE + c] =
                *(const bf16x8*)(Wt_a2 + (size_t)(nb * 128 + r) * 2048 + k0 + c);
        }
        __syncthreads();

        bf16x8 af[4], bfr[4];
#pragma unroll
        for (int mi = 0; mi < 4; ++mi)
            af[mi] = *(const bf16x8*)&As[(wm * 64 + mi * 16 + lr) * LDS_STRIDE + quad * 8];
#pragma unroll
        for (int nj = 0; nj < 4; ++nj)
            bfr[nj] = *(const bf16x8*)&Bs[(wn * 64 + nj * 16 + lr) * LDS_STRIDE + quad * 8];
#pragma unroll
        for (int mi = 0; mi < 4; ++mi)
#pragma unroll
            for (int nj = 0; nj < 4; ++nj)
                acc[mi][nj] = __builtin_amdgcn_mfma_f32_16x16x32_bf16(
                    af[mi], bfr[nj], acc[mi][nj], 0, 0, 0);
    }

    float w3v[4], b2v[4];
#pragma unroll
    for (int nj = 0; nj < 4; ++nj) {
        int col = nb * 128 + wn * 64 + nj * 16 + lr;
        w3v[nj] = (float)w_a3[col];
        b2v[nj] = (float)b_a2[col];
    }
#pragma unroll
    for (int mi = 0; mi < 4; ++mi) {
        f32x4 rs = {0.f, 0.f, 0.f, 0.f};
#pragma unroll
        for (int nj = 0; nj < 4; ++nj)
#pragma unroll
            for (int rr = 0; rr < 4; ++rr)
                rs[rr] += fmaxf(acc[mi][nj][rr] + b2v[nj], 0.f) * w3v[nj];
#pragma unroll
        for (int off = 1; off < 16; off <<= 1) {
            rs[0] += __shfl_xor(rs[0], off);
            rs[1] += __shfl_xor(rs[1], off);
            rs[2] += __shfl_xor(rs[2], off);
            rs[3] += __shfl_xor(rs[3], off);
        }
        if (lr == 0) {
            int p = p0 + wm * 64 + mi * 16 + quad * 4;
            int slot = nb * 2 + wn;
            slots[(size_t)(p + 0) * 16 + slot] = rs[0];
            slots[(size_t)(p + 1) * 16 + slot] = rs[1];
            slots[(size_t)(p + 2) * 16 + slot] = rs[2];
            slots[(size_t)(p + 3) * 16 + slot] = rs[3];
        }
    }
}

__global__ void adj_finalize(const float* __restrict__ slots,
                             const bf16* __restrict__ b_a3, float* __restrict__ adj)
{
    int i = blockIdx.x * 256 + threadIdx.x;
    float s = (float)b_a3[0];
#pragma unroll
    for (int k = 0; k < 16; ++k) s += slots[(size_t)i * 16 + k];
    adj[i] = 1.f / (1.f + expf(-s));
}

__global__ void copy_rows(const bf16* __restrict__ src, int lds_,
                          bf16* __restrict__ dst, int ldd)
{
    int c = blockIdx.x * 256 + threadIdx.x;  // 1024 cols
    int r = blockIdx.y;
    dst[(size_t)r * ldd + c] = src[(size_t)r * lds_ + c];
}

// agg_o[h,e] = sum_n adj[h,n]*obj_msg[n,e]*(nsW[h,e]-nsW[n,e]); out stride 2048
__global__ void agg_o_kernel(const float* __restrict__ adj, const bf16* __restrict__ obj_msg,
                             const bf16* __restrict__ nsW, bf16* __restrict__ out)
{
    int e = blockIdx.x * 256 + threadIdx.x;
    int h = blockIdx.y;
    float nh = (float)nsW[h * 1024 + e];
    float s = 0.f;
    for (int n = 0; n < 256; ++n) {
        float a  = adj[h * 256 + n];
        float om = (float)obj_msg[n * 1024 + e];
        float nw = (float)nsW[n * 1024 + e];
        s += a * om * (nh - nw);
    }
    out[(size_t)h * 2048 + e] = (bf16)s;
}

// agg_h[n,e] = sum_h adj[h,n]*hum_msg[h,e]*(nsW[n,e]-nsW[h,e]); out stride 2048
__global__ void agg_h_kernel(const float* __restrict__ adj, const bf16* __restrict__ hum_msg,
                             const bf16* __restrict__ nsW, bf16* __restrict__ out)
{
    int e = blockIdx.x * 256 + threadIdx.x;
    int n = blockIdx.y;
    float nn = (float)nsW[n * 1024 + e];
    float s = 0.f;
    for (int h = 0; h < 64; ++h) {
        float a  = adj[h * 256 + n];
        float hm = (float)hum_msg[h * 1024 + e];
        float nw = (float)nsW[h * 1024 + e];
        s += a * hm * (nn - nw);
    }
    out[(size_t)n * 2048 + e] = (bf16)s;
}

// Output row r=(x,y): [h_enc[x] | nsp[x] | enc[y] | nsp[y] | prior(117)]
__global__ void out_kernel(const bf16* __restrict__ h_enc, const bf16* __restrict__ enc,
                           const bf16* __restrict__ nsp_bf, const float* __restrict__ adj,
                           const bf16* __restrict__ scores_bf, const int* __restrict__ labels,
                           const int* __restrict__ cmask, void* __restrict__ out,
                           const int* __restrict__ dflag)
{
    const int f32 = *dflag;
    const int r = blockIdx.x;
    const int x = r / 255;
    const int tt = r % 255;
    const int y = tt + (tt >= x ? 1 : 0);
    const size_t rbase = (size_t)r * 4213;
    const bf16* seg[4] = { h_enc + x * 1024, nsp_bf + x * 1024, enc + y * 1024, nsp_bf + y * 1024 };
    const int t = threadIdx.x;
#pragma unroll
    for (int k = 0; k < 4; ++k) {
        int ci = t + k * 256;            // 4-element chunk id
        int sidx = ci >> 8;
        int off = (ci & 255) * 4;
        bf16x4 v = *(const bf16x4*)(seg[sidx] + off);
        size_t d = rbase + sidx * 1024 + off;
        st1(out, d + 0, (float)v[0], f32);
        st1(out, d + 1, (float)v[1], f32);
        st1(out, d + 2, (float)v[2], f32);
        st1(out, d + 3, (float)v[3], f32);
    }
    if (t < 117) {
        float sx = (float)scores_bf[x], sy = (float)scores_bf[y];
        float lx = 8.3f / (1.f + expf(12.f - 10.f * sx));
        float ly = 8.3f / (1.f + expf(12.f - 10.f * sy));
        float a = adj[x * 256 + y];
        float m = cmask[labels[y] * 117 + t] ? 1.f : 0.f;
        st1(out, rbase + 4096 + t, a * lx * ly * m, f32);
    }
}

// ---------------------------------------------------------------------------
extern "C" void kernel_launch(void* const* d_in, const int* in_sizes, int n_in,
                              void* d_out, int out_size, void* d_ws, size_t ws_size,
                              hipStream_t stream)
{
    (void)in_sizes; (void)n_in; (void)out_size; (void)ws_size;
    const void* box    = d_in[0];
    const void* nsp    = d_in[1];
    const void* scores = d_in[2];
    const int*  labels = (const int*)d_in[3];
    const int*  cmask  = (const int*)d_in[4];
    const void* W_bh1 = d_in[5],  *b_bh1 = d_in[6];
    const void* W_bh2 = d_in[7],  *b_bh2 = d_in[8];
    const void* W_sa  = d_in[9];
    const void* W_a1  = d_in[10], *b_a1  = d_in[11];
    const void* W_a2  = d_in[12], *b_a2  = d_in[13];
    const void* W_a3  = d_in[14], *b_a3  = d_in[15];
    const void* W_hm  = d_in[16], *b_hm  = d_in[17];
    const void* W_om  = d_in[18], *b_om  = d_in[19];
    const void* W_hu  = d_in[20];
    const void* W_ou  = d_in[21];

    char* ws = (char*)d_ws;
    size_t off = 0;
    auto alloc = [&](size_t bytes) -> void* {
        off = (off + 255) & ~(size_t)255;
        void* p = ws + off;
        off += bytes;
        return p;
    };
    int*  dflag   = (int*)alloc(4);
    bf16* box_bf  = (bf16*)alloc((size_t)256 * 12544 * 2);
    bf16* nsp_bf  = (bf16*)alloc((size_t)256 * 1024 * 2);
    bf16* Wt_a2   = (bf16*)alloc((size_t)1024 * 2048 * 2);
    bf16* smalls  = (bf16*)alloc((size_t)8464 * 2);
    bf16* sb_bh1 = smalls,        *sb_bh2 = smalls + 1024;
    bf16* sb_om  = smalls + 2048, *sb_hm  = smalls + 3072;
    bf16* sb_a1  = smalls + 4096, *sb_a2  = smalls + 6144;
    bf16* sw_a3  = smalls + 7168, *sb_a3  = smalls + 8192;
    bf16* sscore = smalls + 8208;
    bf16* t0      = (bf16*)alloc((size_t)256 * 1024 * 2);
    bf16* enc     = (bf16*)alloc((size_t)256 * 1024 * 2);
    bf16* nsW     = (bf16*)alloc((size_t)256 * 1024 * 2);
    bf16* h_enc   = (bf16*)alloc((size_t)64 * 1024 * 2);
    bf16* hf      = (bf16*)alloc((size_t)64 * 2048 * 2);
    bf16* of      = (bf16*)alloc((size_t)256 * 2048 * 2);
    float* Hpart  = (float*)alloc((size_t)64 * 2048 * 4);
    float* Opart  = (float*)alloc((size_t)256 * 2048 * 4);
    float* slots  = (float*)alloc((size_t)16384 * 16 * 4);
    float* adj    = (float*)alloc((size_t)16384 * 4);
    bf16* obj_msg = (bf16*)alloc((size_t)256 * 1024 * 2);
    bf16* hu_in   = (bf16*)alloc((size_t)64 * 2048 * 2);
    bf16* hum_msg = (bf16*)alloc((size_t)64 * 1024 * 2);
    bf16* ou_in   = (bf16*)alloc((size_t)256 * 2048 * 2);
    float* part   = (float*)alloc((size_t)2097152 * 4);  // split-K partials (8 MB)

    // 1) dtype probe
    init_flag<<<1, 1, 0, stream>>>(dflag);
    detect_kernel<<<256, 256, 0, stream>>>((const unsigned short*)box, 524288, dflag);

    // 2) convert inputs used as A-operands / epilogue scalars to internal bf16
    auto cvt = [&](const void* s, bf16* d, int n) {
        int g = (n + 2047) / 2048; if (g < 1) g = 1; if (g > 4096) g = 4096;
        cvt_kernel<<<g, 256, 0, stream>>>(s, d, n, dflag);
    };
    cvt(box, box_bf, 256 * 12544);
    cvt(nsp, nsp_bf, 256 * 1024);
    cvt(b_bh1, sb_bh1, 1024);  cvt(b_bh2, sb_bh2, 1024);
    cvt(b_om,  sb_om,  1024);  cvt(b_hm,  sb_hm,  1024);
    cvt(b_a1,  sb_a1,  2048);  cvt(b_a2,  sb_a2,  1024);
    cvt(W_a3,  sw_a3,  1024);  cvt(b_a3,  sb_a3,  1);
    cvt(scores, sscore, 256);

    // 3) W_a2 -> bf16 transposed (hot operand of pair_gemm, re-read 128x)
    transpose_any<<<dim3(1024 / 32, 2048 / 32), dim3(32, 8), 0, stream>>>(
        W_a2, Wt_a2, 2048, 1024, dflag);

    // GEMM helper: split-K partials + fused reduce epilogue
    // 4) enc = relu(relu(box@W_bh1+b)@W_bh2+b); nsW = nsp@W_sa
    gemm_p<<<dim3(16, 4, 8), 256, 0, stream>>>(box_bf, 12544, W_bh1, 0, 1024, part, 1024, 1568, dflag);
    reduce_k<true, true, false><<<dim3(256), 256, 0, stream>>>(part, 8, 262144, sb_bh1, t0, 1024);
    gemm_p<<<dim3(16, 4, 4), 256, 0, stream>>>(t0, 1024, W_bh2, 0, 1024, part, 1024, 256, dflag);
    reduce_k<true, true, false><<<dim3(256), 256, 0, stream>>>(part, 4, 262144, sb_bh2, enc, 1024);
    gemm_p<<<dim3(16, 4, 4), 256, 0, stream>>>(nsp_bf, 1024, W_sa, 0, 1024, part, 1024, 256, dflag);
    reduce_k<false, false, false><<<dim3(256), 256, 0, stream>>>(part, 4, 262144, nullptr, nsW, 1024);
    copy_rows<<<dim3(4, 64), 256, 0, stream>>>(enc, 1024, h_enc, 1024);

    for (int it = 0; it < 2; ++it) {
        copy_rows<<<dim3(4, 64), 256, 0, stream>>>(h_enc, 1024, hf, 2048);
        copy_rows<<<dim3(4, 64), 256, 0, stream>>>(nsp_bf, 1024, hf + 1024, 2048);
        copy_rows<<<dim3(4, 256), 256, 0, stream>>>(enc, 1024, of, 2048);
        copy_rows<<<dim3(4, 256), 256, 0, stream>>>(nsp_bf, 1024, of + 1024, 2048);
        // Hpart = hf @ W_a1[:2048,:], Opart = of @ W_a1[2048:,:]   (fp32 out)
        gemm_p<<<dim3(32, 1, 8), 256, 0, stream>>>(hf, 2048, W_a1, 0, 2048, part, 2048, 256, dflag);
        reduce_k<false, false, true><<<dim3(128), 256, 0, stream>>>(part, 8, 131072, nullptr, Hpart, 2048);
        gemm_p<<<dim3(32, 4, 4), 256, 0, stream>>>(of, 2048, W_a1, (size_t)2048 * 2048, 2048, part, 2048, 512, dflag);
        reduce_k<false, false, true><<<dim3(512), 256, 0, stream>>>(part, 4, 524288, nullptr, Opart, 2048);
        // adj = sigmoid(pair MLP)
        pair_gemm<<<dim3(8, 128), 256, 0, stream>>>(Hpart, Opart, sb_a1, Wt_a2, sb_a2, sw_a3, slots);
        adj_finalize<<<dim3(64), 256, 0, stream>>>(slots, sb_a3, adj);
        // obj_msg = relu(enc @ W_om + b)
        gemm_p<<<dim3(16, 4, 4), 256, 0, stream>>>(enc, 1024, W_om, 0, 1024, part, 1024, 256, dflag);
        reduce_k<true, true, false><<<dim3(256), 256, 0, stream>>>(part, 4, 262144, sb_om, obj_msg, 1024);
        // h_enc = [h_enc | agg_o] @ W_hu
        copy_rows<<<dim3(4, 64), 256, 0, stream>>>(h_enc, 1024, hu_in, 2048);
        agg_o_kernel<<<dim3(4, 64), 256, 0, stream>>>(adj, obj_msg, nsW, hu_in + 1024);
        gemm_p<<<dim3(16, 1, 16), 256, 0, stream>>>(hu_in, 2048, W_hu, 0, 1024, part, 1024, 128, dflag);
        reduce_k<false, false, false><<<dim3(64), 256, 0, stream>>>(part, 16, 65536, nullptr, h_enc, 1024);
        // hum_msg = relu(h_enc @ W_hm + b)
        gemm_p<<<dim3(16, 1, 16), 256, 0, stream>>>(h_enc, 1024, W_hm, 0, 1024, part, 1024, 64, dflag);
        reduce_k<true, true, false><<<dim3(64), 256, 0, stream>>>(part, 16, 65536, sb_hm, hum_msg, 1024);
        // enc = [enc | agg_h] @ W_ou
        copy_rows<<<dim3(4, 256), 256, 0, stream>>>(enc, 1024, ou_in, 2048);
        agg_h_kernel<<<dim3(4, 256), 256, 0, stream>>>(adj, hum_msg, nsW, ou_in + 1024);
        gemm_p<<<dim3(16, 4, 4), 256, 0, stream>>>(ou_in, 2048, W_ou, 0, 1024, part, 1024, 512, dflag);
        reduce_k<false, false, false><<<dim3(256), 256, 0, stream>>>(part, 4, 262144, nullptr, enc, 1024);
    }

    out_kernel<<<dim3(16320), 256, 0, stream>>>(
        h_enc, enc, nsp_bf, adj, sscore, labels, cmask, d_out, dflag);
}

// Round 3
// 1031.052 us; speedup vs baseline: 2.3290x; 1.1175x over previous
//
#include <hip/hip_runtime.h>

using bf16 = __bf16;
typedef __bf16 bf16x4 __attribute__((ext_vector_type(4)));
typedef __bf16 bf16x8 __attribute__((ext_vector_type(8)));
typedef float  f32x4  __attribute__((ext_vector_type(4)));

#define LDS_STRIDE 40  // pair_gemm LDS row stride
#define GST 40         // gemm_p LDS row stride (80 B -> 16B-aligned b128 reads)

// ---- dtype-dispatched access helpers (flag: 1 = inputs are fp32, 0 = bf16) --
__device__ __forceinline__ float ldf(const void* p, size_t i, int f32) {
    return f32 ? ((const float*)p)[i] : (float)((const bf16*)p)[i];
}
__device__ __forceinline__ bf16x8 ld8(const void* p, size_t i, int f32) {
    bf16x8 r;
    if (f32) {
        f32x4 a = *(const f32x4*)((const float*)p + i);
        f32x4 b = *(const f32x4*)((const float*)p + i + 4);
#pragma unroll
        for (int j = 0; j < 4; ++j) { r[j] = (bf16)a[j]; r[j + 4] = (bf16)b[j]; }
    } else {
        r = *(const bf16x8*)((const bf16*)p + i);
    }
    return r;
}
__device__ __forceinline__ void st1(void* p, size_t i, float v, int f32) {
    if (f32) ((float*)p)[i] = v;
    else     ((bf16*)p)[i] = (bf16)v;
}

// ---- detect: bf16 NaN/Inf bit patterns exist iff backing store is fp32 -----
__global__ void init_flag(int* __restrict__ dflag) { *dflag = 0; }

__global__ void detect_kernel(const unsigned short* __restrict__ p, int n,
                              int* __restrict__ dflag)
{
    const unsigned int* q = (const unsigned int*)p;
    const int nw = n >> 1;
    int hit = 0;
    for (int i = blockIdx.x * 256 + threadIdx.x; i < nw; i += gridDim.x * 256) {
        unsigned int w = q[i];
        if ((w & 0x7F80u) == 0x7F80u || (w & 0x7F800000u) == 0x7F800000u) hit = 1;
    }
    if (__any(hit) && (threadIdx.x & 63) == 0) atomicOr(dflag, 1);
}

// ---- convert an input array to internal bf16 (vectorized 8/thread) ---------
__global__ void cvt_kernel(const void* __restrict__ src, bf16* __restrict__ dst,
                           int n, const int* __restrict__ dflag)
{
    const int f32 = *dflag;
    const int stride = gridDim.x * 256;
    if ((n & 7) == 0) {
        const int nv = n >> 3;
        for (int i = blockIdx.x * 256 + threadIdx.x; i < nv; i += stride) {
            bf16x8 v = ld8(src, (size_t)i * 8, f32);
            *(bf16x8*)(dst + (size_t)i * 8) = v;
        }
    } else {
        for (int i = blockIdx.x * 256 + threadIdx.x; i < n; i += stride)
            dst[i] = (bf16)ldf(src, i, f32);
    }
}

// ---- transpose input weight (KxN) -> bf16 Wt (NxK) -------------------------
__global__ void transpose_any(const void* __restrict__ W, bf16* __restrict__ Wt,
                              int K, int N, const int* __restrict__ dflag)
{
    __shared__ bf16 tile[32][33];
    const int f32 = *dflag;
    const int n0 = blockIdx.x * 32, k0 = blockIdx.y * 32;
    const int tx = threadIdx.x, ty = threadIdx.y;  // (32, 8)
#pragma unroll
    for (int i = 0; i < 4; ++i)
        tile[ty + i * 8][tx] = (bf16)ldf(W, (size_t)(k0 + ty + i * 8) * N + n0 + tx, f32);
    __syncthreads();
#pragma unroll
    for (int i = 0; i < 4; ++i)
        Wt[(size_t)(n0 + ty + i * 8) * K + k0 + tx] = tile[tx][ty + i * 8];
}

// ---------------------------------------------------------------------------
// Split-K bf16 MFMA GEMM -> fp32 partials. A: internal bf16 MxK row-major.
// B: INPUT weight (dtype-dispatched), KxN row-major, element offset boff.
// Block 256 = 4 waves 2x2, wave tile 32x32, BK=32. blockIdx.z = K-split;
// each split writes its own fp32 slab part[z][M][N]. Reg-staged prefetch;
// B scatter uses group-XOR swizzle (kills the 16-way bank conflict).
// ---------------------------------------------------------------------------
__global__ __launch_bounds__(256)
void gemm_p(const bf16* __restrict__ A, int lda,
            const void* __restrict__ B, size_t boff, int ldb,
            float* __restrict__ part, int N, int Kc,
            const int* __restrict__ dflag)
{
    __shared__ bf16 As[64 * GST];
    __shared__ bf16 Bs[64 * GST];
    const int f32 = *dflag;
    const int t = threadIdx.x;
    const int l = t & 63;
    const int quad = l >> 4, lr = l & 15;
    const int w = t >> 6, wm = w >> 1, wn = w & 1;
    const int mBlock = blockIdx.y * 64, nBlock = blockIdx.x * 64;
    const int ar = t >> 2, ac = (t & 3) * 8;      // A-stage coords
    const int kr = t >> 3, nc = (t & 7) * 8;      // B-stage coords
    const int kBeg = blockIdx.z * Kc;
    const int nIter = Kc >> 5;

    f32x4 acc[2][2] = {};

    // preload tile 0 into registers
    bf16x8 avr = *(const bf16x8*)(A + (size_t)(mBlock + ar) * lda + kBeg + ac);
    bf16x8 bvr = ld8(B, boff + (size_t)(kBeg + kr) * ldb + nBlock + nc, f32);

    for (int it = 0; it < nIter; ++it) {
        // stage current tile (B scatter with group-XOR swizzle)
        *(bf16x8*)&As[ar * GST + ac] = avr;
#pragma unroll
        for (int j = 0; j < 8; ++j) {
            int wr = nc + j;
            Bs[wr * GST + (kr ^ (((wr >> 3) & 3) << 3))] = bvr[j];
        }
        __syncthreads();
        // prefetch next tile (latency hides under frag reads + MFMA)
        if (it + 1 < nIter) {
            int k0 = kBeg + (it + 1) * 32;
            avr = *(const bf16x8*)(A + (size_t)(mBlock + ar) * lda + k0 + ac);
            bvr = ld8(B, boff + (size_t)(k0 + kr) * ldb + nBlock + nc, f32);
        }
        bf16x8 af[2], bfr[2];
#pragma unroll
        for (int mi = 0; mi < 2; ++mi)
            af[mi] = *(const bf16x8*)&As[(wm * 32 + mi * 16 + lr) * GST + quad * 8];
#pragma unroll
        for (int nj = 0; nj < 2; ++nj) {
            int row = wn * 32 + nj * 16 + lr;
            bfr[nj] = *(const bf16x8*)&Bs[row * GST + ((quad * 8) ^ (((row >> 3) & 3) << 3))];
        }
#pragma unroll
        for (int mi = 0; mi < 2; ++mi)
#pragma unroll
            for (int nj = 0; nj < 2; ++nj)
                acc[mi][nj] = __builtin_amdgcn_mfma_f32_16x16x32_bf16(
                    af[mi], bfr[nj], acc[mi][nj], 0, 0, 0);
        __syncthreads();
    }

    float* outp = part + (size_t)blockIdx.z * ((size_t)gridDim.y * 64 * N);
#pragma unroll
    for (int mi = 0; mi < 2; ++mi)
#pragma unroll
        for (int nj = 0; nj < 2; ++nj) {
            int col = nBlock + wn * 32 + nj * 16 + lr;
#pragma unroll
            for (int rr = 0; rr < 4; ++rr) {
                int row = mBlock + wm * 32 + mi * 16 + quad * 4 + rr;
                outp[(size_t)row * N + col] = acc[mi][nj][rr];
            }
        }
}

// ---- reduce split-K partials, apply bias/relu, write bf16 or fp32 ----------
template<bool RELU, bool BIAS, bool F32OUT>
__global__ void reduce_k(const float* __restrict__ part, int S, int total,
                         const bf16* __restrict__ bias, void* __restrict__ out, int N)
{
    int base = (blockIdx.x * 256 + threadIdx.x) * 4;
    if (base >= total) return;
    f32x4 s = *(const f32x4*)(part + base);
    for (int z = 1; z < S; ++z) {
        f32x4 v = *(const f32x4*)(part + (size_t)z * total + base);
        s[0] += v[0]; s[1] += v[1]; s[2] += v[2]; s[3] += v[3];
    }
    int col = base % N;
#pragma unroll
    for (int j = 0; j < 4; ++j) {
        float v = s[j];
        if (BIAS) v += (float)bias[col + j];
        if (RELU) v = fmaxf(v, 0.f);
        if (F32OUT) ((float*)out)[base + j] = v;
        else        ((bf16*)out)[base + j] = (bf16)v;
    }
}

// ---- A_bf[p=(h,n), k] = bf16(relu(Hb[h,k] + Op[n,k])), Hb has b_a1 folded --
__global__ void build_pairA(const float* __restrict__ Hb, const float* __restrict__ Op,
                            bf16* __restrict__ A)
{
    const int n = blockIdx.x;        // 256
    const int h = blockIdx.y;        // 64
    const int k = threadIdx.x * 8;   // 256 threads x 8 = 2048
    const float* hp = Hb + (size_t)h * 2048 + k;
    const float* op = Op + (size_t)n * 2048 + k;
    f32x4 h0 = *(const f32x4*)hp, h1 = *(const f32x4*)(hp + 4);
    f32x4 o0 = *(const f32x4*)op, o1 = *(const f32x4*)(op + 4);
    bf16x8 r;
#pragma unroll
    for (int j = 0; j < 4; ++j) {
        r[j]     = (bf16)fmaxf(h0[j] + o0[j], 0.f);
        r[j + 4] = (bf16)fmaxf(h1[j] + o1[j], 0.f);
    }
    *(bf16x8*)(A + ((size_t)h * 256 + n) * 2048 + k) = r;
}

// ---------------------------------------------------------------------------
// Pure-GEMM pair MLP: A_bf (16384x2048 bf16) vs Wt_a2 (1024x2048 bf16), both
// K-major. Reg-prefetch double-buffer; epilogue folds relu(.+b_a2).W_a3 into
// per-row partials -> slots[p*16 + nb*2 + wn] (deterministic, no atomics).
// Grid (8 nb, 128 mb); block 256 = 4 waves 2x2, wave tile 64x64.
// ---------------------------------------------------------------------------
__global__ __launch_bounds__(256)
void pair_gemm(const bf16* __restrict__ Apg, const bf16* __restrict__ Wt_a2,
               const bf16* __restrict__ b_a2, const bf16* __restrict__ w_a3,
               float* __restrict__ slots)
{
    __shared__ bf16 As[128 * LDS_STRIDE];
    __shared__ bf16 Bs[128 * LDS_STRIDE];
    const int t = threadIdx.x;
    const int l = t & 63, w = t >> 6;
    const int quad = l >> 4, lr = l & 15;
    const int wm = w >> 1, wn = w & 1;
    const int nb = blockIdx.x, mb = blockIdx.y;
    const int p0 = mb * 128;
    const int ar = t >> 1, ac0 = (t & 1) * 16;   // 2 threads/row x 16 elems

    const bf16* Ap = Apg + (size_t)(p0 + ar) * 2048 + ac0;
    const bf16* Bp = Wt_a2 + (size_t)(nb * 128 + ar) * 2048 + ac0;

    f32x4 acc[4][4] = {};

    bf16x8 a0 = *(const bf16x8*)(Ap);
    bf16x8 a1 = *(const bf16x8*)(Ap + 8);
    bf16x8 b0 = *(const bf16x8*)(Bp);
    bf16x8 b1 = *(const bf16x8*)(Bp + 8);

    for (int k0 = 0; k0 < 2048; k0 += 32) {
        *(bf16x8*)&As[ar * LDS_STRIDE + ac0]     = a0;
        *(bf16x8*)&As[ar * LDS_STRIDE + ac0 + 8] = a1;
        *(bf16x8*)&Bs[ar * LDS_STRIDE + ac0]     = b0;
        *(bf16x8*)&Bs[ar * LDS_STRIDE + ac0 + 8] = b1;
        __syncthreads();
        if (k0 + 32 < 2048) {
            a0 = *(const bf16x8*)(Ap + k0 + 32);
            a1 = *(const bf16x8*)(Ap + k0 + 40);
            b0 = *(const bf16x8*)(Bp + k0 + 32);
            b1 = *(const bf16x8*)(Bp + k0 + 40);
        }

        bf16x8 af[4], bfr[4];
#pragma unroll
        for (int mi = 0; mi < 4; ++mi)
            af[mi] = *(const bf16x8*)&As[(wm * 64 + mi * 16 + lr) * LDS_STRIDE + quad * 8];
#pragma unroll
        for (int nj = 0; nj < 4; ++nj)
            bfr[nj] = *(const bf16x8*)&Bs[(wn * 64 + nj * 16 + lr) * LDS_STRIDE + quad * 8];
#pragma unroll
        for (int mi = 0; mi < 4; ++mi)
#pragma unroll
            for (int nj = 0; nj < 4; ++nj)
                acc[mi][nj] = __builtin_amdgcn_mfma_f32_16x16x32_bf16(
                    af[mi], bfr[nj], acc[mi][nj], 0, 0, 0);
        __syncthreads();
    }

    float w3v[4], b2v[4];
#pragma unroll
    for (int nj = 0; nj < 4; ++nj) {
        int col = nb * 128 + wn * 64 + nj * 16 + lr;
        w3v[nj] = (float)w_a3[col];
        b2v[nj] = (float)b_a2[col];
    }
#pragma unroll
    for (int mi = 0; mi < 4; ++mi) {
        f32x4 rs = {0.f, 0.f, 0.f, 0.f};
#pragma unroll
        for (int nj = 0; nj < 4; ++nj)
#pragma unroll
            for (int rr = 0; rr < 4; ++rr)
                rs[rr] += fmaxf(acc[mi][nj][rr] + b2v[nj], 0.f) * w3v[nj];
#pragma unroll
        for (int off = 1; off < 16; off <<= 1) {
            rs[0] += __shfl_xor(rs[0], off);
            rs[1] += __shfl_xor(rs[1], off);
            rs[2] += __shfl_xor(rs[2], off);
            rs[3] += __shfl_xor(rs[3], off);
        }
        if (lr == 0) {
            int p = p0 + wm * 64 + mi * 16 + quad * 4;
            int slot = nb * 2 + wn;
            slots[(size_t)(p + 0) * 16 + slot] = rs[0];
            slots[(size_t)(p + 1) * 16 + slot] = rs[1];
            slots[(size_t)(p + 2) * 16 + slot] = rs[2];
            slots[(size_t)(p + 3) * 16 + slot] = rs[3];
        }
    }
}

__global__ void adj_finalize(const float* __restrict__ slots,
                             const bf16* __restrict__ b_a3, float* __restrict__ adj)
{
    int i = blockIdx.x * 256 + threadIdx.x;
    float s = (float)b_a3[0];
#pragma unroll
    for (int k = 0; k < 16; ++k) s += slots[(size_t)i * 16 + k];
    adj[i] = 1.f / (1.f + expf(-s));
}

__global__ void copy_rows(const bf16* __restrict__ src, int lds_,
                          bf16* __restrict__ dst, int ldd)
{
    int c = blockIdx.x * 256 + threadIdx.x;  // 1024 cols
    int r = blockIdx.y;
    dst[(size_t)r * ldd + c] = src[(size_t)r * lds_ + c];
}

// agg_o[h,e] = sum_n adj[h,n]*obj_msg[n,e]*(nsW[h,e]-nsW[n,e]); out stride 2048
__global__ void agg_o_kernel(const float* __restrict__ adj, const bf16* __restrict__ obj_msg,
                             const bf16* __restrict__ nsW, bf16* __restrict__ out)
{
    int e = blockIdx.x * 256 + threadIdx.x;
    int h = blockIdx.y;
    float nh = (float)nsW[h * 1024 + e];
    float s = 0.f;
    for (int n = 0; n < 256; ++n) {
        float a  = adj[h * 256 + n];
        float om = (float)obj_msg[n * 1024 + e];
        float nw = (float)nsW[n * 1024 + e];
        s += a * om * (nh - nw);
    }
    out[(size_t)h * 2048 + e] = (bf16)s;
}

// agg_h[n,e] = sum_h adj[h,n]*hum_msg[h,e]*(nsW[n,e]-nsW[h,e]); out stride 2048
__global__ void agg_h_kernel(const float* __restrict__ adj, const bf16* __restrict__ hum_msg,
                             const bf16* __restrict__ nsW, bf16* __restrict__ out)
{
    int e = blockIdx.x * 256 + threadIdx.x;
    int n = blockIdx.y;
    float nn = (float)nsW[n * 1024 + e];
    float s = 0.f;
    for (int h = 0; h < 64; ++h) {
        float a  = adj[h * 256 + n];
        float hm = (float)hum_msg[h * 1024 + e];
        float nw = (float)nsW[h * 1024 + e];
        s += a * hm * (nn - nw);
    }
    out[(size_t)n * 2048 + e] = (bf16)s;
}

// Output row r=(x,y): [h_enc[x] | nsp[x] | enc[y] | nsp[y] | prior(117)]
__global__ void out_kernel(const bf16* __restrict__ h_enc, const bf16* __restrict__ enc,
                           const bf16* __restrict__ nsp_bf, const float* __restrict__ adj,
                           const bf16* __restrict__ scores_bf, const int* __restrict__ labels,
                           const int* __restrict__ cmask, void* __restrict__ out,
                           const int* __restrict__ dflag)
{
    const int f32 = *dflag;
    const int r = blockIdx.x;
    const int x = r / 255;
    const int tt = r % 255;
    const int y = tt + (tt >= x ? 1 : 0);
    const size_t rbase = (size_t)r * 4213;
    const bf16* seg[4] = { h_enc + x * 1024, nsp_bf + x * 1024, enc + y * 1024, nsp_bf + y * 1024 };
    const int t = threadIdx.x;
#pragma unroll
    for (int k = 0; k < 4; ++k) {
        int ci = t + k * 256;            // 4-element chunk id
        int sidx = ci >> 8;
        int off = (ci & 255) * 4;
        bf16x4 v = *(const bf16x4*)(seg[sidx] + off);
        size_t d = rbase + sidx * 1024 + off;
        st1(out, d + 0, (float)v[0], f32);
        st1(out, d + 1, (float)v[1], f32);
        st1(out, d + 2, (float)v[2], f32);
        st1(out, d + 3, (float)v[3], f32);
    }
    if (t < 117) {
        float sx = (float)scores_bf[x], sy = (float)scores_bf[y];
        float lx = 8.3f / (1.f + expf(12.f - 10.f * sx));
        float ly = 8.3f / (1.f + expf(12.f - 10.f * sy));
        float a = adj[x * 256 + y];
        float m = cmask[labels[y] * 117 + t] ? 1.f : 0.f;
        st1(out, rbase + 4096 + t, a * lx * ly * m, f32);
    }
}

// ---------------------------------------------------------------------------
extern "C" void kernel_launch(void* const* d_in, const int* in_sizes, int n_in,
                              void* d_out, int out_size, void* d_ws, size_t ws_size,
                              hipStream_t stream)
{
    (void)in_sizes; (void)n_in; (void)out_size; (void)ws_size;
    const void* box    = d_in[0];
    const void* nsp    = d_in[1];
    const void* scores = d_in[2];
    const int*  labels = (const int*)d_in[3];
    const int*  cmask  = (const int*)d_in[4];
    const void* W_bh1 = d_in[5],  *b_bh1 = d_in[6];
    const void* W_bh2 = d_in[7],  *b_bh2 = d_in[8];
    const void* W_sa  = d_in[9];
    const void* W_a1  = d_in[10], *b_a1  = d_in[11];
    const void* W_a2  = d_in[12], *b_a2  = d_in[13];
    const void* W_a3  = d_in[14], *b_a3  = d_in[15];
    const void* W_hm  = d_in[16], *b_hm  = d_in[17];
    const void* W_om  = d_in[18], *b_om  = d_in[19];
    const void* W_hu  = d_in[20];
    const void* W_ou  = d_in[21];

    char* ws = (char*)d_ws;
    size_t off = 0;
    auto alloc = [&](size_t bytes) -> void* {
        off = (off + 255) & ~(size_t)255;
        void* p = ws + off;
        off += bytes;
        return p;
    };
    int*  dflag   = (int*)alloc(4);
    bf16* box_bf  = (bf16*)alloc((size_t)256 * 12544 * 2);
    bf16* nsp_bf  = (bf16*)alloc((size_t)256 * 1024 * 2);
    bf16* Wt_a2   = (bf16*)alloc((size_t)1024 * 2048 * 2);
    bf16* smalls  = (bf16*)alloc((size_t)8464 * 2);
    bf16* sb_bh1 = smalls,        *sb_bh2 = smalls + 1024;
    bf16* sb_om  = smalls + 2048, *sb_hm  = smalls + 3072;
    bf16* sb_a1  = smalls + 4096, *sb_a2  = smalls + 6144;
    bf16* sw_a3  = smalls + 7168, *sb_a3  = smalls + 8192;
    bf16* sscore = smalls + 8208;
    bf16* t0      = (bf16*)alloc((size_t)256 * 1024 * 2);
    bf16* enc     = (bf16*)alloc((size_t)256 * 1024 * 2);
    bf16* nsW     = (bf16*)alloc((size_t)256 * 1024 * 2);
    bf16* h_enc   = (bf16*)alloc((size_t)64 * 1024 * 2);
    bf16* hf      = (bf16*)alloc((size_t)64 * 2048 * 2);
    bf16* of      = (bf16*)alloc((size_t)256 * 2048 * 2);
    float* Hpart  = (float*)alloc((size_t)64 * 2048 * 4);
    float* Opart  = (float*)alloc((size_t)256 * 2048 * 4);
    float* slots  = (float*)alloc((size_t)16384 * 16 * 4);
    float* adj    = (float*)alloc((size_t)16384 * 4);
    bf16* obj_msg = (bf16*)alloc((size_t)256 * 1024 * 2);
    bf16* hu_in   = (bf16*)alloc((size_t)64 * 2048 * 2);
    bf16* hum_msg = (bf16*)alloc((size_t)64 * 1024 * 2);
    bf16* ou_in   = (bf16*)alloc((size_t)256 * 2048 * 2);
    float* part   = (float*)alloc((size_t)2097152 * 4);        // split-K partials (8 MB)
    bf16* A_bf    = (bf16*)alloc((size_t)16384 * 2048 * 2);    // pair activations (64 MB)

    // 1) dtype probe
    init_flag<<<1, 1, 0, stream>>>(dflag);
    detect_kernel<<<256, 256, 0, stream>>>((const unsigned short*)box, 524288, dflag);

    // 2) convert inputs used as A-operands / epilogue scalars to internal bf16
    auto cvt = [&](const void* s, bf16* d, int n) {
        int g = (n + 2047) / 2048; if (g < 1) g = 1; if (g > 4096) g = 4096;
        cvt_kernel<<<g, 256, 0, stream>>>(s, d, n, dflag);
    };
    cvt(box, box_bf, 256 * 12544);
    cvt(nsp, nsp_bf, 256 * 1024);
    cvt(b_bh1, sb_bh1, 1024);  cvt(b_bh2, sb_bh2, 1024);
    cvt(b_om,  sb_om,  1024);  cvt(b_hm,  sb_hm,  1024);
    cvt(b_a1,  sb_a1,  2048);  cvt(b_a2,  sb_a2,  1024);
    cvt(W_a3,  sw_a3,  1024);  cvt(b_a3,  sb_a3,  1);
    cvt(scores, sscore, 256);

    // 3) W_a2 -> bf16 transposed (hot operand of pair_gemm, re-read 128x)
    transpose_any<<<dim3(1024 / 32, 2048 / 32), dim3(32, 8), 0, stream>>>(
        W_a2, Wt_a2, 2048, 1024, dflag);

    // 4) enc = relu(relu(box@W_bh1+b)@W_bh2+b); nsW = nsp@W_sa
    gemm_p<<<dim3(16, 4, 8), 256, 0, stream>>>(box_bf, 12544, W_bh1, 0, 1024, part, 1024, 1568, dflag);
    reduce_k<true, true, false><<<dim3(256), 256, 0, stream>>>(part, 8, 262144, sb_bh1, t0, 1024);
    gemm_p<<<dim3(16, 4, 4), 256, 0, stream>>>(t0, 1024, W_bh2, 0, 1024, part, 1024, 256, dflag);
    reduce_k<true, true, false><<<dim3(256), 256, 0, stream>>>(part, 4, 262144, sb_bh2, enc, 1024);
    gemm_p<<<dim3(16, 4, 4), 256, 0, stream>>>(nsp_bf, 1024, W_sa, 0, 1024, part, 1024, 256, dflag);
    reduce_k<false, false, false><<<dim3(256), 256, 0, stream>>>(part, 4, 262144, nullptr, nsW, 1024);
    copy_rows<<<dim3(4, 64), 256, 0, stream>>>(enc, 1024, h_enc, 1024);

    for (int it = 0; it < 2; ++it) {
        copy_rows<<<dim3(4, 64), 256, 0, stream>>>(h_enc, 1024, hf, 2048);
        copy_rows<<<dim3(4, 64), 256, 0, stream>>>(nsp_bf, 1024, hf + 1024, 2048);
        copy_rows<<<dim3(4, 256), 256, 0, stream>>>(enc, 1024, of, 2048);
        copy_rows<<<dim3(4, 256), 256, 0, stream>>>(nsp_bf, 1024, of + 1024, 2048);
        // Hpart = hf @ W_a1[:2048,:] (+ b_a1 folded), Opart = of @ W_a1[2048:,:]
        gemm_p<<<dim3(32, 1, 8), 256, 0, stream>>>(hf, 2048, W_a1, 0, 2048, part, 2048, 256, dflag);
        reduce_k<false, true, true><<<dim3(128), 256, 0, stream>>>(part, 8, 131072, sb_a1, Hpart, 2048);
        gemm_p<<<dim3(32, 4, 4), 256, 0, stream>>>(of, 2048, W_a1, (size_t)2048 * 2048, 2048, part, 2048, 512, dflag);
        reduce_k<false, false, true><<<dim3(512), 256, 0, stream>>>(part, 4, 524288, nullptr, Opart, 2048);
        // A_bf[p,k] = bf16(relu(Hpart[h,k] + Opart[n,k]))  (bias already in Hpart)
        build_pairA<<<dim3(256, 64), 256, 0, stream>>>(Hpart, Opart, A_bf);
        // adj = sigmoid(pair MLP)  -- pure bf16 GEMM now
        pair_gemm<<<dim3(8, 128), 256, 0, stream>>>(A_bf, Wt_a2, sb_a2, sw_a3, slots);
        adj_finalize<<<dim3(64), 256, 0, stream>>>(slots, sb_a3, adj);
        // obj_msg = relu(enc @ W_om + b)
        gemm_p<<<dim3(16, 4, 4), 256, 0, stream>>>(enc, 1024, W_om, 0, 1024, part, 1024, 256, dflag);
        reduce_k<true, true, false><<<dim3(256), 256, 0, stream>>>(part, 4, 262144, sb_om, obj_msg, 1024);
        // h_enc = [h_enc | agg_o] @ W_hu
        copy_rows<<<dim3(4, 64), 256, 0, stream>>>(h_enc, 1024, hu_in, 2048);
        agg_o_kernel<<<dim3(4, 64), 256, 0, stream>>>(adj, obj_msg, nsW, hu_in + 1024);
        gemm_p<<<dim3(16, 1, 16), 256, 0, stream>>>(hu_in, 2048, W_hu, 0, 1024, part, 1024, 128, dflag);
        reduce_k<false, false, false><<<dim3(64), 256, 0, stream>>>(part, 16, 65536, nullptr, h_enc, 1024);
        // hum_msg = relu(h_enc @ W_hm + b)
        gemm_p<<<dim3(16, 1, 16), 256, 0, stream>>>(h_enc, 1024, W_hm, 0, 1024, part, 1024, 64, dflag);
        reduce_k<true, true, false><<<dim3(64), 256, 0, stream>>>(part, 16, 65536, sb_hm, hum_msg, 1024);
        // enc = [enc | agg_h] @ W_ou
        copy_rows<<<dim3(4, 256), 256, 0, stream>>>(enc, 1024, ou_in, 2048);
        agg_h_kernel<<<dim3(4, 256), 256, 0, stream>>>(adj, hum_msg, nsW, ou_in + 1024);
        gemm_p<<<dim3(16, 4, 4), 256, 0, stream>>>(ou_in, 2048, W_ou, 0, 1024, part, 1024, 512, dflag);
        reduce_k<false, false, false><<<dim3(256), 256, 0, stream>>>(part, 4, 262144, nullptr, enc, 1024);
    }

    out_kernel<<<dim3(16320), 256, 0, stream>>>(
        h_enc, enc, nsp_bf, adj, sscore, labels, cmask, d_out, dflag);
}

// Round 4
// 991.343 us; speedup vs baseline: 2.4223x; 1.0401x over previous
//
#include <hip/hip_runtime.h>

using bf16 = __bf16;
typedef __bf16 bf16x4 __attribute__((ext_vector_type(4)));
typedef __bf16 bf16x8 __attribute__((ext_vector_type(8)));
typedef float  f32x4  __attribute__((ext_vector_type(4)));

#define GST 40  // gemm_p LDS row stride (80 B -> 16B-aligned b128 reads)

// ---- dtype-dispatched access helpers (flag: 1 = inputs are fp32, 0 = bf16) --
__device__ __forceinline__ float ldf(const void* p, size_t i, int f32) {
    return f32 ? ((const float*)p)[i] : (float)((const bf16*)p)[i];
}
__device__ __forceinline__ bf16x8 ld8(const void* p, size_t i, int f32) {
    bf16x8 r;
    if (f32) {
        f32x4 a = *(const f32x4*)((const float*)p + i);
        f32x4 b = *(const f32x4*)((const float*)p + i + 4);
#pragma unroll
        for (int j = 0; j < 4; ++j) { r[j] = (bf16)a[j]; r[j + 4] = (bf16)b[j]; }
    } else {
        r = *(const bf16x8*)((const bf16*)p + i);
    }
    return r;
}
__device__ __forceinline__ void st1(void* p, size_t i, float v, int f32) {
    if (f32) ((float*)p)[i] = v;
    else     ((bf16*)p)[i] = (bf16)v;
}

// ---- async global->LDS, 16B per lane (dest = wave-uniform base + lane*16) --
__device__ __forceinline__ void gl_lds16(const bf16* g, bf16* l) {
    __builtin_amdgcn_global_load_lds(
        (const __attribute__((address_space(1))) void*)g,
        (__attribute__((address_space(3))) void*)l, 16, 0, 0);
}

// ---- detect: bf16 NaN/Inf bit patterns exist iff backing store is fp32 -----
__global__ void init_flag(int* __restrict__ dflag) { *dflag = 0; }

__global__ void detect_kernel(const unsigned short* __restrict__ p, int n,
                              int* __restrict__ dflag)
{
    const unsigned int* q = (const unsigned int*)p;
    const int nw = n >> 1;
    int hit = 0;
    for (int i = blockIdx.x * 256 + threadIdx.x; i < nw; i += gridDim.x * 256) {
        unsigned int w = q[i];
        if ((w & 0x7F80u) == 0x7F80u || (w & 0x7F800000u) == 0x7F800000u) hit = 1;
    }
    if (__any(hit) && (threadIdx.x & 63) == 0) atomicOr(dflag, 1);
}

// ---- convert an input array to internal bf16 (vectorized 8/thread) ---------
__global__ void cvt_kernel(const void* __restrict__ src, bf16* __restrict__ dst,
                           int n, const int* __restrict__ dflag)
{
    const int f32 = *dflag;
    const int stride = gridDim.x * 256;
    const int nv = n >> 3;
    for (int i = blockIdx.x * 256 + threadIdx.x; i < nv; i += stride) {
        bf16x8 v = ld8(src, (size_t)i * 8, f32);
        *(bf16x8*)(dst + (size_t)i * 8) = v;
    }
}

// ---- one launch converts all small epilogue arrays into the smalls block ---
// layout: [0:1024)=b_bh1 [1024)=b_bh2 [2048)=b_om [3072)=b_hm [4096,6144)=b_a1
//         [6144)=b_a2 [7168)=w_a3 [8192]=b_a3 [8208,8464)=scores
__global__ void cvt_smalls(const void* b_bh1, const void* b_bh2, const void* b_om,
                           const void* b_hm, const void* b_a1, const void* b_a2,
                           const void* w_a3, const void* b_a3, const void* scores,
                           bf16* __restrict__ smalls, const int* __restrict__ dflag)
{
    const int f32 = *dflag;
    int i = blockIdx.x * 256 + threadIdx.x;
    const void* s; int off;
    if      (i < 1024) { s = b_bh1; off = 0;    }
    else if (i < 2048) { s = b_bh2; off = 1024; }
    else if (i < 3072) { s = b_om;  off = 2048; }
    else if (i < 4096) { s = b_hm;  off = 3072; }
    else if (i < 6144) { s = b_a1;  off = 4096; }
    else if (i < 7168) { s = b_a2;  off = 6144; }
    else if (i < 8192) { s = w_a3;  off = 7168; }
    else if (i < 8193) { s = b_a3;  off = 8192; }
    else if (i >= 8208 && i < 8464) { s = scores; off = 8208; }
    else return;
    smalls[i] = (bf16)ldf(s, i - off, f32);
}

// ---- transpose input weight (KxN) -> bf16 Wt (NxK) -------------------------
__global__ void transpose_any(const void* __restrict__ W, bf16* __restrict__ Wt,
                              int K, int N, const int* __restrict__ dflag)
{
    __shared__ bf16 tile[32][33];
    const int f32 = *dflag;
    const int n0 = blockIdx.x * 32, k0 = blockIdx.y * 32;
    const int tx = threadIdx.x, ty = threadIdx.y;  // (32, 8)
#pragma unroll
    for (int i = 0; i < 4; ++i)
        tile[ty + i * 8][tx] = (bf16)ldf(W, (size_t)(k0 + ty + i * 8) * N + n0 + tx, f32);
    __syncthreads();
#pragma unroll
    for (int i = 0; i < 4; ++i)
        Wt[(size_t)(n0 + ty + i * 8) * K + k0 + tx] = tile[tx][ty + i * 8];
}

// ---------------------------------------------------------------------------
// Split-K bf16 MFMA GEMM -> fp32 partials (unchanged; B is dtype-dispatched).
// ---------------------------------------------------------------------------
__global__ __launch_bounds__(256)
void gemm_p(const bf16* __restrict__ A, int lda,
            const void* __restrict__ B, size_t boff, int ldb,
            float* __restrict__ part, int N, int Kc,
            const int* __restrict__ dflag)
{
    __shared__ bf16 As[64 * GST];
    __shared__ bf16 Bs[64 * GST];
    const int f32 = *dflag;
    const int t = threadIdx.x;
    const int l = t & 63;
    const int quad = l >> 4, lr = l & 15;
    const int w = t >> 6, wm = w >> 1, wn = w & 1;
    const int mBlock = blockIdx.y * 64, nBlock = blockIdx.x * 64;
    const int ar = t >> 2, ac = (t & 3) * 8;      // A-stage coords
    const int kr = t >> 3, nc = (t & 7) * 8;      // B-stage coords
    const int kBeg = blockIdx.z * Kc;
    const int nIter = Kc >> 5;

    f32x4 acc[2][2] = {};

    bf16x8 avr = *(const bf16x8*)(A + (size_t)(mBlock + ar) * lda + kBeg + ac);
    bf16x8 bvr = ld8(B, boff + (size_t)(kBeg + kr) * ldb + nBlock + nc, f32);

    for (int it = 0; it < nIter; ++it) {
        *(bf16x8*)&As[ar * GST + ac] = avr;
#pragma unroll
        for (int j = 0; j < 8; ++j) {
            int wr = nc + j;
            Bs[wr * GST + (kr ^ (((wr >> 3) & 3) << 3))] = bvr[j];
        }
        __syncthreads();
        if (it + 1 < nIter) {
            int k0 = kBeg + (it + 1) * 32;
            avr = *(const bf16x8*)(A + (size_t)(mBlock + ar) * lda + k0 + ac);
            bvr = ld8(B, boff + (size_t)(k0 + kr) * ldb + nBlock + nc, f32);
        }
        bf16x8 af[2], bfr[2];
#pragma unroll
        for (int mi = 0; mi < 2; ++mi)
            af[mi] = *(const bf16x8*)&As[(wm * 32 + mi * 16 + lr) * GST + quad * 8];
#pragma unroll
        for (int nj = 0; nj < 2; ++nj) {
            int row = wn * 32 + nj * 16 + lr;
            bfr[nj] = *(const bf16x8*)&Bs[row * GST + ((quad * 8) ^ (((row >> 3) & 3) << 3))];
        }
#pragma unroll
        for (int mi = 0; mi < 2; ++mi)
#pragma unroll
            for (int nj = 0; nj < 2; ++nj)
                acc[mi][nj] = __builtin_amdgcn_mfma_f32_16x16x32_bf16(
                    af[mi], bfr[nj], acc[mi][nj], 0, 0, 0);
        __syncthreads();
    }

    float* outp = part + (size_t)blockIdx.z * ((size_t)gridDim.y * 64 * N);
#pragma unroll
    for (int mi = 0; mi < 2; ++mi)
#pragma unroll
        for (int nj = 0; nj < 2; ++nj) {
            int col = nBlock + wn * 32 + nj * 16 + lr;
#pragma unroll
            for (int rr = 0; rr < 4; ++rr) {
                int row = mBlock + wm * 32 + mi * 16 + quad * 4 + rr;
                outp[(size_t)row * N + col] = acc[mi][nj][rr];
            }
        }
}

// ---- reduce split-K partials, apply bias/relu, write bf16 or fp32 ----------
template<bool RELU, bool BIAS, bool F32OUT>
__global__ void reduce_k(const float* __restrict__ part, int S, int total,
                         const bf16* __restrict__ bias, void* __restrict__ out, int N)
{
    int base = (blockIdx.x * 256 + threadIdx.x) * 4;
    if (base >= total) return;
    f32x4 s = *(const f32x4*)(part + base);
    for (int z = 1; z < S; ++z) {
        f32x4 v = *(const f32x4*)(part + (size_t)z * total + base);
        s[0] += v[0]; s[1] += v[1]; s[2] += v[2]; s[3] += v[3];
    }
    int col = base % N;
#pragma unroll
    for (int j = 0; j < 4; ++j) {
        float v = s[j];
        if (BIAS) v += (float)bias[col + j];
        if (RELU) v = fmaxf(v, 0.f);
        if (F32OUT) ((float*)out)[base + j] = v;
        else        ((bf16*)out)[base + j] = (bf16)v;
    }
}

// ---- A_bf[p=(h,n), k] = bf16(relu(Hb[h,k] + Op[n,k])), Hb has b_a1 folded --
__global__ void build_pairA(const float* __restrict__ Hb, const float* __restrict__ Op,
                            bf16* __restrict__ A)
{
    const int n = blockIdx.x;        // 256
    const int h = blockIdx.y;        // 64
    const int k = threadIdx.x * 8;   // 256 threads x 8 = 2048
    const float* hp = Hb + (size_t)h * 2048 + k;
    const float* op = Op + (size_t)n * 2048 + k;
    f32x4 h0 = *(const f32x4*)hp, h1 = *(const f32x4*)(hp + 4);
    f32x4 o0 = *(const f32x4*)op, o1 = *(const f32x4*)(op + 4);
    bf16x8 r;
#pragma unroll
    for (int j = 0; j < 4; ++j) {
        r[j]     = (bf16)fmaxf(h0[j] + o0[j], 0.f);
        r[j + 4] = (bf16)fmaxf(h1[j] + o1[j], 0.f);
    }
    *(bf16x8*)(A + ((size_t)h * 256 + n) * 2048 + k) = r;
}

// ---------------------------------------------------------------------------
// Pure-GEMM pair MLP, m97 structure: global_load_lds width-16 staging into
// LINEAR LDS [128][32], XOR swizzle applied on BOTH sides (inverse-swizzled
// global source chunk, swizzled ds_read slot) per the both-sides-or-neither
// rule. slot(row,q) = q ^ ((row>>1)&3) -> 2-way max bank aliasing (free).
// Grid (8 nb, 128 mb); block 256 = 4 waves 2x2, wave tile 64x64, BK=32.
// ---------------------------------------------------------------------------
__global__ __launch_bounds__(256)
void pair_gemm(const bf16* __restrict__ Apg, const bf16* __restrict__ Wt_a2,
               const bf16* __restrict__ b_a2, const bf16* __restrict__ w_a3,
               float* __restrict__ slots)
{
    __shared__ bf16 As[128 * 32];
    __shared__ bf16 Bs[128 * 32];
    const int t = threadIdx.x;
    const int l = t & 63, w = t >> 6;
    const int quad = l >> 4, lr = l & 15;
    const int wm = w >> 1, wn = w & 1;
    const int nb = blockIdx.x, mb = blockIdx.y;
    const int p0 = mb * 128;

    // gload geometry: lane l -> LDS bytes (w*1024 + l*16): row=w*16+l/4, slot=l&3
    const int grow = w * 16 + (l >> 2);
    const int slot = l & 3;
    const int csrc = slot ^ ((grow >> 1) & 3);   // inverse swizzle ((row+64)>>1)&3 == same
    const bf16* Asrc0 = Apg + (size_t)(p0 + grow) * 2048 + csrc * 8;
    const bf16* Asrc1 = Apg + (size_t)(p0 + 64 + grow) * 2048 + csrc * 8;
    const bf16* Bsrc0 = Wt_a2 + (size_t)(nb * 128 + grow) * 2048 + csrc * 8;
    const bf16* Bsrc1 = Wt_a2 + (size_t)(nb * 128 + 64 + grow) * 2048 + csrc * 8;
    bf16* AsW0 = As + w * 512;          // wave-uniform LDS bases
    bf16* AsW1 = As + 2048 + w * 512;
    bf16* BsW0 = Bs + w * 512;
    bf16* BsW1 = Bs + 2048 + w * 512;

    f32x4 acc[4][4] = {};

    for (int k0 = 0; k0 < 2048; k0 += 32) {
        gl_lds16(Asrc0 + k0, AsW0);
        gl_lds16(Asrc1 + k0, AsW1);
        gl_lds16(Bsrc0 + k0, BsW0);
        gl_lds16(Bsrc1 + k0, BsW1);
        __syncthreads();    // compiler drains vmcnt before s_barrier

        bf16x8 af[4], bfr[4];
#pragma unroll
        for (int mi = 0; mi < 4; ++mi) {
            int row = wm * 64 + mi * 16 + lr;
            int sl = quad ^ ((row >> 1) & 3);
            af[mi] = *(const bf16x8*)&As[row * 32 + sl * 8];
        }
#pragma unroll
        for (int nj = 0; nj < 4; ++nj) {
            int row = wn * 64 + nj * 16 + lr;
            int sl = quad ^ ((row >> 1) & 3);
            bfr[nj] = *(const bf16x8*)&Bs[row * 32 + sl * 8];
        }
#pragma unroll
        for (int mi = 0; mi < 4; ++mi)
#pragma unroll
            for (int nj = 0; nj < 4; ++nj)
                acc[mi][nj] = __builtin_amdgcn_mfma_f32_16x16x32_bf16(
                    af[mi], bfr[nj], acc[mi][nj], 0, 0, 0);
        __syncthreads();    // all reads done before next overwrite
    }

    float w3v[4], b2v[4];
#pragma unroll
    for (int nj = 0; nj < 4; ++nj) {
        int col = nb * 128 + wn * 64 + nj * 16 + lr;
        w3v[nj] = (float)w_a3[col];
        b2v[nj] = (float)b_a2[col];
    }
#pragma unroll
    for (int mi = 0; mi < 4; ++mi) {
        f32x4 rs = {0.f, 0.f, 0.f, 0.f};
#pragma unroll
        for (int nj = 0; nj < 4; ++nj)
#pragma unroll
            for (int rr = 0; rr < 4; ++rr)
                rs[rr] += fmaxf(acc[mi][nj][rr] + b2v[nj], 0.f) * w3v[nj];
#pragma unroll
        for (int off = 1; off < 16; off <<= 1) {
            rs[0] += __shfl_xor(rs[0], off);
            rs[1] += __shfl_xor(rs[1], off);
            rs[2] += __shfl_xor(rs[2], off);
            rs[3] += __shfl_xor(rs[3], off);
        }
        if (lr == 0) {
            int p = p0 + wm * 64 + mi * 16 + quad * 4;
            int slot2 = nb * 2 + wn;
            slots[(size_t)(p + 0) * 16 + slot2] = rs[0];
            slots[(size_t)(p + 1) * 16 + slot2] = rs[1];
            slots[(size_t)(p + 2) * 16 + slot2] = rs[2];
            slots[(size_t)(p + 3) * 16 + slot2] = rs[3];
        }
    }
}

__global__ void adj_finalize(const float* __restrict__ slots,
                             const bf16* __restrict__ b_a3, float* __restrict__ adj)
{
    int i = blockIdx.x * 256 + threadIdx.x;
    float s = (float)b_a3[0];
#pragma unroll
    for (int k = 0; k < 16; ++k) s += slots[(size_t)i * 16 + k];
    adj[i] = 1.f / (1.f + expf(-s));
}

__global__ void copy_rows(const bf16* __restrict__ src, int lds_,
                          bf16* __restrict__ dst, int ldd)
{
    int c = blockIdx.x * 256 + threadIdx.x;  // 1024 cols
    int r = blockIdx.y;
    dst[(size_t)r * ldd + c] = src[(size_t)r * lds_ + c];
}

// dst[r, 0:1024] = L[r]; dst[r, 1024:2048] = R[r]; dst stride 2048
__global__ void concat2(const bf16* __restrict__ L, const bf16* __restrict__ R,
                        bf16* __restrict__ dst)
{
    int c = blockIdx.x * 256 + threadIdx.x;   // 0..2047 (block-uniform branch)
    int r = blockIdx.y;
    dst[(size_t)r * 2048 + c] = (c < 1024) ? L[(size_t)r * 1024 + c]
                                           : R[(size_t)r * 1024 + (c - 1024)];
}

// fused: out[h,0:1024]=h_enc[h]; out[h,1024+e]=sum_n adj[h,n]*obj_msg[n,e]*(nsW[h,e]-nsW[n,e])
__global__ void agg_o_kernel(const float* __restrict__ adj, const bf16* __restrict__ obj_msg,
                             const bf16* __restrict__ nsW, const bf16* __restrict__ h_enc,
                             bf16* __restrict__ out)
{
    int bx = blockIdx.x;                      // 0..7
    int h = blockIdx.y;
    int e = (bx & 3) * 256 + threadIdx.x;
    if (bx < 4) {
        out[(size_t)h * 2048 + e] = h_enc[(size_t)h * 1024 + e];
        return;
    }
    float nh = (float)nsW[h * 1024 + e];
    float s = 0.f;
    for (int n = 0; n < 256; ++n) {
        float a  = adj[h * 256 + n];
        float om = (float)obj_msg[n * 1024 + e];
        float nw = (float)nsW[n * 1024 + e];
        s += a * om * (nh - nw);
    }
    out[(size_t)h * 2048 + 1024 + e] = (bf16)s;
}

// fused: out[n,0:1024]=enc[n]; out[n,1024+e]=sum_h adj[h,n]*hum_msg[h,e]*(nsW[n,e]-nsW[h,e])
__global__ void agg_h_kernel(const float* __restrict__ adj, const bf16* __restrict__ hum_msg,
                             const bf16* __restrict__ nsW, const bf16* __restrict__ enc,
                             bf16* __restrict__ out)
{
    int bx = blockIdx.x;                      // 0..7
    int n = blockIdx.y;
    int e = (bx & 3) * 256 + threadIdx.x;
    if (bx < 4) {
        out[(size_t)n * 2048 + e] = enc[(size_t)n * 1024 + e];
        return;
    }
    float nn = (float)nsW[n * 1024 + e];
    float s = 0.f;
    for (int h = 0; h < 64; ++h) {
        float a  = adj[h * 256 + n];
        float hm = (float)hum_msg[h * 1024 + e];
        float nw = (float)nsW[h * 1024 + e];
        s += a * hm * (nn - nw);
    }
    out[(size_t)n * 2048 + 1024 + e] = (bf16)s;
}

// Output row r=(x,y): [h_enc[x] | nsp[x] | enc[y] | nsp[y] | prior(117)]
// f32 path: alignment peel + f32x4 stores (16B/lane).
__global__ void out_kernel(const bf16* __restrict__ h_enc, const bf16* __restrict__ enc,
                           const bf16* __restrict__ nsp_bf, const float* __restrict__ adj,
                           const bf16* __restrict__ scores_bf, const int* __restrict__ labels,
                           const int* __restrict__ cmask, void* __restrict__ out,
                           const int* __restrict__ dflag)
{
    const int f32 = *dflag;
    const int r = blockIdx.x;
    const int x = r / 255;
    const int tt = r % 255;
    const int y = tt + (tt >= x ? 1 : 0);
    const size_t rbase = (size_t)r * 4213;
    const bf16* seg[4] = { h_enc + x * 1024, nsp_bf + x * 1024, enc + y * 1024, nsp_bf + y * 1024 };
    const int t = threadIdx.x;

    float sx = (float)scores_bf[x], sy = (float)scores_bf[y];
    float lx = 8.3f / (1.f + expf(12.f - 10.f * sx));
    float ly = 8.3f / (1.f + expf(12.f - 10.f * sy));
    float pf = adj[x * 256 + y] * lx * ly;
    const int* cm = cmask + labels[y] * 117;

    auto getv = [&](int e) -> float {
        if (e < 4096) return (float)seg[e >> 10][e & 1023];
        return cm[e - 4096] ? pf : 0.f;
    };

    if (f32) {
        float* op = (float*)out + rbase;
        const int ali = (int)((4 - (rbase & 3)) & 3);
        const int nv = (4213 - ali) >> 2;
        for (int vi = t; vi < nv; vi += 256) {
            int e0 = ali + vi * 4;
            f32x4 v = { getv(e0), getv(e0 + 1), getv(e0 + 2), getv(e0 + 3) };
            *(f32x4*)(op + e0) = v;
        }
        if (t < ali) op[t] = getv(t);
        int te = ali + nv * 4;
        if (t < 4213 - te) op[te + t] = getv(te + t);
    } else {
        bf16* op = (bf16*)out + rbase;
        for (int e = t; e < 4213; e += 256) op[e] = (bf16)getv(e);
    }
}

// ---------------------------------------------------------------------------
extern "C" void kernel_launch(void* const* d_in, const int* in_sizes, int n_in,
                              void* d_out, int out_size, void* d_ws, size_t ws_size,
                              hipStream_t stream)
{
    (void)in_sizes; (void)n_in; (void)out_size; (void)ws_size;
    const void* box    = d_in[0];
    const void* nsp    = d_in[1];
    const void* scores = d_in[2];
    const int*  labels = (const int*)d_in[3];
    const int*  cmask  = (const int*)d_in[4];
    const void* W_bh1 = d_in[5],  *b_bh1 = d_in[6];
    const void* W_bh2 = d_in[7],  *b_bh2 = d_in[8];
    const void* W_sa  = d_in[9];
    const void* W_a1  = d_in[10], *b_a1  = d_in[11];
    const void* W_a2  = d_in[12], *b_a2  = d_in[13];
    const void* W_a3  = d_in[14], *b_a3  = d_in[15];
    const void* W_hm  = d_in[16], *b_hm  = d_in[17];
    const void* W_om  = d_in[18], *b_om  = d_in[19];
    const void* W_hu  = d_in[20];
    const void* W_ou  = d_in[21];

    char* ws = (char*)d_ws;
    size_t off = 0;
    auto alloc = [&](size_t bytes) -> void* {
        off = (off + 255) & ~(size_t)255;
        void* p = ws + off;
        off += bytes;
        return p;
    };
    int*  dflag   = (int*)alloc(4);
    bf16* box_bf  = (bf16*)alloc((size_t)256 * 12544 * 2);
    bf16* nsp_bf  = (bf16*)alloc((size_t)256 * 1024 * 2);
    bf16* Wt_a2   = (bf16*)alloc((size_t)1024 * 2048 * 2);
    bf16* smalls  = (bf16*)alloc((size_t)8464 * 2);
    bf16* sb_bh1 = smalls,        *sb_bh2 = smalls + 1024;
    bf16* sb_om  = smalls + 2048, *sb_hm  = smalls + 3072;
    bf16* sb_a1  = smalls + 4096, *sb_a2  = smalls + 6144;
    bf16* sw_a3  = smalls + 7168, *sb_a3  = smalls + 8192;
    bf16* sscore = smalls + 8208;
    bf16* t0      = (bf16*)alloc((size_t)256 * 1024 * 2);
    bf16* enc     = (bf16*)alloc((size_t)256 * 1024 * 2);
    bf16* nsW     = (bf16*)alloc((size_t)256 * 1024 * 2);
    bf16* h_enc   = (bf16*)alloc((size_t)64 * 1024 * 2);
    bf16* hf      = (bf16*)alloc((size_t)64 * 2048 * 2);
    bf16* of      = (bf16*)alloc((size_t)256 * 2048 * 2);
    float* Hpart  = (float*)alloc((size_t)64 * 2048 * 4);
    float* Opart  = (float*)alloc((size_t)256 * 2048 * 4);
    float* slots  = (float*)alloc((size_t)16384 * 16 * 4);
    float* adj    = (float*)alloc((size_t)16384 * 4);
    bf16* obj_msg = (bf16*)alloc((size_t)256 * 1024 * 2);
    bf16* hu_in   = (bf16*)alloc((size_t)64 * 2048 * 2);
    bf16* hum_msg = (bf16*)alloc((size_t)64 * 1024 * 2);
    bf16* ou_in   = (bf16*)alloc((size_t)256 * 2048 * 2);
    float* part   = (float*)alloc((size_t)2097152 * 4);        // split-K partials (8 MB)
    bf16* A_bf    = (bf16*)alloc((size_t)16384 * 2048 * 2);    // pair activations (64 MB)

    // 1) dtype probe
    init_flag<<<1, 1, 0, stream>>>(dflag);
    detect_kernel<<<256, 256, 0, stream>>>((const unsigned short*)box, 524288, dflag);

    // 2) convert A-operand inputs + all small epilogue arrays (one launch)
    cvt_kernel<<<1568, 256, 0, stream>>>(box, box_bf, 256 * 12544, dflag);
    cvt_kernel<<<128, 256, 0, stream>>>(nsp, nsp_bf, 256 * 1024, dflag);
    cvt_smalls<<<34, 256, 0, stream>>>(b_bh1, b_bh2, b_om, b_hm, b_a1, b_a2,
                                       W_a3, b_a3, scores, smalls, dflag);

    // 3) W_a2 -> bf16 transposed (hot operand of pair_gemm, re-read 128x)
    transpose_any<<<dim3(1024 / 32, 2048 / 32), dim3(32, 8), 0, stream>>>(
        W_a2, Wt_a2, 2048, 1024, dflag);

    // 4) enc = relu(relu(box@W_bh1+b)@W_bh2+b); nsW = nsp@W_sa
    gemm_p<<<dim3(16, 4, 8), 256, 0, stream>>>(box_bf, 12544, W_bh1, 0, 1024, part, 1024, 1568, dflag);
    reduce_k<true, true, false><<<dim3(256), 256, 0, stream>>>(part, 8, 262144, sb_bh1, t0, 1024);
    gemm_p<<<dim3(16, 4, 4), 256, 0, stream>>>(t0, 1024, W_bh2, 0, 1024, part, 1024, 256, dflag);
    reduce_k<true, true, false><<<dim3(256), 256, 0, stream>>>(part, 4, 262144, sb_bh2, enc, 1024);
    gemm_p<<<dim3(16, 4, 4), 256, 0, stream>>>(nsp_bf, 1024, W_sa, 0, 1024, part, 1024, 256, dflag);
    reduce_k<false, false, false><<<dim3(256), 256, 0, stream>>>(part, 4, 262144, nullptr, nsW, 1024);
    copy_rows<<<dim3(4, 64), 256, 0, stream>>>(enc, 1024, h_enc, 1024);

    for (int it = 0; it < 2; ++it) {
        concat2<<<dim3(8, 64), 256, 0, stream>>>(h_enc, nsp_bf, hf);
        concat2<<<dim3(8, 256), 256, 0, stream>>>(enc, nsp_bf, of);
        // Hpart = hf @ W_a1[:2048,:] (+ b_a1 folded), Opart = of @ W_a1[2048:,:]
        gemm_p<<<dim3(32, 1, 8), 256, 0, stream>>>(hf, 2048, W_a1, 0, 2048, part, 2048, 256, dflag);
        reduce_k<false, true, true><<<dim3(128), 256, 0, stream>>>(part, 8, 131072, sb_a1, Hpart, 2048);
        gemm_p<<<dim3(32, 4, 4), 256, 0, stream>>>(of, 2048, W_a1, (size_t)2048 * 2048, 2048, part, 2048, 512, dflag);
        reduce_k<false, false, true><<<dim3(512), 256, 0, stream>>>(part, 4, 524288, nullptr, Opart, 2048);
        // A_bf[p,k] = bf16(relu(Hpart[h,k] + Opart[n,k]))
        build_pairA<<<dim3(256, 64), 256, 0, stream>>>(Hpart, Opart, A_bf);
        // adj = sigmoid(pair MLP)
        pair_gemm<<<dim3(8, 128), 256, 0, stream>>>(A_bf, Wt_a2, sb_a2, sw_a3, slots);
        adj_finalize<<<dim3(64), 256, 0, stream>>>(slots, sb_a3, adj);
        // obj_msg = relu(enc @ W_om + b)
        gemm_p<<<dim3(16, 4, 4), 256, 0, stream>>>(enc, 1024, W_om, 0, 1024, part, 1024, 256, dflag);
        reduce_k<true, true, false><<<dim3(256), 256, 0, stream>>>(part, 4, 262144, sb_om, obj_msg, 1024);
        // h_enc = [h_enc | agg_o] @ W_hu   (copy fused into agg)
        agg_o_kernel<<<dim3(8, 64), 256, 0, stream>>>(adj, obj_msg, nsW, h_enc, hu_in);
        gemm_p<<<dim3(16, 1, 16), 256, 0, stream>>>(hu_in, 2048, W_hu, 0, 1024, part, 1024, 128, dflag);
        reduce_k<false, false, false><<<dim3(64), 256, 0, stream>>>(part, 16, 65536, nullptr, h_enc, 1024);
        // hum_msg = relu(h_enc @ W_hm + b)
        gemm_p<<<dim3(16, 1, 16), 256, 0, stream>>>(h_enc, 1024, W_hm, 0, 1024, part, 1024, 64, dflag);
        reduce_k<true, true, false><<<dim3(64), 256, 0, stream>>>(part, 16, 65536, sb_hm, hum_msg, 1024);
        // enc = [enc | agg_h] @ W_ou   (copy fused into agg)
        agg_h_kernel<<<dim3(8, 256), 256, 0, stream>>>(adj, hum_msg, nsW, enc, ou_in);
        gemm_p<<<dim3(16, 4, 4), 256, 0, stream>>>(ou_in, 2048, W_ou, 0, 1024, part, 1024, 512, dflag);
        reduce_k<false, false, false><<<dim3(256), 256, 0, stream>>>(part, 4, 262144, nullptr, enc, 1024);
    }

    out_kernel<<<dim3(16320), 256, 0, stream>>>(
        h_enc, enc, nsp_bf, adj, sscore, labels, cmask, d_out, dflag);
}

// Round 5
// 966.150 us; speedup vs baseline: 2.4854x; 1.0261x over previous
//
#include <hip/hip_runtime.h>

using bf16 = __bf16;
typedef __bf16 bf16x4 __attribute__((ext_vector_type(4)));
typedef __bf16 bf16x8 __attribute__((ext_vector_type(8)));
typedef float  f32x4  __attribute__((ext_vector_type(4)));

#define GST 40  // gemm_p LDS row stride (80 B -> 16B-aligned b128 reads)

// ---- dtype-dispatched access helpers (flag: 1 = inputs are fp32, 0 = bf16) --
__device__ __forceinline__ float ldf(const void* p, size_t i, int f32) {
    return f32 ? ((const float*)p)[i] : (float)((const bf16*)p)[i];
}
__device__ __forceinline__ bf16x8 ld8(const void* p, size_t i, int f32) {
    bf16x8 r;
    if (f32) {
        f32x4 a = *(const f32x4*)((const float*)p + i);
        f32x4 b = *(const f32x4*)((const float*)p + i + 4);
#pragma unroll
        for (int j = 0; j < 4; ++j) { r[j] = (bf16)a[j]; r[j + 4] = (bf16)b[j]; }
    } else {
        r = *(const bf16x8*)((const bf16*)p + i);
    }
    return r;
}
__device__ __forceinline__ void st1(void* p, size_t i, float v, int f32) {
    if (f32) ((float*)p)[i] = v;
    else     ((bf16*)p)[i] = (bf16)v;
}

// ---- async global->LDS, 16B per lane (dest = wave-uniform base + lane*16) --
__device__ __forceinline__ void gl_lds16(const bf16* g, bf16* l) {
    __builtin_amdgcn_global_load_lds(
        (const __attribute__((address_space(1))) void*)g,
        (__attribute__((address_space(3))) void*)l, 16, 0, 0);
}

// ---- detect: bf16 NaN/Inf bit patterns exist iff backing store is fp32 -----
__global__ void init_flag(int* __restrict__ dflag) { *dflag = 0; }

__global__ void detect_kernel(const unsigned short* __restrict__ p, int n,
                              int* __restrict__ dflag)
{
    const unsigned int* q = (const unsigned int*)p;
    const int nw = n >> 1;
    int hit = 0;
    for (int i = blockIdx.x * 256 + threadIdx.x; i < nw; i += gridDim.x * 256) {
        unsigned int w = q[i];
        if ((w & 0x7F80u) == 0x7F80u || (w & 0x7F800000u) == 0x7F800000u) hit = 1;
    }
    if (__any(hit) && (threadIdx.x & 63) == 0) atomicOr(dflag, 1);
}

// ---- convert an input array to internal bf16 (vectorized 8/thread) ---------
__global__ void cvt_kernel(const void* __restrict__ src, bf16* __restrict__ dst,
                           int n, const int* __restrict__ dflag)
{
    const int f32 = *dflag;
    const int stride = gridDim.x * 256;
    const int nv = n >> 3;
    for (int i = blockIdx.x * 256 + threadIdx.x; i < nv; i += stride) {
        bf16x8 v = ld8(src, (size_t)i * 8, f32);
        *(bf16x8*)(dst + (size_t)i * 8) = v;
    }
}

// ---- one launch converts all small epilogue arrays into the smalls block ---
__global__ void cvt_smalls(const void* b_bh1, const void* b_bh2, const void* b_om,
                           const void* b_hm, const void* b_a1, const void* b_a2,
                           const void* w_a3, const void* b_a3, const void* scores,
                           bf16* __restrict__ smalls, const int* __restrict__ dflag)
{
    const int f32 = *dflag;
    int i = blockIdx.x * 256 + threadIdx.x;
    const void* s; int off;
    if      (i < 1024) { s = b_bh1; off = 0;    }
    else if (i < 2048) { s = b_bh2; off = 1024; }
    else if (i < 3072) { s = b_om;  off = 2048; }
    else if (i < 4096) { s = b_hm;  off = 3072; }
    else if (i < 6144) { s = b_a1;  off = 4096; }
    else if (i < 7168) { s = b_a2;  off = 6144; }
    else if (i < 8192) { s = w_a3;  off = 7168; }
    else if (i < 8193) { s = b_a3;  off = 8192; }
    else if (i >= 8208 && i < 8464) { s = scores; off = 8208; }
    else return;
    smalls[i] = (bf16)ldf(s, i - off, f32);
}

// ---- transpose input weight (KxN) -> bf16 Wt (NxK) -------------------------
__global__ void transpose_any(const void* __restrict__ W, bf16* __restrict__ Wt,
                              int K, int N, const int* __restrict__ dflag)
{
    __shared__ bf16 tile[32][33];
    const int f32 = *dflag;
    const int n0 = blockIdx.x * 32, k0 = blockIdx.y * 32;
    const int tx = threadIdx.x, ty = threadIdx.y;  // (32, 8)
#pragma unroll
    for (int i = 0; i < 4; ++i)
        tile[ty + i * 8][tx] = (bf16)ldf(W, (size_t)(k0 + ty + i * 8) * N + n0 + tx, f32);
    __syncthreads();
#pragma unroll
    for (int i = 0; i < 4; ++i)
        Wt[(size_t)(n0 + ty + i * 8) * K + k0 + tx] = tile[tx][ty + i * 8];
}

// ---------------------------------------------------------------------------
// Split-K bf16 MFMA GEMM -> fp32 partials (B is dtype-dispatched).
// ---------------------------------------------------------------------------
__global__ __launch_bounds__(256)
void gemm_p(const bf16* __restrict__ A, int lda,
            const void* __restrict__ B, size_t boff, int ldb,
            float* __restrict__ part, int N, int Kc,
            const int* __restrict__ dflag)
{
    __shared__ bf16 As[64 * GST];
    __shared__ bf16 Bs[64 * GST];
    const int f32 = *dflag;
    const int t = threadIdx.x;
    const int l = t & 63;
    const int quad = l >> 4, lr = l & 15;
    const int w = t >> 6, wm = w >> 1, wn = w & 1;
    const int mBlock = blockIdx.y * 64, nBlock = blockIdx.x * 64;
    const int ar = t >> 2, ac = (t & 3) * 8;      // A-stage coords
    const int kr = t >> 3, nc = (t & 7) * 8;      // B-stage coords
    const int kBeg = blockIdx.z * Kc;
    const int nIter = Kc >> 5;

    f32x4 acc[2][2] = {};

    bf16x8 avr = *(const bf16x8*)(A + (size_t)(mBlock + ar) * lda + kBeg + ac);
    bf16x8 bvr = ld8(B, boff + (size_t)(kBeg + kr) * ldb + nBlock + nc, f32);

    for (int it = 0; it < nIter; ++it) {
        *(bf16x8*)&As[ar * GST + ac] = avr;
#pragma unroll
        for (int j = 0; j < 8; ++j) {
            int wr = nc + j;
            Bs[wr * GST + (kr ^ (((wr >> 3) & 3) << 3))] = bvr[j];
        }
        __syncthreads();
        if (it + 1 < nIter) {
            int k0 = kBeg + (it + 1) * 32;
            avr = *(const bf16x8*)(A + (size_t)(mBlock + ar) * lda + k0 + ac);
            bvr = ld8(B, boff + (size_t)(k0 + kr) * ldb + nBlock + nc, f32);
        }
        bf16x8 af[2], bfr[2];
#pragma unroll
        for (int mi = 0; mi < 2; ++mi)
            af[mi] = *(const bf16x8*)&As[(wm * 32 + mi * 16 + lr) * GST + quad * 8];
#pragma unroll
        for (int nj = 0; nj < 2; ++nj) {
            int row = wn * 32 + nj * 16 + lr;
            bfr[nj] = *(const bf16x8*)&Bs[row * GST + ((quad * 8) ^ (((row >> 3) & 3) << 3))];
        }
#pragma unroll
        for (int mi = 0; mi < 2; ++mi)
#pragma unroll
            for (int nj = 0; nj < 2; ++nj)
                acc[mi][nj] = __builtin_amdgcn_mfma_f32_16x16x32_bf16(
                    af[mi], bfr[nj], acc[mi][nj], 0, 0, 0);
        __syncthreads();
    }

    float* outp = part + (size_t)blockIdx.z * ((size_t)gridDim.y * 64 * N);
#pragma unroll
    for (int mi = 0; mi < 2; ++mi)
#pragma unroll
        for (int nj = 0; nj < 2; ++nj) {
            int col = nBlock + wn * 32 + nj * 16 + lr;
#pragma unroll
            for (int rr = 0; rr < 4; ++rr) {
                int row = mBlock + wm * 32 + mi * 16 + quad * 4 + rr;
                outp[(size_t)row * N + col] = acc[mi][nj][rr];
            }
        }
}

// ---- reduce split-K partials, apply bias/relu, write (strided) out ---------
template<bool RELU, bool BIAS, bool F32OUT>
__global__ void reduce_k(const float* __restrict__ part, int S, int total,
                         const bf16* __restrict__ bias, void* __restrict__ out,
                         int N, int ldd)
{
    int base = (blockIdx.x * 256 + threadIdx.x) * 4;
    if (base >= total) return;
    f32x4 s = *(const f32x4*)(part + base);
    for (int z = 1; z < S; ++z) {
        f32x4 v = *(const f32x4*)(part + (size_t)z * total + base);
        s[0] += v[0]; s[1] += v[1]; s[2] += v[2]; s[3] += v[3];
    }
    int row = base / N, col = base % N;
    size_t ob = (size_t)row * ldd + col;
#pragma unroll
    for (int j = 0; j < 4; ++j) {
        float v = s[j];
        if (BIAS) v += (float)bias[col + j];
        if (RELU) v = fmaxf(v, 0.f);
        if (F32OUT) ((float*)out)[ob + j] = v;
        else        ((bf16*)out)[ob + j] = (bf16)v;
    }
}

// ---- A_bf[p=(h,n), k] = bf16(relu(Hb[h,k] + Op[n,k])), Hb has b_a1 folded --
__global__ void build_pairA(const float* __restrict__ Hb, const float* __restrict__ Op,
                            bf16* __restrict__ A)
{
    const int n = blockIdx.x;        // 256
    const int h = blockIdx.y;        // 64
    const int k = threadIdx.x * 8;   // 256 threads x 8 = 2048
    const float* hp = Hb + (size_t)h * 2048 + k;
    const float* op = Op + (size_t)n * 2048 + k;
    f32x4 h0 = *(const f32x4*)hp, h1 = *(const f32x4*)(hp + 4);
    f32x4 o0 = *(const f32x4*)op, o1 = *(const f32x4*)(op + 4);
    bf16x8 r;
#pragma unroll
    for (int j = 0; j < 4; ++j) {
        r[j]     = (bf16)fmaxf(h0[j] + o0[j], 0.f);
        r[j + 4] = (bf16)fmaxf(h1[j] + o1[j], 0.f);
    }
    *(bf16x8*)(A + ((size_t)h * 256 + n) * 2048 + k) = r;
}

// ---------------------------------------------------------------------------
// Pure-GEMM pair MLP, double-buffered m97 schedule: stage tile t+1 via
// global_load_lds BEFORE computing tile t; ONE barrier per K-step (its
// implicit vmcnt drain lands after the MFMA phase). LDS 2x(A,B) 8KB tiles.
// XOR swizzle both-sides (inverse-swizzled source chunk / swizzled ds_read).
// Block remap: the 8 nb-blocks sharing an A-tile land on one XCD.
// Grid (16, 64) remapped; block 256 = 4 waves 2x2, wave tile 64x64, BK=32.
// ---------------------------------------------------------------------------
__global__ __launch_bounds__(256)
void pair_gemm(const bf16* __restrict__ Apg, const bf16* __restrict__ Wt_a2,
               const bf16* __restrict__ b_a2, const bf16* __restrict__ w_a3,
               float* __restrict__ slots)
{
    __shared__ bf16 As[2][128 * 32];
    __shared__ bf16 Bs[2][128 * 32];
    const int t = threadIdx.x;
    const int l = t & 63, w = t >> 6;
    const int quad = l >> 4, lr = l & 15;
    const int wm = w >> 1, wn = w & 1;
    // dispatch o = bx + 8*by (grid (8,128)); remap so blocks with o%8 equal
    // (same XCD under round-robin) share the same A row-panels.
    const int nb = blockIdx.y & 7;
    const int mb = blockIdx.x * 16 + (blockIdx.y >> 3);
    const int p0 = mb * 128;

    // gload geometry: lane l -> LDS bytes (w*1024 + l*16): row=w*16+l/4, slot=l&3
    const int grow = w * 16 + (l >> 2);
    const int slot = l & 3;
    const int csrc = slot ^ ((grow >> 1) & 3);   // ((row+64)>>1)&3 == (row>>1)&3
    const bf16* Asrc0 = Apg + (size_t)(p0 + grow) * 2048 + csrc * 8;
    const bf16* Asrc1 = Apg + (size_t)(p0 + 64 + grow) * 2048 + csrc * 8;
    const bf16* Bsrc0 = Wt_a2 + (size_t)(nb * 128 + grow) * 2048 + csrc * 8;
    const bf16* Bsrc1 = Wt_a2 + (size_t)(nb * 128 + 64 + grow) * 2048 + csrc * 8;
    const int woff = w * 512;                    // wave-uniform LDS offset

    f32x4 acc[4][4] = {};

    // prologue: stage tile 0 into buffer 0
    gl_lds16(Asrc0, As[0] + woff);
    gl_lds16(Asrc1, As[0] + 2048 + woff);
    gl_lds16(Bsrc0, Bs[0] + woff);
    gl_lds16(Bsrc1, Bs[0] + 2048 + woff);
    __syncthreads();

    int cur = 0;
    for (int kt = 0; kt < 64; ++kt) {
        // issue next tile's loads (overlap with this tile's compute)
        if (kt < 63) {
            int kn = (kt + 1) * 32;
            bf16* An = As[cur ^ 1];
            bf16* Bn = Bs[cur ^ 1];
            gl_lds16(Asrc0 + kn, An + woff);
            gl_lds16(Asrc1 + kn, An + 2048 + woff);
            gl_lds16(Bsrc0 + kn, Bn + woff);
            gl_lds16(Bsrc1 + kn, Bn + 2048 + woff);
        }
        const bf16* Ac = As[cur];
        const bf16* Bc = Bs[cur];
        bf16x8 af[4], bfr[4];
#pragma unroll
        for (int mi = 0; mi < 4; ++mi) {
            int row = wm * 64 + mi * 16 + lr;
            int sl = quad ^ ((row >> 1) & 3);
            af[mi] = *(const bf16x8*)&Ac[row * 32 + sl * 8];
        }
#pragma unroll
        for (int nj = 0; nj < 4; ++nj) {
            int row = wn * 64 + nj * 16 + lr;
            int sl = quad ^ ((row >> 1) & 3);
            bfr[nj] = *(const bf16x8*)&Bc[row * 32 + sl * 8];
        }
#pragma unroll
        for (int mi = 0; mi < 4; ++mi)
#pragma unroll
            for (int nj = 0; nj < 4; ++nj)
                acc[mi][nj] = __builtin_amdgcn_mfma_f32_16x16x32_bf16(
                    af[mi], bfr[nj], acc[mi][nj], 0, 0, 0);
        __syncthreads();   // reads of buf[cur] done; next-tile writes drained
        cur ^= 1;
    }

    float w3v[4], b2v[4];
#pragma unroll
    for (int nj = 0; nj < 4; ++nj) {
        int col = nb * 128 + wn * 64 + nj * 16 + lr;
        w3v[nj] = (float)w_a3[col];
        b2v[nj] = (float)b_a2[col];
    }
#pragma unroll
    for (int mi = 0; mi < 4; ++mi) {
        f32x4 rs = {0.f, 0.f, 0.f, 0.f};
#pragma unroll
        for (int nj = 0; nj < 4; ++nj)
#pragma unroll
            for (int rr = 0; rr < 4; ++rr)
                rs[rr] += fmaxf(acc[mi][nj][rr] + b2v[nj], 0.f) * w3v[nj];
#pragma unroll
        for (int off = 1; off < 16; off <<= 1) {
            rs[0] += __shfl_xor(rs[0], off);
            rs[1] += __shfl_xor(rs[1], off);
            rs[2] += __shfl_xor(rs[2], off);
            rs[3] += __shfl_xor(rs[3], off);
        }
        if (lr == 0) {
            int p = p0 + wm * 64 + mi * 16 + quad * 4;
            int slot2 = nb * 2 + wn;
            slots[(size_t)(p + 0) * 16 + slot2] = rs[0];
            slots[(size_t)(p + 1) * 16 + slot2] = rs[1];
            slots[(size_t)(p + 2) * 16 + slot2] = rs[2];
            slots[(size_t)(p + 3) * 16 + slot2] = rs[3];
        }
    }
}

__global__ void adj_finalize(const float* __restrict__ slots,
                             const bf16* __restrict__ b_a3, float* __restrict__ adj)
{
    int i = blockIdx.x * 256 + threadIdx.x;
    float s = (float)b_a3[0];
#pragma unroll
    for (int k = 0; k < 16; ++k) s += slots[(size_t)i * 16 + k];
    adj[i] = 1.f / (1.f + expf(-s));
}

__global__ void copy_rows(const bf16* __restrict__ src, int lds_,
                          bf16* __restrict__ dst, int ldd)
{
    int c = blockIdx.x * 256 + threadIdx.x;  // 1024 cols
    int r = blockIdx.y;
    dst[(size_t)r * ldd + c] = src[(size_t)r * lds_ + c];
}

// fused: out[h,0:1024]=hf[h,:1024]; out[h,1024+e]=sum_n adj*obj_msg*(nsW_h-nsW_n)
__global__ void agg_o_kernel(const float* __restrict__ adj, const bf16* __restrict__ obj_msg,
                             const bf16* __restrict__ nsW, const bf16* __restrict__ hf,
                             bf16* __restrict__ out)
{
    int bx = blockIdx.x;                      // 0..7
    int h = blockIdx.y;
    int e = (bx & 3) * 256 + threadIdx.x;
    if (bx < 4) {
        out[(size_t)h * 2048 + e] = hf[(size_t)h * 2048 + e];
        return;
    }
    float nh = (float)nsW[h * 1024 + e];
    float s = 0.f;
    for (int n = 0; n < 256; ++n) {
        float a  = adj[h * 256 + n];
        float om = (float)obj_msg[n * 1024 + e];
        float nw = (float)nsW[n * 1024 + e];
        s += a * om * (nh - nw);
    }
    out[(size_t)h * 2048 + 1024 + e] = (bf16)s;
}

// fused: out[n,0:1024]=of[n,:1024]; out[n,1024+e]=sum_h adj*hum_msg*(nsW_n-nsW_h)
__global__ void agg_h_kernel(const float* __restrict__ adj, const bf16* __restrict__ hum_msg,
                             const bf16* __restrict__ nsW, const bf16* __restrict__ of,
                             bf16* __restrict__ out)
{
    int bx = blockIdx.x;                      // 0..7
    int n = blockIdx.y;
    int e = (bx & 3) * 256 + threadIdx.x;
    if (bx < 4) {
        out[(size_t)n * 2048 + e] = of[(size_t)n * 2048 + e];
        return;
    }
    float nn = (float)nsW[n * 1024 + e];
    float s = 0.f;
    for (int h = 0; h < 64; ++h) {
        float a  = adj[h * 256 + n];
        float hm = (float)hum_msg[h * 1024 + e];
        float nw = (float)nsW[h * 1024 + e];
        s += a * hm * (nn - nw);
    }
    out[(size_t)n * 2048 + 1024 + e] = (bf16)s;
}

// Output row r=(x,y): [h_enc[x] | nsp[x] | enc[y] | nsp[y] | prior(117)]
// h_enc lives in hf (stride 2048), enc lives in of (stride 2048).
__global__ void out_kernel(const bf16* __restrict__ hf, const bf16* __restrict__ of,
                           const bf16* __restrict__ nsp_bf, const float* __restrict__ adj,
                           const bf16* __restrict__ scores_bf, const int* __restrict__ labels,
                           const int* __restrict__ cmask, void* __restrict__ out,
                           const int* __restrict__ dflag)
{
    const int f32 = *dflag;
    const int r = blockIdx.x;
    const int x = r / 255;
    const int tt = r % 255;
    const int y = tt + (tt >= x ? 1 : 0);
    const size_t rbase = (size_t)r * 4213;
    const bf16* seg[4] = { hf + (size_t)x * 2048, nsp_bf + x * 1024,
                           of + (size_t)y * 2048, nsp_bf + y * 1024 };
    const int t = threadIdx.x;

    float sx = (float)scores_bf[x], sy = (float)scores_bf[y];
    float lx = 8.3f / (1.f + expf(12.f - 10.f * sx));
    float ly = 8.3f / (1.f + expf(12.f - 10.f * sy));
    float pf = adj[x * 256 + y] * lx * ly;
    const int* cm = cmask + labels[y] * 117;

    auto getv = [&](int e) -> float {
        if (e < 4096) return (float)seg[e >> 10][e & 1023];
        return cm[e - 4096] ? pf : 0.f;
    };

    if (f32) {
        float* op = (float*)out + rbase;
        const int ali = (int)((4 - (rbase & 3)) & 3);
        const int nv = (4213 - ali) >> 2;
        for (int vi = t; vi < nv; vi += 256) {
            int e0 = ali + vi * 4;
            f32x4 v = { getv(e0), getv(e0 + 1), getv(e0 + 2), getv(e0 + 3) };
            *(f32x4*)(op + e0) = v;
        }
        if (t < ali) op[t] = getv(t);
        int te = ali + nv * 4;
        if (t < 4213 - te) op[te + t] = getv(te + t);
    } else {
        bf16* op = (bf16*)out + rbase;
        for (int e = t; e < 4213; e += 256) op[e] = (bf16)getv(e);
    }
}

// ---------------------------------------------------------------------------
extern "C" void kernel_launch(void* const* d_in, const int* in_sizes, int n_in,
                              void* d_out, int out_size, void* d_ws, size_t ws_size,
                              hipStream_t stream)
{
    (void)in_sizes; (void)n_in; (void)out_size; (void)ws_size;
    const void* box    = d_in[0];
    const void* nsp    = d_in[1];
    const void* scores = d_in[2];
    const int*  labels = (const int*)d_in[3];
    const int*  cmask  = (const int*)d_in[4];
    const void* W_bh1 = d_in[5],  *b_bh1 = d_in[6];
    const void* W_bh2 = d_in[7],  *b_bh2 = d_in[8];
    const void* W_sa  = d_in[9];
    const void* W_a1  = d_in[10], *b_a1  = d_in[11];
    const void* W_a2  = d_in[12], *b_a2  = d_in[13];
    const void* W_a3  = d_in[14], *b_a3  = d_in[15];
    const void* W_hm  = d_in[16], *b_hm  = d_in[17];
    const void* W_om  = d_in[18], *b_om  = d_in[19];
    const void* W_hu  = d_in[20];
    const void* W_ou  = d_in[21];

    char* ws = (char*)d_ws;
    size_t off = 0;
    auto alloc = [&](size_t bytes) -> void* {
        off = (off + 255) & ~(size_t)255;
        void* p = ws + off;
        off += bytes;
        return p;
    };
    int*  dflag   = (int*)alloc(4);
    bf16* box_bf  = (bf16*)alloc((size_t)256 * 12544 * 2);
    bf16* nsp_bf  = (bf16*)alloc((size_t)256 * 1024 * 2);
    bf16* Wt_a2   = (bf16*)alloc((size_t)1024 * 2048 * 2);
    bf16* smalls  = (bf16*)alloc((size_t)8464 * 2);
    bf16* sb_bh1 = smalls,        *sb_bh2 = smalls + 1024;
    bf16* sb_om  = smalls + 2048, *sb_hm  = smalls + 3072;
    bf16* sb_a1  = smalls + 4096, *sb_a2  = smalls + 6144;
    bf16* sw_a3  = smalls + 7168, *sb_a3  = smalls + 8192;
    bf16* sscore = smalls + 8208;
    bf16* t0      = (bf16*)alloc((size_t)256 * 1024 * 2);
    bf16* nsW     = (bf16*)alloc((size_t)256 * 1024 * 2);
    bf16* hf      = (bf16*)alloc((size_t)64 * 2048 * 2);   // [h_enc | nsp[:64]]
    bf16* of      = (bf16*)alloc((size_t)256 * 2048 * 2);  // [enc   | nsp]
    float* Hpart  = (float*)alloc((size_t)64 * 2048 * 4);
    float* Opart  = (float*)alloc((size_t)256 * 2048 * 4);
    float* slots  = (float*)alloc((size_t)16384 * 16 * 4);
    float* adj    = (float*)alloc((size_t)16384 * 4);
    bf16* obj_msg = (bf16*)alloc((size_t)256 * 1024 * 2);
    bf16* hu_in   = (bf16*)alloc((size_t)64 * 2048 * 2);
    bf16* hum_msg = (bf16*)alloc((size_t)64 * 1024 * 2);
    bf16* ou_in   = (bf16*)alloc((size_t)256 * 2048 * 2);
    float* part   = (float*)alloc((size_t)2097152 * 4);        // split-K partials (8 MB)
    bf16* A_bf    = (bf16*)alloc((size_t)16384 * 2048 * 2);    // pair activations (64 MB)

    // 1) dtype probe
    init_flag<<<1, 1, 0, stream>>>(dflag);
    detect_kernel<<<256, 256, 0, stream>>>((const unsigned short*)box, 524288, dflag);

    // 2) convert A-operand inputs + all small epilogue arrays
    cvt_kernel<<<1568, 256, 0, stream>>>(box, box_bf, 256 * 12544, dflag);
    cvt_kernel<<<128, 256, 0, stream>>>(nsp, nsp_bf, 256 * 1024, dflag);
    cvt_smalls<<<34, 256, 0, stream>>>(b_bh1, b_bh2, b_om, b_hm, b_a1, b_a2,
                                       W_a3, b_a3, scores, smalls, dflag);

    // 3) W_a2 -> bf16 transposed (hot operand of pair_gemm, re-read 128x)
    transpose_any<<<dim3(1024 / 32, 2048 / 32), dim3(32, 8), 0, stream>>>(
        W_a2, Wt_a2, 2048, 1024, dflag);

    // 4) enc = relu(relu(box@W_bh1+b)@W_bh2+b) -> of[:, :1024]; nsW = nsp@W_sa
    gemm_p<<<dim3(16, 4, 8), 256, 0, stream>>>(box_bf, 12544, W_bh1, 0, 1024, part, 1024, 1568, dflag);
    reduce_k<true, true, false><<<dim3(256), 256, 0, stream>>>(part, 8, 262144, sb_bh1, t0, 1024, 1024);
    gemm_p<<<dim3(16, 4, 4), 256, 0, stream>>>(t0, 1024, W_bh2, 0, 1024, part, 1024, 256, dflag);
    reduce_k<true, true, false><<<dim3(256), 256, 0, stream>>>(part, 4, 262144, sb_bh2, of, 1024, 2048);
    gemm_p<<<dim3(16, 4, 4), 256, 0, stream>>>(nsp_bf, 1024, W_sa, 0, 1024, part, 1024, 256, dflag);
    reduce_k<false, false, false><<<dim3(256), 256, 0, stream>>>(part, 4, 262144, nullptr, nsW, 1024, 1024);
    // h_enc init + one-time nsp halves of hf / of
    copy_rows<<<dim3(4, 64), 256, 0, stream>>>(of, 2048, hf, 2048);
    copy_rows<<<dim3(4, 64), 256, 0, stream>>>(nsp_bf, 1024, hf + 1024, 2048);
    copy_rows<<<dim3(4, 256), 256, 0, stream>>>(nsp_bf, 1024, of + 1024, 2048);

    for (int it = 0; it < 2; ++it) {
        // Hpart = hf @ W_a1[:2048,:] (+ b_a1 folded), Opart = of @ W_a1[2048:,:]
        gemm_p<<<dim3(32, 1, 8), 256, 0, stream>>>(hf, 2048, W_a1, 0, 2048, part, 2048, 256, dflag);
        reduce_k<false, true, true><<<dim3(128), 256, 0, stream>>>(part, 8, 131072, sb_a1, Hpart, 2048, 2048);
        gemm_p<<<dim3(32, 4, 4), 256, 0, stream>>>(of, 2048, W_a1, (size_t)2048 * 2048, 2048, part, 2048, 512, dflag);
        reduce_k<false, false, true><<<dim3(512), 256, 0, stream>>>(part, 4, 524288, nullptr, Opart, 2048, 2048);
        // A_bf[p,k] = bf16(relu(Hpart[h,k] + Opart[n,k]))
        build_pairA<<<dim3(256, 64), 256, 0, stream>>>(Hpart, Opart, A_bf);
        // adj = sigmoid(pair MLP)
        pair_gemm<<<dim3(8, 128), 256, 0, stream>>>(A_bf, Wt_a2, sb_a2, sw_a3, slots);
        adj_finalize<<<dim3(64), 256, 0, stream>>>(slots, sb_a3, adj);
        // obj_msg = relu(enc @ W_om + b)   (enc = of left half, lda 2048)
        gemm_p<<<dim3(16, 4, 4), 256, 0, stream>>>(of, 2048, W_om, 0, 1024, part, 1024, 256, dflag);
        reduce_k<true, true, false><<<dim3(256), 256, 0, stream>>>(part, 4, 262144, sb_om, obj_msg, 1024, 1024);
        // h_enc = [h_enc | agg_o] @ W_hu -> hf[:, :1024]
        agg_o_kernel<<<dim3(8, 64), 256, 0, stream>>>(adj, obj_msg, nsW, hf, hu_in);
        gemm_p<<<dim3(16, 1, 16), 256, 0, stream>>>(hu_in, 2048, W_hu, 0, 1024, part, 1024, 128, dflag);
        reduce_k<false, false, false><<<dim3(64), 256, 0, stream>>>(part, 16, 65536, nullptr, hf, 1024, 2048);
        // hum_msg = relu(h_enc @ W_hm + b)   (h_enc = hf left half)
        gemm_p<<<dim3(16, 1, 16), 256, 0, stream>>>(hf, 2048, W_hm, 0, 1024, part, 1024, 64, dflag);
        reduce_k<true, true, false><<<dim3(64), 256, 0, stream>>>(part, 16, 65536, sb_hm, hum_msg, 1024, 1024);
        // enc = [enc | agg_h] @ W_ou -> of[:, :1024]
        agg_h_kernel<<<dim3(8, 256), 256, 0, stream>>>(adj, hum_msg, nsW, of, ou_in);
        gemm_p<<<dim3(16, 4, 4), 256, 0, stream>>>(ou_in, 2048, W_ou, 0, 1024, part, 1024, 512, dflag);
        reduce_k<false, false, false><<<dim3(256), 256, 0, stream>>>(part, 4, 262144, nullptr, of, 1024, 2048);
    }

    out_kernel<<<dim3(16320), 256, 0, stream>>>(
        hf, of, nsp_bf, adj, sscore, labels, cmask, d_out, dflag);
}

// Round 6
// 964.448 us; speedup vs baseline: 2.4898x; 1.0018x over previous
//
#include <hip/hip_runtime.h>

using bf16 = __bf16;
typedef __bf16 bf16x4 __attribute__((ext_vector_type(4)));
typedef __bf16 bf16x8 __attribute__((ext_vector_type(8)));
typedef float  f32x4  __attribute__((ext_vector_type(4)));

#define GST 40  // gemm_p LDS row stride (80 B -> 16B-aligned b128 reads)

// ---- dtype-dispatched access helpers (flag: 1 = inputs are fp32, 0 = bf16) --
__device__ __forceinline__ float ldf(const void* p, size_t i, int f32) {
    return f32 ? ((const float*)p)[i] : (float)((const bf16*)p)[i];
}
__device__ __forceinline__ bf16x8 ld8(const void* p, size_t i, int f32) {
    bf16x8 r;
    if (f32) {
        f32x4 a = *(const f32x4*)((const float*)p + i);
        f32x4 b = *(const f32x4*)((const float*)p + i + 4);
#pragma unroll
        for (int j = 0; j < 4; ++j) { r[j] = (bf16)a[j]; r[j + 4] = (bf16)b[j]; }
    } else {
        r = *(const bf16x8*)((const bf16*)p + i);
    }
    return r;
}
__device__ __forceinline__ void st1(void* p, size_t i, float v, int f32) {
    if (f32) ((float*)p)[i] = v;
    else     ((bf16*)p)[i] = (bf16)v;
}

// ---- async global->LDS, 16B per lane (dest = wave-uniform base + lane*16) --
__device__ __forceinline__ void gl_lds16(const bf16* g, bf16* l) {
    __builtin_amdgcn_global_load_lds(
        (const __attribute__((address_space(1))) void*)g,
        (__attribute__((address_space(3))) void*)l, 16, 0, 0);
}

// ---- detect: bf16 NaN/Inf bit patterns exist iff backing store is fp32 -----
__global__ void init_flag(int* __restrict__ dflag) { *dflag = 0; }

__global__ void detect_kernel(const unsigned short* __restrict__ p, int n,
                              int* __restrict__ dflag)
{
    const unsigned int* q = (const unsigned int*)p;
    const int nw = n >> 1;
    int hit = 0;
    for (int i = blockIdx.x * 256 + threadIdx.x; i < nw; i += gridDim.x * 256) {
        unsigned int w = q[i];
        if ((w & 0x7F80u) == 0x7F80u || (w & 0x7F800000u) == 0x7F800000u) hit = 1;
    }
    if (__any(hit) && (threadIdx.x & 63) == 0) atomicOr(dflag, 1);
}

// ---- ONE launch converts box + nsp (8-elem vector chunks) + all smalls -----
// smalls layout: [0:1024)=b_bh1 [1024)=b_bh2 [2048)=b_om [3072)=b_hm
// [4096,6144)=b_a1 [6144)=b_a2 [7168)=w_a3 [8192]=b_a3 [8208,8464)=scores
#define CVT_V1 401408   // 256*12544/8 chunks (box)
#define CVT_V2 32768    // 256*1024/8 chunks (nsp)
__global__ void cvt_fused(const void* __restrict__ box, bf16* __restrict__ box_bf,
                          const void* __restrict__ nsp, bf16* __restrict__ nsp_bf,
                          const void* b_bh1, const void* b_bh2, const void* b_om,
                          const void* b_hm, const void* b_a1, const void* b_a2,
                          const void* w_a3, const void* b_a3, const void* scores,
                          bf16* __restrict__ smalls, const int* __restrict__ dflag)
{
    const int f32 = *dflag;
    int i = blockIdx.x * 256 + threadIdx.x;
    if (i < CVT_V1) {
        bf16x8 v = ld8(box, (size_t)i * 8, f32);
        *(bf16x8*)(box_bf + (size_t)i * 8) = v;
        return;
    }
    i -= CVT_V1;
    if (i < CVT_V2) {
        bf16x8 v = ld8(nsp, (size_t)i * 8, f32);
        *(bf16x8*)(nsp_bf + (size_t)i * 8) = v;
        return;
    }
    i -= CVT_V2;
    const void* s; int off;
    if      (i < 1024) { s = b_bh1; off = 0;    }
    else if (i < 2048) { s = b_bh2; off = 1024; }
    else if (i < 3072) { s = b_om;  off = 2048; }
    else if (i < 4096) { s = b_hm;  off = 3072; }
    else if (i < 6144) { s = b_a1;  off = 4096; }
    else if (i < 7168) { s = b_a2;  off = 6144; }
    else if (i < 8192) { s = w_a3;  off = 7168; }
    else if (i < 8193) { s = b_a3;  off = 8192; }
    else if (i >= 8208 && i < 8464) { s = scores; off = 8208; }
    else return;
    smalls[i] = (bf16)ldf(s, i - off, f32);
}

// ---- transpose input weight (KxN) -> bf16 Wt (NxK) -------------------------
__global__ void transpose_any(const void* __restrict__ W, bf16* __restrict__ Wt,
                              int K, int N, const int* __restrict__ dflag)
{
    __shared__ bf16 tile[32][33];
    const int f32 = *dflag;
    const int n0 = blockIdx.x * 32, k0 = blockIdx.y * 32;
    const int tx = threadIdx.x, ty = threadIdx.y;  // (32, 8)
#pragma unroll
    for (int i = 0; i < 4; ++i)
        tile[ty + i * 8][tx] = (bf16)ldf(W, (size_t)(k0 + ty + i * 8) * N + n0 + tx, f32);
    __syncthreads();
#pragma unroll
    for (int i = 0; i < 4; ++i)
        Wt[(size_t)(n0 + ty + i * 8) * K + k0 + tx] = tile[tx][ty + i * 8];
}

// ---------------------------------------------------------------------------
// Split-K bf16 MFMA GEMM -> fp32 partials (B is dtype-dispatched).
// NEW: LDS double-buffer, ONE barrier per K-step. Per iter: prefetch next
// tile to regs -> ds_read + MFMA from buf[cur] -> ds_write buf[cur^1] (vmcnt
// wait for the prefetch lands after the MFMA phase) -> single sync.
// ---------------------------------------------------------------------------
__global__ __launch_bounds__(256)
void gemm_p(const bf16* __restrict__ A, int lda,
            const void* __restrict__ B, size_t boff, int ldb,
            float* __restrict__ part, int N, int Kc,
            const int* __restrict__ dflag)
{
    __shared__ bf16 As[2][64 * GST];
    __shared__ bf16 Bs[2][64 * GST];
    const int f32 = *dflag;
    const int t = threadIdx.x;
    const int l = t & 63;
    const int quad = l >> 4, lr = l & 15;
    const int w = t >> 6, wm = w >> 1, wn = w & 1;
    const int mBlock = blockIdx.y * 64, nBlock = blockIdx.x * 64;
    const int ar = t >> 2, ac = (t & 3) * 8;      // A-stage coords
    const int kr = t >> 3, nc = (t & 7) * 8;      // B-stage coords
    const int kBeg = blockIdx.z * Kc;
    const int nIter = Kc >> 5;

    f32x4 acc[2][2] = {};

    // stage tile 0 into buffer 0
    {
        bf16x8 avr = *(const bf16x8*)(A + (size_t)(mBlock + ar) * lda + kBeg + ac);
        bf16x8 bvr = ld8(B, boff + (size_t)(kBeg + kr) * ldb + nBlock + nc, f32);
        *(bf16x8*)&As[0][ar * GST + ac] = avr;
#pragma unroll
        for (int j = 0; j < 8; ++j) {
            int wr = nc + j;
            Bs[0][wr * GST + (kr ^ (((wr >> 3) & 3) << 3))] = bvr[j];
        }
    }
    __syncthreads();

    int cur = 0;
    for (int it = 0; it < nIter; ++it) {
        const bool more = (it + 1 < nIter);
        bf16x8 av2, bv2;
        if (more) {
            int k0 = kBeg + (it + 1) * 32;
            av2 = *(const bf16x8*)(A + (size_t)(mBlock + ar) * lda + k0 + ac);
            bv2 = ld8(B, boff + (size_t)(k0 + kr) * ldb + nBlock + nc, f32);
        }
        const bf16* Ac = As[cur];
        const bf16* Bc = Bs[cur];
        bf16x8 af[2], bfr[2];
#pragma unroll
        for (int mi = 0; mi < 2; ++mi)
            af[mi] = *(const bf16x8*)&Ac[(wm * 32 + mi * 16 + lr) * GST + quad * 8];
#pragma unroll
        for (int nj = 0; nj < 2; ++nj) {
            int row = wn * 32 + nj * 16 + lr;
            bfr[nj] = *(const bf16x8*)&Bc[row * GST + ((quad * 8) ^ (((row >> 3) & 3) << 3))];
        }
#pragma unroll
        for (int mi = 0; mi < 2; ++mi)
#pragma unroll
            for (int nj = 0; nj < 2; ++nj)
                acc[mi][nj] = __builtin_amdgcn_mfma_f32_16x16x32_bf16(
                    af[mi], bfr[nj], acc[mi][nj], 0, 0, 0);
        if (more) {
            bf16* An = As[cur ^ 1];
            bf16* Bn = Bs[cur ^ 1];
            *(bf16x8*)&An[ar * GST + ac] = av2;
#pragma unroll
            for (int j = 0; j < 8; ++j) {
                int wr = nc + j;
                Bn[wr * GST + (kr ^ (((wr >> 3) & 3) << 3))] = bv2[j];
            }
        }
        __syncthreads();   // my reads of buf[cur] done; my writes to buf[cur^1] visible
        cur ^= 1;
    }

    float* outp = part + (size_t)blockIdx.z * ((size_t)gridDim.y * 64 * N);
#pragma unroll
    for (int mi = 0; mi < 2; ++mi)
#pragma unroll
        for (int nj = 0; nj < 2; ++nj) {
            int col = nBlock + wn * 32 + nj * 16 + lr;
#pragma unroll
            for (int rr = 0; rr < 4; ++rr) {
                int row = mBlock + wm * 32 + mi * 16 + quad * 4 + rr;
                outp[(size_t)row * N + col] = acc[mi][nj][rr];
            }
        }
}

// ---- reduce split-K partials, apply bias/relu, write (strided) out ---------
template<bool RELU, bool BIAS, bool F32OUT>
__global__ void reduce_k(const float* __restrict__ part, int S, int total,
                         const bf16* __restrict__ bias, void* __restrict__ out,
                         int N, int ldd)
{
    int base = (blockIdx.x * 256 + threadIdx.x) * 4;
    if (base >= total) return;
    f32x4 s = *(const f32x4*)(part + base);
    for (int z = 1; z < S; ++z) {
        f32x4 v = *(const f32x4*)(part + (size_t)z * total + base);
        s[0] += v[0]; s[1] += v[1]; s[2] += v[2]; s[3] += v[3];
    }
    int row = base / N, col = base % N;
    size_t ob = (size_t)row * ldd + col;
#pragma unroll
    for (int j = 0; j < 4; ++j) {
        float v = s[j];
        if (BIAS) v += (float)bias[col + j];
        if (RELU) v = fmaxf(v, 0.f);
        if (F32OUT) ((float*)out)[ob + j] = v;
        else        ((bf16*)out)[ob + j] = (bf16)v;
    }
}

// ---- A_bf[p=(h,n), k] = bf16(relu(Hb[h,k] + Op[n,k])), Hb has b_a1 folded --
__global__ void build_pairA(const float* __restrict__ Hb, const float* __restrict__ Op,
                            bf16* __restrict__ A)
{
    const int n = blockIdx.x;        // 256
    const int h = blockIdx.y;        // 64
    const int k = threadIdx.x * 8;   // 256 threads x 8 = 2048
    const float* hp = Hb + (size_t)h * 2048 + k;
    const float* op = Op + (size_t)n * 2048 + k;
    f32x4 h0 = *(const f32x4*)hp, h1 = *(const f32x4*)(hp + 4);
    f32x4 o0 = *(const f32x4*)op, o1 = *(const f32x4*)(op + 4);
    bf16x8 r;
#pragma unroll
    for (int j = 0; j < 4; ++j) {
        r[j]     = (bf16)fmaxf(h0[j] + o0[j], 0.f);
        r[j + 4] = (bf16)fmaxf(h1[j] + o1[j], 0.f);
    }
    *(bf16x8*)(A + ((size_t)h * 256 + n) * 2048 + k) = r;
}

// ---------------------------------------------------------------------------
// Pure-GEMM pair MLP, double-buffered m97 schedule (round-4 version).
// ---------------------------------------------------------------------------
__global__ __launch_bounds__(256)
void pair_gemm(const bf16* __restrict__ Apg, const bf16* __restrict__ Wt_a2,
               const bf16* __restrict__ b_a2, const bf16* __restrict__ w_a3,
               float* __restrict__ slots)
{
    __shared__ bf16 As[2][128 * 32];
    __shared__ bf16 Bs[2][128 * 32];
    const int t = threadIdx.x;
    const int l = t & 63, w = t >> 6;
    const int quad = l >> 4, lr = l & 15;
    const int wm = w >> 1, wn = w & 1;
    const int nb = blockIdx.y & 7;
    const int mb = blockIdx.x * 16 + (blockIdx.y >> 3);
    const int p0 = mb * 128;

    const int grow = w * 16 + (l >> 2);
    const int slot = l & 3;
    const int csrc = slot ^ ((grow >> 1) & 3);
    const bf16* Asrc0 = Apg + (size_t)(p0 + grow) * 2048 + csrc * 8;
    const bf16* Asrc1 = Apg + (size_t)(p0 + 64 + grow) * 2048 + csrc * 8;
    const bf16* Bsrc0 = Wt_a2 + (size_t)(nb * 128 + grow) * 2048 + csrc * 8;
    const bf16* Bsrc1 = Wt_a2 + (size_t)(nb * 128 + 64 + grow) * 2048 + csrc * 8;
    const int woff = w * 512;

    f32x4 acc[4][4] = {};

    gl_lds16(Asrc0, As[0] + woff);
    gl_lds16(Asrc1, As[0] + 2048 + woff);
    gl_lds16(Bsrc0, Bs[0] + woff);
    gl_lds16(Bsrc1, Bs[0] + 2048 + woff);
    __syncthreads();

    int cur = 0;
    for (int kt = 0; kt < 64; ++kt) {
        if (kt < 63) {
            int kn = (kt + 1) * 32;
            bf16* An = As[cur ^ 1];
            bf16* Bn = Bs[cur ^ 1];
            gl_lds16(Asrc0 + kn, An + woff);
            gl_lds16(Asrc1 + kn, An + 2048 + woff);
            gl_lds16(Bsrc0 + kn, Bn + woff);
            gl_lds16(Bsrc1 + kn, Bn + 2048 + woff);
        }
        const bf16* Ac = As[cur];
        const bf16* Bc = Bs[cur];
        bf16x8 af[4], bfr[4];
#pragma unroll
        for (int mi = 0; mi < 4; ++mi) {
            int row = wm * 64 + mi * 16 + lr;
            int sl = quad ^ ((row >> 1) & 3);
            af[mi] = *(const bf16x8*)&Ac[row * 32 + sl * 8];
        }
#pragma unroll
        for (int nj = 0; nj < 4; ++nj) {
            int row = wn * 64 + nj * 16 + lr;
            int sl = quad ^ ((row >> 1) & 3);
            bfr[nj] = *(const bf16x8*)&Bc[row * 32 + sl * 8];
        }
#pragma unroll
        for (int mi = 0; mi < 4; ++mi)
#pragma unroll
            for (int nj = 0; nj < 4; ++nj)
                acc[mi][nj] = __builtin_amdgcn_mfma_f32_16x16x32_bf16(
                    af[mi], bfr[nj], acc[mi][nj], 0, 0, 0);
        __syncthreads();
        cur ^= 1;
    }

    float w3v[4], b2v[4];
#pragma unroll
    for (int nj = 0; nj < 4; ++nj) {
        int col = nb * 128 + wn * 64 + nj * 16 + lr;
        w3v[nj] = (float)w_a3[col];
        b2v[nj] = (float)b_a2[col];
    }
#pragma unroll
    for (int mi = 0; mi < 4; ++mi) {
        f32x4 rs = {0.f, 0.f, 0.f, 0.f};
#pragma unroll
        for (int nj = 0; nj < 4; ++nj)
#pragma unroll
            for (int rr = 0; rr < 4; ++rr)
                rs[rr] += fmaxf(acc[mi][nj][rr] + b2v[nj], 0.f) * w3v[nj];
#pragma unroll
        for (int off = 1; off < 16; off <<= 1) {
            rs[0] += __shfl_xor(rs[0], off);
            rs[1] += __shfl_xor(rs[1], off);
            rs[2] += __shfl_xor(rs[2], off);
            rs[3] += __shfl_xor(rs[3], off);
        }
        if (lr == 0) {
            int p = p0 + wm * 64 + mi * 16 + quad * 4;
            int slot2 = nb * 2 + wn;
            slots[(size_t)(p + 0) * 16 + slot2] = rs[0];
            slots[(size_t)(p + 1) * 16 + slot2] = rs[1];
            slots[(size_t)(p + 2) * 16 + slot2] = rs[2];
            slots[(size_t)(p + 3) * 16 + slot2] = rs[3];
        }
    }
}

__global__ void adj_finalize(const float* __restrict__ slots,
                             const bf16* __restrict__ b_a3, float* __restrict__ adj)
{
    int i = blockIdx.x * 256 + threadIdx.x;
    float s = (float)b_a3[0];
#pragma unroll
    for (int k = 0; k < 16; ++k) s += slots[(size_t)i * 16 + k];
    adj[i] = 1.f / (1.f + expf(-s));
}

// one launch: of[:,1024:]=nsp; hf[:,1024:]=nsp[:64]; hf[:,:1024]=of[:64,:1024]
__global__ void setup_concat(const bf16* __restrict__ nsp_bf, const bf16* __restrict__ of_ro,
                             bf16* __restrict__ of, bf16* __restrict__ hf)
{
    int c = blockIdx.x * 256 + threadIdx.x;   // 0..1023
    int r = blockIdx.y;                        // 0..383
    if (r < 256) {
        of[(size_t)r * 2048 + 1024 + c] = nsp_bf[(size_t)r * 1024 + c];
    } else if (r < 320) {
        int rr = r - 256;
        hf[(size_t)rr * 2048 + 1024 + c] = nsp_bf[(size_t)rr * 1024 + c];
    } else {
        int rr = r - 320;
        hf[(size_t)rr * 2048 + c] = of_ro[(size_t)rr * 2048 + c];
    }
}

// fused: out[h,0:1024]=hf[h,:1024]; out[h,1024+e]=sum_n adj*obj_msg*(nsW_h-nsW_n)
__global__ void agg_o_kernel(const float* __restrict__ adj, const bf16* __restrict__ obj_msg,
                             const bf16* __restrict__ nsW, const bf16* __restrict__ hf,
                             bf16* __restrict__ out)
{
    int bx = blockIdx.x;                      // 0..7
    int h = blockIdx.y;
    int e = (bx & 3) * 256 + threadIdx.x;
    if (bx < 4) {
        out[(size_t)h * 2048 + e] = hf[(size_t)h * 2048 + e];
        return;
    }
    float nh = (float)nsW[h * 1024 + e];
    float s = 0.f;
    for (int n = 0; n < 256; ++n) {
        float a  = adj[h * 256 + n];
        float om = (float)obj_msg[n * 1024 + e];
        float nw = (float)nsW[n * 1024 + e];
        s += a * om * (nh - nw);
    }
    out[(size_t)h * 2048 + 1024 + e] = (bf16)s;
}

// fused: out[n,0:1024]=of[n,:1024]; out[n,1024+e]=sum_h adj*hum_msg*(nsW_n-nsW_h)
__global__ void agg_h_kernel(const float* __restrict__ adj, const bf16* __restrict__ hum_msg,
                             const bf16* __restrict__ nsW, const bf16* __restrict__ of,
                             bf16* __restrict__ out)
{
    int bx = blockIdx.x;                      // 0..7
    int n = blockIdx.y;
    int e = (bx & 3) * 256 + threadIdx.x;
    if (bx < 4) {
        out[(size_t)n * 2048 + e] = of[(size_t)n * 2048 + e];
        return;
    }
    float nn = (float)nsW[n * 1024 + e];
    float s = 0.f;
    for (int h = 0; h < 64; ++h) {
        float a  = adj[h * 256 + n];
        float hm = (float)hum_msg[h * 1024 + e];
        float nw = (float)nsW[h * 1024 + e];
        s += a * hm * (nn - nw);
    }
    out[(size_t)n * 2048 + 1024 + e] = (bf16)s;
}

// Output row r=(x,y): [h_enc[x] | nsp[x] | enc[y] | nsp[y] | prior(117)]
__global__ void out_kernel(const bf16* __restrict__ hf, const bf16* __restrict__ of,
                           const bf16* __restrict__ nsp_bf, const float* __restrict__ adj,
                           const bf16* __restrict__ scores_bf, const int* __restrict__ labels,
                           const int* __restrict__ cmask, void* __restrict__ out,
                           const int* __restrict__ dflag)
{
    const int f32 = *dflag;
    const int r = blockIdx.x;
    const int x = r / 255;
    const int tt = r % 255;
    const int y = tt + (tt >= x ? 1 : 0);
    const size_t rbase = (size_t)r * 4213;
    const bf16* seg[4] = { hf + (size_t)x * 2048, nsp_bf + x * 1024,
                           of + (size_t)y * 2048, nsp_bf + y * 1024 };
    const int t = threadIdx.x;

    float sx = (float)scores_bf[x], sy = (float)scores_bf[y];
    float lx = 8.3f / (1.f + expf(12.f - 10.f * sx));
    float ly = 8.3f / (1.f + expf(12.f - 10.f * sy));
    float pf = adj[x * 256 + y] * lx * ly;
    const int* cm = cmask + labels[y] * 117;

    auto getv = [&](int e) -> float {
        if (e < 4096) return (float)seg[e >> 10][e & 1023];
        return cm[e - 4096] ? pf : 0.f;
    };

    if (f32) {
        float* op = (float*)out + rbase;
        const int ali = (int)((4 - (rbase & 3)) & 3);
        const int nv = (4213 - ali) >> 2;
        for (int vi = t; vi < nv; vi += 256) {
            int e0 = ali + vi * 4;
            f32x4 v = { getv(e0), getv(e0 + 1), getv(e0 + 2), getv(e0 + 3) };
            *(f32x4*)(op + e0) = v;
        }
        if (t < ali) op[t] = getv(t);
        int te = ali + nv * 4;
        if (t < 4213 - te) op[te + t] = getv(te + t);
    } else {
        bf16* op = (bf16*)out + rbase;
        for (int e = t; e < 4213; e += 256) op[e] = (bf16)getv(e);
    }
}

// ---------------------------------------------------------------------------
extern "C" void kernel_launch(void* const* d_in, const int* in_sizes, int n_in,
                              void* d_out, int out_size, void* d_ws, size_t ws_size,
                              hipStream_t stream)
{
    (void)in_sizes; (void)n_in; (void)out_size; (void)ws_size;
    const void* box    = d_in[0];
    const void* nsp    = d_in[1];
    const void* scores = d_in[2];
    const int*  labels = (const int*)d_in[3];
    const int*  cmask  = (const int*)d_in[4];
    const void* W_bh1 = d_in[5],  *b_bh1 = d_in[6];
    const void* W_bh2 = d_in[7],  *b_bh2 = d_in[8];
    const void* W_sa  = d_in[9];
    const void* W_a1  = d_in[10], *b_a1  = d_in[11];
    const void* W_a2  = d_in[12], *b_a2  = d_in[13];
    const void* W_a3  = d_in[14], *b_a3  = d_in[15];
    const void* W_hm  = d_in[16], *b_hm  = d_in[17];
    const void* W_om  = d_in[18], *b_om  = d_in[19];
    const void* W_hu  = d_in[20];
    const void* W_ou  = d_in[21];

    char* ws = (char*)d_ws;
    size_t off = 0;
    auto alloc = [&](size_t bytes) -> void* {
        off = (off + 255) & ~(size_t)255;
        void* p = ws + off;
        off += bytes;
        return p;
    };
    int*  dflag   = (int*)alloc(4);
    bf16* box_bf  = (bf16*)alloc((size_t)256 * 12544 * 2);
    bf16* nsp_bf  = (bf16*)alloc((size_t)256 * 1024 * 2);
    bf16* Wt_a2   = (bf16*)alloc((size_t)1024 * 2048 * 2);
    bf16* smalls  = (bf16*)alloc((size_t)8464 * 2);
    bf16* sb_bh1 = smalls,        *sb_bh2 = smalls + 1024;
    bf16* sb_om  = smalls + 2048, *sb_hm  = smalls + 3072;
    bf16* sb_a1  = smalls + 4096, *sb_a2  = smalls + 6144;
    bf16* sw_a3  = smalls + 7168, *sb_a3  = smalls + 8192;
    bf16* sscore = smalls + 8208;
    bf16* t0      = (bf16*)alloc((size_t)256 * 1024 * 2);
    bf16* nsW     = (bf16*)alloc((size_t)256 * 1024 * 2);
    bf16* hf      = (bf16*)alloc((size_t)64 * 2048 * 2);   // [h_enc | nsp[:64]]
    bf16* of      = (bf16*)alloc((size_t)256 * 2048 * 2);  // [enc   | nsp]
    float* Hpart  = (float*)alloc((size_t)64 * 2048 * 4);
    float* Opart  = (float*)alloc((size_t)256 * 2048 * 4);
    float* slots  = (float*)alloc((size_t)16384 * 16 * 4);
    float* adj    = (float*)alloc((size_t)16384 * 4);
    bf16* obj_msg = (bf16*)alloc((size_t)256 * 1024 * 2);
    bf16* hu_in   = (bf16*)alloc((size_t)64 * 2048 * 2);
    bf16* hum_msg = (bf16*)alloc((size_t)64 * 1024 * 2);
    bf16* ou_in   = (bf16*)alloc((size_t)256 * 2048 * 2);
    float* part   = (float*)alloc((size_t)2097152 * 4);        // split-K partials (8 MB)
    bf16* A_bf    = (bf16*)alloc((size_t)16384 * 2048 * 2);    // pair activations (64 MB)

    // 1) dtype probe
    init_flag<<<1, 1, 0, stream>>>(dflag);
    detect_kernel<<<256, 256, 0, stream>>>((const unsigned short*)box, 524288, dflag);

    // 2) convert box + nsp + all smalls (ONE launch)
    cvt_fused<<<(CVT_V1 + CVT_V2 + 8464 + 255) / 256, 256, 0, stream>>>(
        box, box_bf, nsp, nsp_bf, b_bh1, b_bh2, b_om, b_hm, b_a1, b_a2,
        W_a3, b_a3, scores, smalls, dflag);

    // 3) W_a2 -> bf16 transposed (hot operand of pair_gemm, re-read 128x)
    transpose_any<<<dim3(1024 / 32, 2048 / 32), dim3(32, 8), 0, stream>>>(
        W_a2, Wt_a2, 2048, 1024, dflag);

    // 4) enc = relu(relu(box@W_bh1+b)@W_bh2+b) -> of[:, :1024]; nsW = nsp@W_sa
    gemm_p<<<dim3(16, 4, 8), 256, 0, stream>>>(box_bf, 12544, W_bh1, 0, 1024, part, 1024, 1568, dflag);
    reduce_k<true, true, false><<<dim3(256), 256, 0, stream>>>(part, 8, 262144, sb_bh1, t0, 1024, 1024);
    gemm_p<<<dim3(16, 4, 4), 256, 0, stream>>>(t0, 1024, W_bh2, 0, 1024, part, 1024, 256, dflag);
    reduce_k<true, true, false><<<dim3(256), 256, 0, stream>>>(part, 4, 262144, sb_bh2, of, 1024, 2048);
    gemm_p<<<dim3(16, 4, 4), 256, 0, stream>>>(nsp_bf, 1024, W_sa, 0, 1024, part, 1024, 256, dflag);
    reduce_k<false, false, false><<<dim3(256), 256, 0, stream>>>(part, 4, 262144, nullptr, nsW, 1024, 1024);
    // one-time nsp halves of hf/of + h_enc init (ONE launch)
    setup_concat<<<dim3(4, 384), 256, 0, stream>>>(nsp_bf, of, of, hf);

    for (int it = 0; it < 2; ++it) {
        // Hpart = hf @ W_a1[:2048,:] (+ b_a1 folded), Opart = of @ W_a1[2048:,:]
        gemm_p<<<dim3(32, 1, 8), 256, 0, stream>>>(hf, 2048, W_a1, 0, 2048, part, 2048, 256, dflag);
        reduce_k<false, true, true><<<dim3(128), 256, 0, stream>>>(part, 8, 131072, sb_a1, Hpart, 2048, 2048);
        gemm_p<<<dim3(32, 4, 4), 256, 0, stream>>>(of, 2048, W_a1, (size_t)2048 * 2048, 2048, part, 2048, 512, dflag);
        reduce_k<false, false, true><<<dim3(512), 256, 0, stream>>>(part, 4, 524288, nullptr, Opart, 2048, 2048);
        // A_bf[p,k] = bf16(relu(Hpart[h,k] + Opart[n,k]))
        build_pairA<<<dim3(256, 64), 256, 0, stream>>>(Hpart, Opart, A_bf);
        // adj = sigmoid(pair MLP)
        pair_gemm<<<dim3(8, 128), 256, 0, stream>>>(A_bf, Wt_a2, sb_a2, sw_a3, slots);
        adj_finalize<<<dim3(64), 256, 0, stream>>>(slots, sb_a3, adj);
        // obj_msg = relu(enc @ W_om + b)   (enc = of left half, lda 2048)
        gemm_p<<<dim3(16, 4, 4), 256, 0, stream>>>(of, 2048, W_om, 0, 1024, part, 1024, 256, dflag);
        reduce_k<true, true, false><<<dim3(256), 256, 0, stream>>>(part, 4, 262144, sb_om, obj_msg, 1024, 1024);
        // h_enc = [h_enc | agg_o] @ W_hu -> hf[:, :1024]
        agg_o_kernel<<<dim3(8, 64), 256, 0, stream>>>(adj, obj_msg, nsW, hf, hu_in);
        gemm_p<<<dim3(16, 1, 16), 256, 0, stream>>>(hu_in, 2048, W_hu, 0, 1024, part, 1024, 128, dflag);
        reduce_k<false, false, false><<<dim3(64), 256, 0, stream>>>(part, 16, 65536, nullptr, hf, 1024, 2048);
        // hum_msg = relu(h_enc @ W_hm + b)   (h_enc = hf left half)
        gemm_p<<<dim3(16, 1, 16), 256, 0, stream>>>(hf, 2048, W_hm, 0, 1024, part, 1024, 64, dflag);
        reduce_k<true, true, false><<<dim3(64), 256, 0, stream>>>(part, 16, 65536, sb_hm, hum_msg, 1024, 1024);
        // enc = [enc | agg_h] @ W_ou -> of[:, :1024]
        agg_h_kernel<<<dim3(8, 256), 256, 0, stream>>>(adj, hum_msg, nsW, of, ou_in);
        gemm_p<<<dim3(16, 4, 4), 256, 0, stream>>>(ou_in, 2048, W_ou, 0, 1024, part, 1024, 512, dflag);
        reduce_k<false, false, false><<<dim3(256), 256, 0, stream>>>(part, 4, 262144, nullptr, of, 1024, 2048);
    }

    out_kernel<<<dim3(16320), 256, 0, stream>>>(
        hf, of, nsp_bf, adj, sscore, labels, cmask, d_out, dflag);
}

// Round 7
// 931.162 us; speedup vs baseline: 2.5788x; 1.0357x over previous
//
#include <hip/hip_runtime.h>

using bf16 = __bf16;
typedef __bf16 bf16x4 __attribute__((ext_vector_type(4)));
typedef __bf16 bf16x8 __attribute__((ext_vector_type(8)));
typedef float  f32x4  __attribute__((ext_vector_type(4)));

#define GST 40  // gemm_p LDS row stride (80 B -> 16B-aligned b128 reads)

// ---- dtype-dispatched access helpers (flag: 1 = inputs are fp32, 0 = bf16) --
__device__ __forceinline__ float ldf(const void* p, size_t i, int f32) {
    return f32 ? ((const float*)p)[i] : (float)((const bf16*)p)[i];
}
__device__ __forceinline__ bf16x8 ld8(const void* p, size_t i, int f32) {
    bf16x8 r;
    if (f32) {
        f32x4 a = *(const f32x4*)((const float*)p + i);
        f32x4 b = *(const f32x4*)((const float*)p + i + 4);
#pragma unroll
        for (int j = 0; j < 4; ++j) { r[j] = (bf16)a[j]; r[j + 4] = (bf16)b[j]; }
    } else {
        r = *(const bf16x8*)((const bf16*)p + i);
    }
    return r;
}
__device__ __forceinline__ void st1(void* p, size_t i, float v, int f32) {
    if (f32) ((float*)p)[i] = v;
    else     ((bf16*)p)[i] = (bf16)v;
}

// ---- async global->LDS, 16B per lane (dest = wave-uniform base + lane*16) --
__device__ __forceinline__ void gl_lds16(const bf16* g, bf16* l) {
    __builtin_amdgcn_global_load_lds(
        (const __attribute__((address_space(1))) void*)g,
        (__attribute__((address_space(3))) void*)l, 16, 0, 0);
}

// ---- detect: bf16 NaN/Inf bit patterns exist iff backing store is fp32 -----
__global__ void init_flag(int* __restrict__ dflag) { *dflag = 0; }

__global__ void detect_kernel(const unsigned short* __restrict__ p, int n,
                              int* __restrict__ dflag)
{
    const unsigned int* q = (const unsigned int*)p;
    const int nw = n >> 1;
    int hit = 0;
    for (int i = blockIdx.x * 256 + threadIdx.x; i < nw; i += gridDim.x * 256) {
        unsigned int w = q[i];
        if ((w & 0x7F80u) == 0x7F80u || (w & 0x7F800000u) == 0x7F800000u) hit = 1;
    }
    if (__any(hit) && (threadIdx.x & 63) == 0) atomicOr(dflag, 1);
}

// ---- ONE launch converts box + nsp (8-elem vector chunks) + all smalls -----
#define CVT_V1 401408   // 256*12544/8 chunks (box)
#define CVT_V2 32768    // 256*1024/8 chunks (nsp)
__global__ void cvt_fused(const void* __restrict__ box, bf16* __restrict__ box_bf,
                          const void* __restrict__ nsp, bf16* __restrict__ nsp_bf,
                          const void* b_bh1, const void* b_bh2, const void* b_om,
                          const void* b_hm, const void* b_a1, const void* b_a2,
                          const void* w_a3, const void* b_a3, const void* scores,
                          bf16* __restrict__ smalls, const int* __restrict__ dflag)
{
    const int f32 = *dflag;
    int i = blockIdx.x * 256 + threadIdx.x;
    if (i < CVT_V1) {
        bf16x8 v = ld8(box, (size_t)i * 8, f32);
        *(bf16x8*)(box_bf + (size_t)i * 8) = v;
        return;
    }
    i -= CVT_V1;
    if (i < CVT_V2) {
        bf16x8 v = ld8(nsp, (size_t)i * 8, f32);
        *(bf16x8*)(nsp_bf + (size_t)i * 8) = v;
        return;
    }
    i -= CVT_V2;
    const void* s; int off;
    if      (i < 1024) { s = b_bh1; off = 0;    }
    else if (i < 2048) { s = b_bh2; off = 1024; }
    else if (i < 3072) { s = b_om;  off = 2048; }
    else if (i < 4096) { s = b_hm;  off = 3072; }
    else if (i < 6144) { s = b_a1;  off = 4096; }
    else if (i < 7168) { s = b_a2;  off = 6144; }
    else if (i < 8192) { s = w_a3;  off = 7168; }
    else if (i < 8193) { s = b_a3;  off = 8192; }
    else if (i >= 8208 && i < 8464) { s = scores; off = 8208; }
    else return;
    smalls[i] = (bf16)ldf(s, i - off, f32);
}

// ---- transpose input weight (KxN) -> bf16 Wt (NxK) -------------------------
__global__ void transpose_any(const void* __restrict__ W, bf16* __restrict__ Wt,
                              int K, int N, const int* __restrict__ dflag)
{
    __shared__ bf16 tile[32][33];
    const int f32 = *dflag;
    const int n0 = blockIdx.x * 32, k0 = blockIdx.y * 32;
    const int tx = threadIdx.x, ty = threadIdx.y;  // (32, 8)
#pragma unroll
    for (int i = 0; i < 4; ++i)
        tile[ty + i * 8][tx] = (bf16)ldf(W, (size_t)(k0 + ty + i * 8) * N + n0 + tx, f32);
    __syncthreads();
#pragma unroll
    for (int i = 0; i < 4; ++i)
        Wt[(size_t)(n0 + ty + i * 8) * K + k0 + tx] = tile[tx][ty + i * 8];
}

// ---------------------------------------------------------------------------
// Split-K bf16 MFMA GEMM -> fp32 partials (B is dtype-dispatched).
// ---------------------------------------------------------------------------
__global__ __launch_bounds__(256)
void gemm_p(const bf16* __restrict__ A, int lda,
            const void* __restrict__ B, size_t boff, int ldb,
            float* __restrict__ part, int N, int Kc,
            const int* __restrict__ dflag)
{
    __shared__ bf16 As[2][64 * GST];
    __shared__ bf16 Bs[2][64 * GST];
    const int f32 = *dflag;
    const int t = threadIdx.x;
    const int l = t & 63;
    const int quad = l >> 4, lr = l & 15;
    const int w = t >> 6, wm = w >> 1, wn = w & 1;
    const int mBlock = blockIdx.y * 64, nBlock = blockIdx.x * 64;
    const int ar = t >> 2, ac = (t & 3) * 8;      // A-stage coords
    const int kr = t >> 3, nc = (t & 7) * 8;      // B-stage coords
    const int kBeg = blockIdx.z * Kc;
    const int nIter = Kc >> 5;

    f32x4 acc[2][2] = {};

    {
        bf16x8 avr = *(const bf16x8*)(A + (size_t)(mBlock + ar) * lda + kBeg + ac);
        bf16x8 bvr = ld8(B, boff + (size_t)(kBeg + kr) * ldb + nBlock + nc, f32);
        *(bf16x8*)&As[0][ar * GST + ac] = avr;
#pragma unroll
        for (int j = 0; j < 8; ++j) {
            int wr = nc + j;
            Bs[0][wr * GST + (kr ^ (((wr >> 3) & 3) << 3))] = bvr[j];
        }
    }
    __syncthreads();

    int cur = 0;
    for (int it = 0; it < nIter; ++it) {
        const bool more = (it + 1 < nIter);
        bf16x8 av2, bv2;
        if (more) {
            int k0 = kBeg + (it + 1) * 32;
            av2 = *(const bf16x8*)(A + (size_t)(mBlock + ar) * lda + k0 + ac);
            bv2 = ld8(B, boff + (size_t)(k0 + kr) * ldb + nBlock + nc, f32);
        }
        const bf16* Ac = As[cur];
        const bf16* Bc = Bs[cur];
        bf16x8 af[2], bfr[2];
#pragma unroll
        for (int mi = 0; mi < 2; ++mi)
            af[mi] = *(const bf16x8*)&Ac[(wm * 32 + mi * 16 + lr) * GST + quad * 8];
#pragma unroll
        for (int nj = 0; nj < 2; ++nj) {
            int row = wn * 32 + nj * 16 + lr;
            bfr[nj] = *(const bf16x8*)&Bc[row * GST + ((quad * 8) ^ (((row >> 3) & 3) << 3))];
        }
#pragma unroll
        for (int mi = 0; mi < 2; ++mi)
#pragma unroll
            for (int nj = 0; nj < 2; ++nj)
                acc[mi][nj] = __builtin_amdgcn_mfma_f32_16x16x32_bf16(
                    af[mi], bfr[nj], acc[mi][nj], 0, 0, 0);
        if (more) {
            bf16* An = As[cur ^ 1];
            bf16* Bn = Bs[cur ^ 1];
            *(bf16x8*)&An[ar * GST + ac] = av2;
#pragma unroll
            for (int j = 0; j < 8; ++j) {
                int wr = nc + j;
                Bn[wr * GST + (kr ^ (((wr >> 3) & 3) << 3))] = bv2[j];
            }
        }
        __syncthreads();
        cur ^= 1;
    }

    float* outp = part + (size_t)blockIdx.z * ((size_t)gridDim.y * 64 * N);
#pragma unroll
    for (int mi = 0; mi < 2; ++mi)
#pragma unroll
        for (int nj = 0; nj < 2; ++nj) {
            int col = nBlock + wn * 32 + nj * 16 + lr;
#pragma unroll
            for (int rr = 0; rr < 4; ++rr) {
                int row = mBlock + wm * 32 + mi * 16 + quad * 4 + rr;
                outp[(size_t)row * N + col] = acc[mi][nj][rr];
            }
        }
}

// ---- reduce split-K partials, apply bias/relu, write (strided) out ---------
template<bool RELU, bool BIAS, bool F32OUT>
__global__ void reduce_k(const float* __restrict__ part, int S, int total,
                         const bf16* __restrict__ bias, void* __restrict__ out,
                         int N, int ldd)
{
    int base = (blockIdx.x * 256 + threadIdx.x) * 4;
    if (base >= total) return;
    f32x4 s = *(const f32x4*)(part + base);
    for (int z = 1; z < S; ++z) {
        f32x4 v = *(const f32x4*)(part + (size_t)z * total + base);
        s[0] += v[0]; s[1] += v[1]; s[2] += v[2]; s[3] += v[3];
    }
    int row = base / N, col = base % N;
    size_t ob = (size_t)row * ldd + col;
#pragma unroll
    for (int j = 0; j < 4; ++j) {
        float v = s[j];
        if (BIAS) v += (float)bias[col + j];
        if (RELU) v = fmaxf(v, 0.f);
        if (F32OUT) ((float*)out)[ob + j] = v;
        else        ((bf16*)out)[ob + j] = (bf16)v;
    }
}

// ---- A_bf[p=(h,n), k] = bf16(relu(Hb[h,k] + Op[n,k])), Hb has b_a1 folded --
__global__ void build_pairA(const float* __restrict__ Hb, const float* __restrict__ Op,
                            bf16* __restrict__ A)
{
    const int n = blockIdx.x;        // 256
    const int h = blockIdx.y;        // 64
    const int k = threadIdx.x * 8;   // 256 threads x 8 = 2048
    const float* hp = Hb + (size_t)h * 2048 + k;
    const float* op = Op + (size_t)n * 2048 + k;
    f32x4 h0 = *(const f32x4*)hp, h1 = *(const f32x4*)(hp + 4);
    f32x4 o0 = *(const f32x4*)op, o1 = *(const f32x4*)(op + 4);
    bf16x8 r;
#pragma unroll
    for (int j = 0; j < 4; ++j) {
        r[j]     = (bf16)fmaxf(h0[j] + o0[j], 0.f);
        r[j + 4] = (bf16)fmaxf(h1[j] + o1[j], 0.f);
    }
    *(bf16x8*)(A + ((size_t)h * 256 + n) * 2048 + k) = r;
}

// ---------------------------------------------------------------------------
// Pure-GEMM pair MLP — T4 counted-vmcnt pipeline: 3-deep LDS buffer rotation,
// ONE raw s_barrier per K-step, s_waitcnt vmcnt(4) (never 0 in the loop) so
// prefetch gl_lds stay in flight ACROSS the barrier (AITER pattern).
// Per iter kt: vmcnt(4) [tile kt landed; kt+1 in flight] -> s_barrier ->
// ds_read+MFMA buf[kt%3] -> issue 4 gl_lds for tile kt+2 into buf[(kt+2)%3].
// Buffer-b writes (tile t+2, issued iter t) land only after the iter-t
// barrier, by which b's last reader (iter t-1) has consumed its MFMAs: safe.
// Tail wraps write dead buffers; reads stay inside d_ws. LDS 48 KB.
// ---------------------------------------------------------------------------
__global__ __launch_bounds__(256)
void pair_gemm(const bf16* __restrict__ Apg, const bf16* __restrict__ Wt_a2,
               const bf16* __restrict__ b_a2, const bf16* __restrict__ w_a3,
               float* __restrict__ slots)
{
    __shared__ bf16 As[3][128 * 32];
    __shared__ bf16 Bs[3][128 * 32];
    const int t = threadIdx.x;
    const int l = t & 63, w = t >> 6;
    const int quad = l >> 4, lr = l & 15;
    const int wm = w >> 1, wn = w & 1;
    const int nb = blockIdx.y & 7;
    const int mb = blockIdx.x * 16 + (blockIdx.y >> 3);
    const int p0 = mb * 128;

    const int grow = w * 16 + (l >> 2);
    const int slot = l & 3;
    const int csrc = slot ^ ((grow >> 1) & 3);
    const bf16* Asrc0 = Apg + (size_t)(p0 + grow) * 2048 + csrc * 8;
    const bf16* Asrc1 = Apg + (size_t)(p0 + 64 + grow) * 2048 + csrc * 8;
    const bf16* Bsrc0 = Wt_a2 + (size_t)(nb * 128 + grow) * 2048 + csrc * 8;
    const bf16* Bsrc1 = Wt_a2 + (size_t)(nb * 128 + 64 + grow) * 2048 + csrc * 8;
    const int woff = w * 512;

    f32x4 acc[4][4] = {};

    // prologue: stage tiles 0 and 1 (4 loads each per wave)
    gl_lds16(Asrc0, As[0] + woff);
    gl_lds16(Asrc1, As[0] + 2048 + woff);
    gl_lds16(Bsrc0, Bs[0] + woff);
    gl_lds16(Bsrc1, Bs[0] + 2048 + woff);
    gl_lds16(Asrc0 + 32, As[1] + woff);
    gl_lds16(Asrc1 + 32, As[1] + 2048 + woff);
    gl_lds16(Bsrc0 + 32, Bs[1] + woff);
    gl_lds16(Bsrc1 + 32, Bs[1] + 2048 + woff);

    int cur = 0;        // buffer holding tile kt
    int nxt2 = 2;       // buffer for tile kt+2
    for (int kt = 0; kt < 64; ++kt) {
        // wait: my 4 tile-kt loads done (4 newest = tile kt+1 stay in flight)
        asm volatile("s_waitcnt vmcnt(4)" ::: "memory");
        __builtin_amdgcn_s_barrier();          // all waves' tile-kt loads landed
        __builtin_amdgcn_sched_barrier(0);

        const bf16* Ac = As[cur];
        const bf16* Bc = Bs[cur];
        bf16x8 af[4], bfr[4];
#pragma unroll
        for (int mi = 0; mi < 4; ++mi) {
            int row = wm * 64 + mi * 16 + lr;
            int sl = quad ^ ((row >> 1) & 3);
            af[mi] = *(const bf16x8*)&Ac[row * 32 + sl * 8];
        }
#pragma unroll
        for (int nj = 0; nj < 4; ++nj) {
            int row = wn * 64 + nj * 16 + lr;
            int sl = quad ^ ((row >> 1) & 3);
            bfr[nj] = *(const bf16x8*)&Bc[row * 32 + sl * 8];
        }
#pragma unroll
        for (int mi = 0; mi < 4; ++mi)
#pragma unroll
            for (int nj = 0; nj < 4; ++nj)
                acc[mi][nj] = __builtin_amdgcn_mfma_f32_16x16x32_bf16(
                    af[mi], bfr[nj], acc[mi][nj], 0, 0, 0);

        // issue tile kt+2 (wraps harmlessly into dead buffers at the tail)
        {
            int kn = ((kt + 2) & 63) * 32;
            bf16* An = As[nxt2];
            bf16* Bn = Bs[nxt2];
            gl_lds16(Asrc0 + kn, An + woff);
            gl_lds16(Asrc1 + kn, An + 2048 + woff);
            gl_lds16(Bsrc0 + kn, Bn + woff);
            gl_lds16(Bsrc1 + kn, Bn + 2048 + woff);
        }
        cur = (cur == 2) ? 0 : cur + 1;
        nxt2 = (nxt2 == 2) ? 0 : nxt2 + 1;
    }

    float w3v[4], b2v[4];
#pragma unroll
    for (int nj = 0; nj < 4; ++nj) {
        int col = nb * 128 + wn * 64 + nj * 16 + lr;
        w3v[nj] = (float)w_a3[col];
        b2v[nj] = (float)b_a2[col];
    }
#pragma unroll
    for (int mi = 0; mi < 4; ++mi) {
        f32x4 rs = {0.f, 0.f, 0.f, 0.f};
#pragma unroll
        for (int nj = 0; nj < 4; ++nj)
#pragma unroll
            for (int rr = 0; rr < 4; ++rr)
                rs[rr] += fmaxf(acc[mi][nj][rr] + b2v[nj], 0.f) * w3v[nj];
#pragma unroll
        for (int off = 1; off < 16; off <<= 1) {
            rs[0] += __shfl_xor(rs[0], off);
            rs[1] += __shfl_xor(rs[1], off);
            rs[2] += __shfl_xor(rs[2], off);
            rs[3] += __shfl_xor(rs[3], off);
        }
        if (lr == 0) {
            int p = p0 + wm * 64 + mi * 16 + quad * 4;
            int slot2 = nb * 2 + wn;
            slots[(size_t)(p + 0) * 16 + slot2] = rs[0];
            slots[(size_t)(p + 1) * 16 + slot2] = rs[1];
            slots[(size_t)(p + 2) * 16 + slot2] = rs[2];
            slots[(size_t)(p + 3) * 16 + slot2] = rs[3];
        }
    }
}

__global__ void adj_finalize(const float* __restrict__ slots,
                             const bf16* __restrict__ b_a3, float* __restrict__ adj)
{
    int i = blockIdx.x * 256 + threadIdx.x;
    float s = (float)b_a3[0];
#pragma unroll
    for (int k = 0; k < 16; ++k) s += slots[(size_t)i * 16 + k];
    adj[i] = 1.f / (1.f + expf(-s));
}

// one launch: of[:,1024:]=nsp; hf[:,1024:]=nsp[:64]; hf[:,:1024]=of[:64,:1024]
__global__ void setup_concat(const bf16* __restrict__ nsp_bf, const bf16* __restrict__ of_ro,
                             bf16* __restrict__ of, bf16* __restrict__ hf)
{
    int c = blockIdx.x * 256 + threadIdx.x;   // 0..1023
    int r = blockIdx.y;                        // 0..383
    if (r < 256) {
        of[(size_t)r * 2048 + 1024 + c] = nsp_bf[(size_t)r * 1024 + c];
    } else if (r < 320) {
        int rr = r - 256;
        hf[(size_t)rr * 2048 + 1024 + c] = nsp_bf[(size_t)rr * 1024 + c];
    } else {
        int rr = r - 320;
        hf[(size_t)rr * 2048 + c] = of_ro[(size_t)rr * 2048 + c];
    }
}

// fused: out[h,0:1024]=hf[h,:1024]; out[h,1024+e]=sum_n adj*obj_msg*(nsW_h-nsW_n)
__global__ void agg_o_kernel(const float* __restrict__ adj, const bf16* __restrict__ obj_msg,
                             const bf16* __restrict__ nsW, const bf16* __restrict__ hf,
                             bf16* __restrict__ out)
{
    int bx = blockIdx.x;                      // 0..7
    int h = blockIdx.y;
    int e = (bx & 3) * 256 + threadIdx.x;
    if (bx < 4) {
        out[(size_t)h * 2048 + e] = hf[(size_t)h * 2048 + e];
        return;
    }
    float nh = (float)nsW[h * 1024 + e];
    float s = 0.f;
    for (int n = 0; n < 256; ++n) {
        float a  = adj[h * 256 + n];
        float om = (float)obj_msg[n * 1024 + e];
        float nw = (float)nsW[n * 1024 + e];
        s += a * om * (nh - nw);
    }
    out[(size_t)h * 2048 + 1024 + e] = (bf16)s;
}

// fused: out[n,0:1024]=of[n,:1024]; out[n,1024+e]=sum_h adj*hum_msg*(nsW_n-nsW_h)
__global__ void agg_h_kernel(const float* __restrict__ adj, const bf16* __restrict__ hum_msg,
                             const bf16* __restrict__ nsW, const bf16* __restrict__ of,
                             bf16* __restrict__ out)
{
    int bx = blockIdx.x;                      // 0..7
    int n = blockIdx.y;
    int e = (bx & 3) * 256 + threadIdx.x;
    if (bx < 4) {
        out[(size_t)n * 2048 + e] = of[(size_t)n * 2048 + e];
        return;
    }
    float nn = (float)nsW[n * 1024 + e];
    float s = 0.f;
    for (int h = 0; h < 64; ++h) {
        float a  = adj[h * 256 + n];
        float hm = (float)hum_msg[h * 1024 + e];
        float nw = (float)nsW[h * 1024 + e];
        s += a * hm * (nn - nw);
    }
    out[(size_t)n * 2048 + 1024 + e] = (bf16)s;
}

// Output row r=(x,y): [h_enc[x] | nsp[x] | enc[y] | nsp[y] | prior(117)]
__global__ void out_kernel(const bf16* __restrict__ hf, const bf16* __restrict__ of,
                           const bf16* __restrict__ nsp_bf, const float* __restrict__ adj,
                           const bf16* __restrict__ scores_bf, const int* __restrict__ labels,
                           const int* __restrict__ cmask, void* __restrict__ out,
                           const int* __restrict__ dflag)
{
    const int f32 = *dflag;
    const int r = blockIdx.x;
    const int x = r / 255;
    const int tt = r % 255;
    const int y = tt + (tt >= x ? 1 : 0);
    const size_t rbase = (size_t)r * 4213;
    const bf16* seg[4] = { hf + (size_t)x * 2048, nsp_bf + x * 1024,
                           of + (size_t)y * 2048, nsp_bf + y * 1024 };
    const int t = threadIdx.x;

    float sx = (float)scores_bf[x], sy = (float)scores_bf[y];
    float lx = 8.3f / (1.f + expf(12.f - 10.f * sx));
    float ly = 8.3f / (1.f + expf(12.f - 10.f * sy));
    float pf = adj[x * 256 + y] * lx * ly;
    const int* cm = cmask + labels[y] * 117;

    auto getv = [&](int e) -> float {
        if (e < 4096) return (float)seg[e >> 10][e & 1023];
        return cm[e - 4096] ? pf : 0.f;
    };

    if (f32) {
        float* op = (float*)out + rbase;
        const int ali = (int)((4 - (rbase & 3)) & 3);
        const int nv = (4213 - ali) >> 2;
        for (int vi = t; vi < nv; vi += 256) {
            int e0 = ali + vi * 4;
            f32x4 v = { getv(e0), getv(e0 + 1), getv(e0 + 2), getv(e0 + 3) };
            *(f32x4*)(op + e0) = v;
        }
        if (t < ali) op[t] = getv(t);
        int te = ali + nv * 4;
        if (t < 4213 - te) op[te + t] = getv(te + t);
    } else {
        bf16* op = (bf16*)out + rbase;
        for (int e = t; e < 4213; e += 256) op[e] = (bf16)getv(e);
    }
}

// ---------------------------------------------------------------------------
extern "C" void kernel_launch(void* const* d_in, const int* in_sizes, int n_in,
                              void* d_out, int out_size, void* d_ws, size_t ws_size,
                              hipStream_t stream)
{
    (void)in_sizes; (void)n_in; (void)out_size; (void)ws_size;
    const void* box    = d_in[0];
    const void* nsp    = d_in[1];
    const void* scores = d_in[2];
    const int*  labels = (const int*)d_in[3];
    const int*  cmask  = (const int*)d_in[4];
    const void* W_bh1 = d_in[5],  *b_bh1 = d_in[6];
    const void* W_bh2 = d_in[7],  *b_bh2 = d_in[8];
    const void* W_sa  = d_in[9];
    const void* W_a1  = d_in[10], *b_a1  = d_in[11];
    const void* W_a2  = d_in[12], *b_a2  = d_in[13];
    const void* W_a3  = d_in[14], *b_a3  = d_in[15];
    const void* W_hm  = d_in[16], *b_hm  = d_in[17];
    const void* W_om  = d_in[18], *b_om  = d_in[19];
    const void* W_hu  = d_in[20];
    const void* W_ou  = d_in[21];

    char* ws = (char*)d_ws;
    size_t off = 0;
    auto alloc = [&](size_t bytes) -> void* {
        off = (off + 255) & ~(size_t)255;
        void* p = ws + off;
        off += bytes;
        return p;
    };
    int*  dflag   = (int*)alloc(4);
    bf16* box_bf  = (bf16*)alloc((size_t)256 * 12544 * 2);
    bf16* nsp_bf  = (bf16*)alloc((size_t)256 * 1024 * 2);
    bf16* Wt_a2   = (bf16*)alloc((size_t)1024 * 2048 * 2);
    bf16* smalls  = (bf16*)alloc((size_t)8464 * 2);
    bf16* sb_bh1 = smalls,        *sb_bh2 = smalls + 1024;
    bf16* sb_om  = smalls + 2048, *sb_hm  = smalls + 3072;
    bf16* sb_a1  = smalls + 4096, *sb_a2  = smalls + 6144;
    bf16* sw_a3  = smalls + 7168, *sb_a3  = smalls + 8192;
    bf16* sscore = smalls + 8208;
    bf16* t0      = (bf16*)alloc((size_t)256 * 1024 * 2);
    bf16* nsW     = (bf16*)alloc((size_t)256 * 1024 * 2);
    bf16* hf      = (bf16*)alloc((size_t)64 * 2048 * 2);   // [h_enc | nsp[:64]]
    bf16* of      = (bf16*)alloc((size_t)256 * 2048 * 2);  // [enc   | nsp]
    float* Hpart  = (float*)alloc((size_t)64 * 2048 * 4);
    float* Opart  = (float*)alloc((size_t)256 * 2048 * 4);
    float* slots  = (float*)alloc((size_t)16384 * 16 * 4);
    float* adj    = (float*)alloc((size_t)16384 * 4);
    bf16* obj_msg = (bf16*)alloc((size_t)256 * 1024 * 2);
    bf16* hu_in   = (bf16*)alloc((size_t)64 * 2048 * 2);
    bf16* hum_msg = (bf16*)alloc((size_t)64 * 1024 * 2);
    bf16* ou_in   = (bf16*)alloc((size_t)256 * 2048 * 2);
    float* part   = (float*)alloc((size_t)2097152 * 4);        // split-K partials (8 MB)
    bf16* A_bf    = (bf16*)alloc((size_t)16384 * 2048 * 2);    // pair activations (64 MB)

    // 1) dtype probe
    init_flag<<<1, 1, 0, stream>>>(dflag);
    detect_kernel<<<256, 256, 0, stream>>>((const unsigned short*)box, 524288, dflag);

    // 2) convert box + nsp + all smalls (ONE launch)
    cvt_fused<<<(CVT_V1 + CVT_V2 + 8464 + 255) / 256, 256, 0, stream>>>(
        box, box_bf, nsp, nsp_bf, b_bh1, b_bh2, b_om, b_hm, b_a1, b_a2,
        W_a3, b_a3, scores, smalls, dflag);

    // 3) W_a2 -> bf16 transposed (hot operand of pair_gemm, re-read 128x)
    transpose_any<<<dim3(1024 / 32, 2048 / 32), dim3(32, 8), 0, stream>>>(
        W_a2, Wt_a2, 2048, 1024, dflag);

    // 4) enc = relu(relu(box@W_bh1+b)@W_bh2+b) -> of[:, :1024]; nsW = nsp@W_sa
    gemm_p<<<dim3(16, 4, 8), 256, 0, stream>>>(box_bf, 12544, W_bh1, 0, 1024, part, 1024, 1568, dflag);
    reduce_k<true, true, false><<<dim3(256), 256, 0, stream>>>(part, 8, 262144, sb_bh1, t0, 1024, 1024);
    gemm_p<<<dim3(16, 4, 4), 256, 0, stream>>>(t0, 1024, W_bh2, 0, 1024, part, 1024, 256, dflag);
    reduce_k<true, true, false><<<dim3(256), 256, 0, stream>>>(part, 4, 262144, sb_bh2, of, 1024, 2048);
    gemm_p<<<dim3(16, 4, 4), 256, 0, stream>>>(nsp_bf, 1024, W_sa, 0, 1024, part, 1024, 256, dflag);
    reduce_k<false, false, false><<<dim3(256), 256, 0, stream>>>(part, 4, 262144, nullptr, nsW, 1024, 1024);
    // one-time nsp halves of hf/of + h_enc init (ONE launch)
    setup_concat<<<dim3(4, 384), 256, 0, stream>>>(nsp_bf, of, of, hf);

    for (int it = 0; it < 2; ++it) {
        // Hpart = hf @ W_a1[:2048,:] (+ b_a1 folded), Opart = of @ W_a1[2048:,:]
        gemm_p<<<dim3(32, 1, 8), 256, 0, stream>>>(hf, 2048, W_a1, 0, 2048, part, 2048, 256, dflag);
        reduce_k<false, true, true><<<dim3(128), 256, 0, stream>>>(part, 8, 131072, sb_a1, Hpart, 2048, 2048);
        gemm_p<<<dim3(32, 4, 4), 256, 0, stream>>>(of, 2048, W_a1, (size_t)2048 * 2048, 2048, part, 2048, 512, dflag);
        reduce_k<false, false, true><<<dim3(512), 256, 0, stream>>>(part, 4, 524288, nullptr, Opart, 2048, 2048);
        // A_bf[p,k] = bf16(relu(Hpart[h,k] + Opart[n,k]))
        build_pairA<<<dim3(256, 64), 256, 0, stream>>>(Hpart, Opart, A_bf);
        // adj = sigmoid(pair MLP)
        pair_gemm<<<dim3(8, 128), 256, 0, stream>>>(A_bf, Wt_a2, sb_a2, sw_a3, slots);
        adj_finalize<<<dim3(64), 256, 0, stream>>>(slots, sb_a3, adj);
        // obj_msg = relu(enc @ W_om + b)   (enc = of left half, lda 2048)
        gemm_p<<<dim3(16, 4, 4), 256, 0, stream>>>(of, 2048, W_om, 0, 1024, part, 1024, 256, dflag);
        reduce_k<true, true, false><<<dim3(256), 256, 0, stream>>>(part, 4, 262144, sb_om, obj_msg, 1024, 1024);
        // h_enc = [h_enc | agg_o] @ W_hu -> hf[:, :1024]
        agg_o_kernel<<<dim3(8, 64), 256, 0, stream>>>(adj, obj_msg, nsW, hf, hu_in);
        gemm_p<<<dim3(16, 1, 16), 256, 0, stream>>>(hu_in, 2048, W_hu, 0, 1024, part, 1024, 128, dflag);
        reduce_k<false, false, false><<<dim3(64), 256, 0, stream>>>(part, 16, 65536, nullptr, hf, 1024, 2048);
        // hum_msg = relu(h_enc @ W_hm + b)   (h_enc = hf left half)
        gemm_p<<<dim3(16, 1, 16), 256, 0, stream>>>(hf, 2048, W_hm, 0, 1024, part, 1024, 64, dflag);
        reduce_k<true, true, false><<<dim3(64), 256, 0, stream>>>(part, 16, 65536, sb_hm, hum_msg, 1024, 1024);
        // enc = [enc | agg_h] @ W_ou -> of[:, :1024]
        agg_h_kernel<<<dim3(8, 256), 256, 0, stream>>>(adj, hum_msg, nsW, of, ou_in);
        gemm_p<<<dim3(16, 4, 4), 256, 0, stream>>>(ou_in, 2048, W_ou, 0, 1024, part, 1024, 512, dflag);
        reduce_k<false, false, false><<<dim3(256), 256, 0, stream>>>(part, 4, 262144, nullptr, of, 1024, 2048);
    }

    out_kernel<<<dim3(16320), 256, 0, stream>>>(
        hf, of, nsp_bf, adj, sscore, labels, cmask, d_out, dflag);
}